// Round 1
// baseline (4419.654 us; speedup 1.0000x reference)
//
#include <hip/hip_runtime.h>
#include <math.h>

#define B_ 8
#define N_ 1024
#define F_ 32
#define T_ 24
#define E_ 16384
#define CC_ 64
#define CT_ 64
#define LN_EPS_ 1e-5f

// ---------------- temporal attention ----------------

// lhs_tf[b,t,f] = sum_n X[b,n,f,t] * U1[n]
__global__ void k_lhs_tf(const float* __restrict__ X, const float* __restrict__ U1,
                         float* __restrict__ out) {
    int idx = blockIdx.x * 256 + threadIdx.x;
    if (idx >= B_ * T_ * F_) return;
    int f = idx % F_;
    int t = (idx / F_) % T_;
    int b = idx / (F_ * T_);
    const float* xp = X + ((size_t)b * N_ * F_ + f) * T_ + t;
    float acc = 0.f;
    for (int n = 0; n < N_; ++n) acc += xp[(size_t)n * F_ * T_] * U1[n];
    out[idx] = acc;
}

// lhsN[b,t,n] = sum_f lhs_tf[b,t,f] * U2[f,n]
__global__ void k_lhsN(const float* __restrict__ lhs_tf, const float* __restrict__ U2,
                       float* __restrict__ out) {
    int idx = blockIdx.x * 256 + threadIdx.x;
    if (idx >= B_ * T_ * N_) return;
    int n = idx % N_;
    int bt = idx / N_;
    float acc = 0.f;
#pragma unroll
    for (int f = 0; f < F_; ++f) acc += lhs_tf[bt * F_ + f] * U2[(size_t)f * N_ + n];
    out[idx] = acc;
}

// rhsT[b,n,t] = sum_f U3[f] * X[b,n,f,t]
__global__ void k_rhsT(const float* __restrict__ X, const float* __restrict__ U3,
                       float* __restrict__ out) {
    int idx = blockIdx.x * 256 + threadIdx.x;
    if (idx >= B_ * N_ * T_) return;
    int t = idx % T_;
    int n = (idx / T_) % N_;
    int b = idx / (N_ * T_);
    const float* xp = X + ((size_t)(b * N_ + n) * F_) * T_ + t;
    float acc = 0.f;
#pragma unroll
    for (int f = 0; f < F_; ++f) acc += U3[f] * xp[f * T_];
    out[idx] = acc;
}

// per-batch: prod -> sigmoid(+be) -> Ve@ -> col softmax -> Eatt[b,i,j]
__global__ __launch_bounds__(576) void k_eatt(const float* __restrict__ lhsN,
                                              const float* __restrict__ rhsT,
                                              const float* __restrict__ be,
                                              const float* __restrict__ Ve,
                                              float* __restrict__ Eatt) {
    __shared__ float sig[T_ * T_];
    __shared__ float esc[T_ * T_];
    int b = blockIdx.x;
    int tid = threadIdx.x;  // 0..575 == T_*T_
    int i = tid / T_, j = tid % T_;
    {
        const float* lp = lhsN + (size_t)(b * T_ + i) * N_;
        const float* rp = rhsT + (size_t)b * N_ * T_ + j;
        float acc = 0.f;
        for (int n = 0; n < N_; ++n) acc += lp[n] * rp[n * T_];
        sig[tid] = 1.f / (1.f + expf(-(acc + be[tid])));
    }
    __syncthreads();
    {
        float acc = 0.f;
#pragma unroll
        for (int m = 0; m < T_; ++m) acc += Ve[i * T_ + m] * sig[m * T_ + j];
        esc[tid] = acc;
    }
    __syncthreads();
    if (tid < T_) {
        int jj = tid;
        float mx = -1e30f;
        for (int r = 0; r < T_; ++r) mx = fmaxf(mx, esc[r * T_ + jj]);
        float s = 0.f;
        for (int r = 0; r < T_; ++r) {
            float e = expf(esc[r * T_ + jj] - mx);
            sig[r * T_ + jj] = e;
            s += e;
        }
        float inv = 1.f / s;
        for (int r = 0; r < T_; ++r) Eatt[(size_t)(b * T_ + r) * T_ + jj] = sig[r * T_ + jj] * inv;
    }
}

// Xt[b,nf,t] = sum_k X[b,nf,k] * Eatt[b,k,t]
__global__ void k_xt(const float* __restrict__ X, const float* __restrict__ Eatt,
                     float* __restrict__ Xt) {
    __shared__ float e[T_ * T_];
    const int per_b = N_ * F_ * T_ / 256;  // 3072
    int b = blockIdx.x / per_b;
    int tid = threadIdx.x;
    for (int q = tid; q < T_ * T_; q += 256) e[q] = Eatt[(size_t)b * T_ * T_ + q];
    __syncthreads();
    int off = (blockIdx.x % per_b) * 256 + tid;
    int t = off % T_;
    int nf = off / T_;
    const float* xr = X + ((size_t)b * N_ * F_ + nf) * T_;
    float acc = 0.f;
#pragma unroll
    for (int k = 0; k < T_; ++k) acc += xr[k] * e[k * T_ + t];
    Xt[((size_t)b * N_ * F_ + nf) * T_ + t] = acc;
}

// ---------------- spatial attention ----------------

// slhsF[b,n,f] = sum_t Xt[b,n,f,t] * W1[t]
__global__ void k_slhsF(const float* __restrict__ Xt, const float* __restrict__ W1,
                        float* __restrict__ out) {
    int idx = blockIdx.x * 256 + threadIdx.x;
    if (idx >= B_ * N_ * F_) return;
    const float* xp = Xt + (size_t)idx * T_;
    float acc = 0.f;
#pragma unroll
    for (int t = 0; t < T_; ++t) acc += xp[t] * W1[t];
    out[idx] = acc;
}

// slhs[b,n,t] = sum_f slhsF[b,n,f] * W2[f,t]
__global__ void k_slhs(const float* __restrict__ slhsF, const float* __restrict__ W2,
                       float* __restrict__ out) {
    int idx = blockIdx.x * 256 + threadIdx.x;
    if (idx >= B_ * N_ * T_) return;
    int t = idx % T_;
    int bn = idx / T_;
    float acc = 0.f;
#pragma unroll
    for (int f = 0; f < F_; ++f) acc += slhsF[(size_t)bn * F_ + f] * W2[f * T_ + t];
    out[idx] = acc;
}

// srhs[b,t,n] = sum_f W3[f] * Xt[b,n,f,t]
__global__ void k_srhs(const float* __restrict__ Xt, const float* __restrict__ W3,
                       float* __restrict__ out) {
    int idx = blockIdx.x * 256 + threadIdx.x;
    if (idx >= B_ * N_ * T_) return;
    int t = idx % T_;
    int n = (idx / T_) % N_;
    int b = idx / (N_ * T_);
    const float* xp = Xt + ((size_t)(b * N_ + n) * F_) * T_ + t;
    float acc = 0.f;
#pragma unroll
    for (int f = 0; f < F_; ++f) acc += W3[f] * xp[f * T_];
    out[((size_t)b * T_ + t) * N_ + n] = acc;
}

// Psig[b,i,k] = sigmoid( sum_t slhs[b,i,t]*srhs[b,t,k] + bs[i,k] )
__global__ void k_psig(const float* __restrict__ slhs, const float* __restrict__ srhs,
                       const float* __restrict__ bs, float* __restrict__ Psig) {
    int idx = blockIdx.x * 256 + threadIdx.x;
    if (idx >= B_ * N_ * N_) return;
    int k = idx % N_;
    int i = (idx / N_) % N_;
    int b = idx / (N_ * N_);
    const float* lp = slhs + (size_t)(b * N_ + i) * T_;
    const float* rp = srhs + (size_t)b * T_ * N_ + k;
    float acc = bs[(size_t)i * N_ + k];
#pragma unroll
    for (int t = 0; t < T_; ++t) acc += lp[t] * rp[(size_t)t * N_];
    Psig[idx] = 1.f / (1.f + expf(-acc));
}

// Sc[b] = Vs @ Psig[b]   (64x64 tile, 4x4 per thread)
__global__ __launch_bounds__(256) void k_sscore(const float* __restrict__ Vs,
                                                const float* __restrict__ P,
                                                float* __restrict__ Sc) {
    const int b = blockIdx.z;
    const int bm = blockIdx.y * 64, bn = blockIdx.x * 64;
    __shared__ float As[16][65];  // [k][m], padded
    __shared__ float Bs[16][64];  // [k][n]
    const float* Pb = P + (size_t)b * N_ * N_;
    float acc[4][4] = {};
    const int tid = threadIdx.x;
    const int tm = (tid >> 4) << 2, tn = (tid & 15) << 2;
    for (int k0 = 0; k0 < N_; k0 += 16) {
        for (int q = tid; q < 1024; q += 256) {
            int m = q >> 4, k = q & 15;
            As[k][m] = Vs[(size_t)(bm + m) * N_ + k0 + k];
        }
        for (int q = tid; q < 1024; q += 256) {
            int k = q >> 6, n2 = q & 63;
            Bs[k][n2] = Pb[(size_t)(k0 + k) * N_ + bn + n2];
        }
        __syncthreads();
#pragma unroll
        for (int k = 0; k < 16; ++k) {
            float a0 = As[k][tm + 0], a1 = As[k][tm + 1], a2 = As[k][tm + 2], a3 = As[k][tm + 3];
            float b0 = Bs[k][tn + 0], b1 = Bs[k][tn + 1], b2 = Bs[k][tn + 2], b3 = Bs[k][tn + 3];
            acc[0][0] += a0 * b0; acc[0][1] += a0 * b1; acc[0][2] += a0 * b2; acc[0][3] += a0 * b3;
            acc[1][0] += a1 * b0; acc[1][1] += a1 * b1; acc[1][2] += a1 * b2; acc[1][3] += a1 * b3;
            acc[2][0] += a2 * b0; acc[2][1] += a2 * b1; acc[2][2] += a2 * b2; acc[2][3] += a2 * b3;
            acc[3][0] += a3 * b0; acc[3][1] += a3 * b1; acc[3][2] += a3 * b2; acc[3][3] += a3 * b3;
        }
        __syncthreads();
    }
    float* Scb = Sc + (size_t)b * N_ * N_;
    for (int i = 0; i < 4; ++i)
        for (int j = 0; j < 4; ++j)
            Scb[(size_t)(bm + tm + i) * N_ + bn + tn + j] = acc[i][j];
}

// in-place softmax over rows (axis=1): one block handles 64 columns of one b
__global__ __launch_bounds__(256) void k_colsoftmax(float* __restrict__ S) {
    int b = blockIdx.y;
    int k = blockIdx.x * 64 + (threadIdx.x & 63);
    int grp = threadIdx.x >> 6;  // 0..3
    float* Sb = S + (size_t)b * N_ * N_;
    __shared__ float red[4][64];
    float mx = -1e30f;
    for (int r = grp; r < N_; r += 4) mx = fmaxf(mx, Sb[(size_t)r * N_ + k]);
    red[grp][threadIdx.x & 63] = mx;
    __syncthreads();
    mx = fmaxf(fmaxf(red[0][threadIdx.x & 63], red[1][threadIdx.x & 63]),
               fmaxf(red[2][threadIdx.x & 63], red[3][threadIdx.x & 63]));
    __syncthreads();
    float s = 0.f;
    for (int r = grp; r < N_; r += 4) s += expf(Sb[(size_t)r * N_ + k] - mx);
    red[grp][threadIdx.x & 63] = s;
    __syncthreads();
    s = red[0][threadIdx.x & 63] + red[1][threadIdx.x & 63] + red[2][threadIdx.x & 63] +
        red[3][threadIdx.x & 63];
    float inv = 1.f / s;
    for (int r = grp; r < N_; r += 4) {
        size_t idx = (size_t)r * N_ + k;
        Sb[idx] = expf(Sb[idx] - mx) * inv;
    }
}

// ---------------- graph normalization ----------------

__global__ void k_deg(const int* __restrict__ rowI, const int* __restrict__ colI,
                      float* __restrict__ deg) {
    int e = blockIdx.x * 256 + threadIdx.x;
    if (e >= E_) return;
    if (rowI[e] != colI[e]) atomicAdd(&deg[rowI[e]], 1.0f);
}

__global__ void k_norm(const int* __restrict__ rowI, const int* __restrict__ colI,
                       const float* __restrict__ deg, float* __restrict__ normE) {
    int e = blockIdx.x * 256 + threadIdx.x;
    if (e >= E_) return;
    int r = rowI[e], c = colI[e];
    if (r == c) { normE[e] = 0.f; return; }
    float dr = deg[r] > 0.f ? rsqrtf(deg[r]) : 0.f;
    float dc = deg[c] > 0.f ? rsqrtf(deg[c]) : 0.f;
    normE[e] = -dr * dc;
}

__global__ void k_attn(const float* __restrict__ normE, const float* __restrict__ S,
                       const int* __restrict__ rowI, const int* __restrict__ colI,
                       float* __restrict__ attn) {
    int idx = blockIdx.x * 256 + threadIdx.x;
    if (idx >= B_ * E_) return;
    int e = idx % E_;
    int b = idx / E_;
    attn[idx] = normE[e] * S[(size_t)b * N_ * N_ + (size_t)rowI[e] * N_ + colI[e]];
}

__global__ void k_diag(const float* __restrict__ S, float* __restrict__ diagS) {
    int idx = blockIdx.x * 256 + threadIdx.x;
    if (idx >= B_ * N_) return;
    int n = idx % N_;
    int b = idx / N_;
    diagS[idx] = S[(size_t)b * N_ * N_ + (size_t)n * N_ + n];
}

// Tx0 = diagS * X
__global__ void k_tx0(const float* __restrict__ X, const float* __restrict__ diagS,
                      float* __restrict__ Tx0) {
    int idx = blockIdx.x * 256 + threadIdx.x;
    if (idx >= B_ * N_ * F_ * T_) return;
    int bn = idx / (F_ * T_);
    Tx0[idx] = diagS[bn] * X[idx];
}

// Tx2 init = -Tx0
__global__ void k_neg(const float* __restrict__ Tx0, float* __restrict__ Tx2) {
    int idx = blockIdx.x * 256 + threadIdx.x;
    if (idx >= B_ * N_ * F_ * T_) return;
    Tx2[idx] = -Tx0[idx];
}

// scatter: Tout[b,row[e]] += scale*coef*Tin[b,col[e]]  (4 floats per thread)
__global__ void k_prop(const float* __restrict__ Tin, float* __restrict__ Tout,
                       const float* __restrict__ coef, const int* __restrict__ rowI,
                       const int* __restrict__ colI, int perB, float scale) {
    int gid = blockIdx.x * 256 + threadIdx.x;
    const int CH = F_ * T_ / 4;  // 192
    if (gid >= B_ * E_ * CH) return;
    int c4 = gid % CH;
    int e = (gid / CH) % E_;
    int b = gid / (CH * E_);
    float cf = coef[perB ? (b * E_ + e) : e] * scale;
    int r = rowI[e], c = colI[e];
    const float4 v = *(const float4*)(Tin + ((size_t)(b * N_ + c) * F_ * T_) + c4 * 4);
    float* dst = Tout + ((size_t)(b * N_ + r) * F_ * T_) + (size_t)c4 * 4;
    atomicAdd(dst + 0, cf * v.x);
    atomicAdd(dst + 1, cf * v.y);
    atomicAdd(dst + 2, cf * v.z);
    atomicAdd(dst + 3, cf * v.w);
}

// Xhat[b,n,c,t] = relu( sum_k sum_f Txk[b,n,f,t] * chW[k,f,c] + chb[c] )
__global__ __launch_bounds__(256) void k_cheb(const float* __restrict__ Tx0,
                                              const float* __restrict__ Tx1,
                                              const float* __restrict__ Tx2,
                                              const float* __restrict__ W,
                                              const float* __restrict__ bias,
                                              float* __restrict__ Xhat) {
    __shared__ float s0[F_ * T_], s1[F_ * T_], s2[F_ * T_];
    __shared__ float sw[3 * F_ * CC_];
    int bn = blockIdx.x;
    size_t base = (size_t)bn * F_ * T_;
    int tid = threadIdx.x;
    for (int q = tid; q < F_ * T_; q += 256) {
        s0[q] = Tx0[base + q];
        s1[q] = Tx1[base + q];
        s2[q] = Tx2[base + q];
    }
    for (int q = tid; q < 3 * F_ * CC_; q += 256) sw[q] = W[q];
    __syncthreads();
    for (int q = tid; q < CC_ * T_; q += 256) {
        int c = q / T_, t = q % T_;
        float acc = bias[c];
#pragma unroll
        for (int f = 0; f < F_; ++f) {
            acc += s0[f * T_ + t] * sw[(0 * F_ + f) * CC_ + c];
            acc += s1[f * T_ + t] * sw[(1 * F_ + f) * CC_ + c];
            acc += s2[f * T_ + t] * sw[(2 * F_ + f) * CC_ + c];
        }
        Xhat[(size_t)bn * CC_ * T_ + q] = fmaxf(acc, 0.f);
    }
}

// fused: time conv (1x3) + residual conv (1x1) + relu + layernorm over channels
#define NPER_ 16
__global__ __launch_bounds__(256) void k_final(const float* __restrict__ Xhat,
                                               const float* __restrict__ X,
                                               const float* __restrict__ tw,
                                               const float* __restrict__ tb,
                                               const float* __restrict__ rw,
                                               const float* __restrict__ rb,
                                               const float* __restrict__ g,
                                               const float* __restrict__ bb,
                                               float* __restrict__ out) {
    __shared__ float s_tw[CC_ * 3 * CT_];  // [(ci*3+dt)*64 + co]
    __shared__ float s_rw[F_ * CT_];       // [ci*64 + co]
    __shared__ float s_tb[CT_], s_rb[CT_], s_g[CT_], s_b[CT_];
    __shared__ float s_xh[CC_][T_];
    __shared__ float s_x[F_][T_];
    __shared__ float s_z[CT_ * T_];
    int tid = threadIdx.x;
    for (int q = tid; q < CC_ * 3 * CT_; q += 256) {
        int co = q % CT_;
        int r = q / CT_;
        int dt = r % 3;
        int ci = r / 3;
        s_tw[q] = tw[(co * CC_ + ci) * 3 + dt];
    }
    for (int q = tid; q < F_ * CT_; q += 256) {
        int co = q % CT_;
        int ci = q / CT_;
        s_rw[q] = rw[co * F_ + ci];
    }
    if (tid < CT_) {
        s_tb[tid] = tb[tid];
        s_rb[tid] = rb[tid];
        s_g[tid] = g[tid];
        s_b[tid] = bb[tid];
    }
    int c = tid & 63;
    int tg = tid >> 6;
    for (int ni = 0; ni < NPER_; ++ni) {
        int bn = blockIdx.x * NPER_ + ni;
        size_t xh_base = (size_t)bn * CC_ * T_;
        size_t x_base = (size_t)bn * F_ * T_;
        __syncthreads();
        for (int q = tid; q < CC_ * T_; q += 256) ((float*)s_xh)[q] = Xhat[xh_base + q];
        for (int q = tid; q < F_ * T_; q += 256) ((float*)s_x)[q] = X[x_base + q];
        __syncthreads();
        for (int t = tg; t < T_; t += 4) {
            float acc = s_tb[c] + s_rb[c];
#pragma unroll
            for (int ci = 0; ci < CC_; ++ci) {
                float w0 = s_tw[(ci * 3 + 0) * CT_ + c];
                float w1 = s_tw[(ci * 3 + 1) * CT_ + c];
                float w2 = s_tw[(ci * 3 + 2) * CT_ + c];
                if (t > 0) acc += s_xh[ci][t - 1] * w0;
                acc += s_xh[ci][t] * w1;
                if (t < T_ - 1) acc += s_xh[ci][t + 1] * w2;
            }
#pragma unroll
            for (int ci = 0; ci < F_; ++ci) acc += s_x[ci][t] * s_rw[ci * CT_ + c];
            float z = fmaxf(acc, 0.f);
            float sum1 = z, sum2 = z * z;
            for (int off = 32; off > 0; off >>= 1) {
                sum1 += __shfl_xor(sum1, off);
                sum2 += __shfl_xor(sum2, off);
            }
            float mu = sum1 * (1.f / CT_);
            float var = sum2 * (1.f / CT_) - mu * mu;
            s_z[c * T_ + t] = (z - mu) * rsqrtf(var + LN_EPS_) * s_g[c] + s_b[c];
        }
        __syncthreads();
        for (int q = tid; q < CT_ * T_; q += 256) out[(size_t)bn * CT_ * T_ + q] = s_z[q];
    }
}

extern "C" void kernel_launch(void* const* d_in, const int* in_sizes, int n_in,
                              void* d_out, int out_size, void* d_ws, size_t ws_size,
                              hipStream_t stream) {
    const float* X = (const float*)d_in[0];
    const int* ei = (const int*)d_in[1];
    const float* U1 = (const float*)d_in[2];
    const float* U2 = (const float*)d_in[3];
    const float* U3 = (const float*)d_in[4];
    const float* be = (const float*)d_in[5];
    const float* Ve = (const float*)d_in[6];
    const float* W1 = (const float*)d_in[7];
    const float* W2 = (const float*)d_in[8];
    const float* W3 = (const float*)d_in[9];
    const float* bs = (const float*)d_in[10];
    const float* Vs = (const float*)d_in[11];
    const float* chW = (const float*)d_in[12];
    const float* chb = (const float*)d_in[13];
    const float* tw = (const float*)d_in[14];
    const float* tb = (const float*)d_in[15];
    const float* rw = (const float*)d_in[16];
    const float* rb = (const float*)d_in[17];
    const float* lng = (const float*)d_in[18];
    const float* lnb = (const float*)d_in[19];
    float* out = (float*)d_out;
    float* ws = (float*)d_ws;

    size_t o = 0;
    float* lhs_tf = ws + o; o += B_ * T_ * F_;
    float* lhsN  = ws + o; o += (size_t)B_ * T_ * N_;
    float* rhsT  = ws + o; o += (size_t)B_ * N_ * T_;
    float* Eatt  = ws + o; o += B_ * T_ * T_;
    float* slhsF = ws + o; o += (size_t)B_ * N_ * F_;
    float* slhs  = ws + o; o += (size_t)B_ * N_ * T_;
    float* srhs  = ws + o; o += (size_t)B_ * T_ * N_;
    float* deg   = ws + o; o += N_;
    float* normE = ws + o; o += E_;
    float* attn  = ws + o; o += (size_t)B_ * E_;
    float* diagS = ws + o; o += B_ * N_;
    float* Xt    = ws + o; o += (size_t)B_ * N_ * F_ * T_;  // later reused as Tx2
    float* Psig  = ws + o; o += (size_t)B_ * N_ * N_;       // later reused as Tx0
    float* S     = ws + o; o += (size_t)B_ * N_ * N_;       // later reused as Tx1
    float* Xhat  = ws + o; o += (size_t)B_ * N_ * CC_ * T_;
    float* Tx0 = Psig;
    float* Tx1 = S;
    float* Tx2 = Xt;
    const int* rowI = ei;
    const int* colI = ei + E_;

    // temporal attention
    k_lhs_tf<<<(B_ * T_ * F_ + 255) / 256, 256, 0, stream>>>(X, U1, lhs_tf);
    k_lhsN<<<(B_ * T_ * N_ + 255) / 256, 256, 0, stream>>>(lhs_tf, U2, lhsN);
    k_rhsT<<<(B_ * N_ * T_ + 255) / 256, 256, 0, stream>>>(X, U3, rhsT);
    k_eatt<<<B_, 576, 0, stream>>>(lhsN, rhsT, be, Ve, Eatt);
    k_xt<<<B_ * (N_ * F_ * T_ / 256), 256, 0, stream>>>(X, Eatt, Xt);
    // spatial attention
    k_slhsF<<<(B_ * N_ * F_ + 255) / 256, 256, 0, stream>>>(Xt, W1, slhsF);
    k_slhs<<<(B_ * N_ * T_ + 255) / 256, 256, 0, stream>>>(slhsF, W2, slhs);
    k_srhs<<<(B_ * N_ * T_ + 255) / 256, 256, 0, stream>>>(Xt, W3, srhs);
    k_psig<<<(B_ * N_ * N_ + 255) / 256, 256, 0, stream>>>(slhs, srhs, bs, Psig);
    {
        dim3 g(N_ / 64, N_ / 64, B_);
        k_sscore<<<g, 256, 0, stream>>>(Vs, Psig, S);
    }
    {
        dim3 g(N_ / 64, B_);
        k_colsoftmax<<<g, 256, 0, stream>>>(S);
    }
    // graph norm
    hipMemsetAsync(deg, 0, N_ * sizeof(float), stream);
    k_deg<<<(E_ + 255) / 256, 256, 0, stream>>>(rowI, colI, deg);
    k_norm<<<(E_ + 255) / 256, 256, 0, stream>>>(rowI, colI, deg, normE);
    k_attn<<<(B_ * E_ + 255) / 256, 256, 0, stream>>>(normE, S, rowI, colI, attn);
    k_diag<<<(B_ * N_ + 255) / 256, 256, 0, stream>>>(S, diagS);
    // chebyshev propagation
    k_tx0<<<(B_ * N_ * F_ * T_ + 255) / 256, 256, 0, stream>>>(X, diagS, Tx0);
    hipMemsetAsync(Tx1, 0, (size_t)B_ * N_ * F_ * T_ * sizeof(float), stream);
    {
        int tot = B_ * E_ * (F_ * T_ / 4);
        k_prop<<<(tot + 255) / 256, 256, 0, stream>>>(Tx0, Tx1, attn, rowI, colI, 1, 1.0f);
    }
    k_neg<<<(B_ * N_ * F_ * T_ + 255) / 256, 256, 0, stream>>>(Tx0, Tx2);
    {
        int tot = B_ * E_ * (F_ * T_ / 4);
        k_prop<<<(tot + 255) / 256, 256, 0, stream>>>(Tx1, Tx2, normE, rowI, colI, 0, 2.0f);
    }
    k_cheb<<<B_ * N_, 256, 0, stream>>>(Tx0, Tx1, Tx2, chW, chb, Xhat);
    // fused time conv + residual + layernorm
    k_final<<<B_ * N_ / NPER_, 256, 0, stream>>>(Xhat, X, tw, tb, rw, rb, lng, lnb, out);
}

// Round 3
// 1871.788 us; speedup vs baseline: 2.3612x; 2.3612x over previous
//
#include <hip/hip_runtime.h>
#include <math.h>

#define B_ 8
#define N_ 1024
#define F_ 32
#define T_ 24
#define E_ 16384
#define CC_ 64
#define CT_ 64
#define LN_EPS_ 1e-5f

// ---------------- temporal attention ----------------

// lhs_tf[b,t,f] = sum_n X[b,n,f,t] * U1[n]
__global__ void k_lhs_tf(const float* __restrict__ X, const float* __restrict__ U1,
                         float* __restrict__ out) {
    int idx = blockIdx.x * 256 + threadIdx.x;
    if (idx >= B_ * T_ * F_) return;
    int f = idx % F_;
    int t = (idx / F_) % T_;
    int b = idx / (F_ * T_);
    const float* xp = X + ((size_t)b * N_ * F_ + f) * T_ + t;
    float acc = 0.f;
    for (int n = 0; n < N_; ++n) acc += xp[(size_t)n * F_ * T_] * U1[n];
    out[idx] = acc;
}

// lhsN[b,t,n] = sum_f lhs_tf[b,t,f] * U2[f,n]
__global__ void k_lhsN(const float* __restrict__ lhs_tf, const float* __restrict__ U2,
                       float* __restrict__ out) {
    int idx = blockIdx.x * 256 + threadIdx.x;
    if (idx >= B_ * T_ * N_) return;
    int n = idx % N_;
    int bt = idx / N_;
    float acc = 0.f;
#pragma unroll
    for (int f = 0; f < F_; ++f) acc += lhs_tf[bt * F_ + f] * U2[(size_t)f * N_ + n];
    out[idx] = acc;
}

// rhsT[b,n,t] = sum_f U3[f] * X[b,n,f,t]
__global__ void k_rhsT(const float* __restrict__ X, const float* __restrict__ U3,
                       float* __restrict__ out) {
    int idx = blockIdx.x * 256 + threadIdx.x;
    if (idx >= B_ * N_ * T_) return;
    int t = idx % T_;
    int n = (idx / T_) % N_;
    int b = idx / (N_ * T_);
    const float* xp = X + ((size_t)(b * N_ + n) * F_) * T_ + t;
    float acc = 0.f;
#pragma unroll
    for (int f = 0; f < F_; ++f) acc += U3[f] * xp[f * T_];
    out[idx] = acc;
}

// per-batch: prod -> sigmoid(+be) -> Ve@ -> col softmax -> Eatt[b,i,j]
__global__ __launch_bounds__(576) void k_eatt(const float* __restrict__ lhsN,
                                              const float* __restrict__ rhsT,
                                              const float* __restrict__ be,
                                              const float* __restrict__ Ve,
                                              float* __restrict__ Eatt) {
    __shared__ float sig[T_ * T_];
    __shared__ float esc[T_ * T_];
    int b = blockIdx.x;
    int tid = threadIdx.x;  // 0..575 == T_*T_
    int i = tid / T_, j = tid % T_;
    {
        const float* lp = lhsN + (size_t)(b * T_ + i) * N_;
        const float* rp = rhsT + (size_t)b * N_ * T_ + j;
        float acc = 0.f;
        for (int n = 0; n < N_; ++n) acc += lp[n] * rp[n * T_];
        sig[tid] = 1.f / (1.f + expf(-(acc + be[tid])));
    }
    __syncthreads();
    {
        float acc = 0.f;
#pragma unroll
        for (int m = 0; m < T_; ++m) acc += Ve[i * T_ + m] * sig[m * T_ + j];
        esc[tid] = acc;
    }
    __syncthreads();
    if (tid < T_) {
        int jj = tid;
        float mx = -1e30f;
        for (int r = 0; r < T_; ++r) mx = fmaxf(mx, esc[r * T_ + jj]);
        float s = 0.f;
        for (int r = 0; r < T_; ++r) {
            float e = expf(esc[r * T_ + jj] - mx);
            sig[r * T_ + jj] = e;
            s += e;
        }
        float inv = 1.f / s;
        for (int r = 0; r < T_; ++r) Eatt[(size_t)(b * T_ + r) * T_ + jj] = sig[r * T_ + jj] * inv;
    }
}

// Xt[b,nf,t] = sum_k X[b,nf,k] * Eatt[b,k,t]
__global__ void k_xt(const float* __restrict__ X, const float* __restrict__ Eatt,
                     float* __restrict__ Xt) {
    __shared__ float e[T_ * T_];
    const int per_b = N_ * F_ * T_ / 256;  // 3072
    int b = blockIdx.x / per_b;
    int tid = threadIdx.x;
    for (int q = tid; q < T_ * T_; q += 256) e[q] = Eatt[(size_t)b * T_ * T_ + q];
    __syncthreads();
    int off = (blockIdx.x % per_b) * 256 + tid;
    int t = off % T_;
    int nf = off / T_;
    const float* xr = X + ((size_t)b * N_ * F_ + nf) * T_;
    float acc = 0.f;
#pragma unroll
    for (int k = 0; k < T_; ++k) acc += xr[k] * e[k * T_ + t];
    Xt[((size_t)b * N_ * F_ + nf) * T_ + t] = acc;
}

// ---------------- spatial attention ----------------

// slhsF[b,n,f] = sum_t Xt[b,n,f,t] * W1[t]
__global__ void k_slhsF(const float* __restrict__ Xt, const float* __restrict__ W1,
                        float* __restrict__ out) {
    int idx = blockIdx.x * 256 + threadIdx.x;
    if (idx >= B_ * N_ * F_) return;
    const float* xp = Xt + (size_t)idx * T_;
    float acc = 0.f;
#pragma unroll
    for (int t = 0; t < T_; ++t) acc += xp[t] * W1[t];
    out[idx] = acc;
}

// slhs[b,n,t] = sum_f slhsF[b,n,f] * W2[f,t]
__global__ void k_slhs(const float* __restrict__ slhsF, const float* __restrict__ W2,
                       float* __restrict__ out) {
    int idx = blockIdx.x * 256 + threadIdx.x;
    if (idx >= B_ * N_ * T_) return;
    int t = idx % T_;
    int bn = idx / T_;
    float acc = 0.f;
#pragma unroll
    for (int f = 0; f < F_; ++f) acc += slhsF[(size_t)bn * F_ + f] * W2[f * T_ + t];
    out[idx] = acc;
}

// srhs[b,t,n] = sum_f W3[f] * Xt[b,n,f,t]
__global__ void k_srhs(const float* __restrict__ Xt, const float* __restrict__ W3,
                       float* __restrict__ out) {
    int idx = blockIdx.x * 256 + threadIdx.x;
    if (idx >= B_ * N_ * T_) return;
    int t = idx % T_;
    int n = (idx / T_) % N_;
    int b = idx / (N_ * T_);
    const float* xp = Xt + ((size_t)(b * N_ + n) * F_) * T_ + t;
    float acc = 0.f;
#pragma unroll
    for (int f = 0; f < F_; ++f) acc += W3[f] * xp[f * T_];
    out[((size_t)b * T_ + t) * N_ + n] = acc;
}

// Psig[b,i,k] = sigmoid( sum_t slhs[b,i,t]*srhs[b,t,k] + bs[i,k] )
__global__ void k_psig(const float* __restrict__ slhs, const float* __restrict__ srhs,
                       const float* __restrict__ bs, float* __restrict__ Psig) {
    int idx = blockIdx.x * 256 + threadIdx.x;
    if (idx >= B_ * N_ * N_) return;
    int k = idx % N_;
    int i = (idx / N_) % N_;
    int b = idx / (N_ * N_);
    const float* lp = slhs + (size_t)(b * N_ + i) * T_;
    const float* rp = srhs + (size_t)b * T_ * N_ + k;
    float acc = bs[(size_t)i * N_ + k];
#pragma unroll
    for (int t = 0; t < T_; ++t) acc += lp[t] * rp[(size_t)t * N_];
    Psig[idx] = 1.f / (1.f + expf(-acc));
}

// Sc[b] = Vs @ Psig[b]   (64x64 tile, 4x4 per thread)
__global__ __launch_bounds__(256) void k_sscore(const float* __restrict__ Vs,
                                                const float* __restrict__ P,
                                                float* __restrict__ Sc) {
    const int b = blockIdx.z;
    const int bm = blockIdx.y * 64, bn = blockIdx.x * 64;
    __shared__ float As[16][65];  // [k][m], padded
    __shared__ float Bs[16][64];  // [k][n]
    const float* Pb = P + (size_t)b * N_ * N_;
    float acc[4][4] = {};
    const int tid = threadIdx.x;
    const int tm = (tid >> 4) << 2, tn = (tid & 15) << 2;
    for (int k0 = 0; k0 < N_; k0 += 16) {
        for (int q = tid; q < 1024; q += 256) {
            int m = q >> 4, k = q & 15;
            As[k][m] = Vs[(size_t)(bm + m) * N_ + k0 + k];
        }
        for (int q = tid; q < 1024; q += 256) {
            int k = q >> 6, n2 = q & 63;
            Bs[k][n2] = Pb[(size_t)(k0 + k) * N_ + bn + n2];
        }
        __syncthreads();
#pragma unroll
        for (int k = 0; k < 16; ++k) {
            float a0 = As[k][tm + 0], a1 = As[k][tm + 1], a2 = As[k][tm + 2], a3 = As[k][tm + 3];
            float b0 = Bs[k][tn + 0], b1 = Bs[k][tn + 1], b2 = Bs[k][tn + 2], b3 = Bs[k][tn + 3];
            acc[0][0] += a0 * b0; acc[0][1] += a0 * b1; acc[0][2] += a0 * b2; acc[0][3] += a0 * b3;
            acc[1][0] += a1 * b0; acc[1][1] += a1 * b1; acc[1][2] += a1 * b2; acc[1][3] += a1 * b3;
            acc[2][0] += a2 * b0; acc[2][1] += a2 * b1; acc[2][2] += a2 * b2; acc[2][3] += a2 * b3;
            acc[3][0] += a3 * b0; acc[3][1] += a3 * b1; acc[3][2] += a3 * b2; acc[3][3] += a3 * b3;
        }
        __syncthreads();
    }
    float* Scb = Sc + (size_t)b * N_ * N_;
    for (int i = 0; i < 4; ++i)
        for (int j = 0; j < 4; ++j)
            Scb[(size_t)(bm + tm + i) * N_ + bn + tn + j] = acc[i][j];
}

// in-place softmax over rows (axis=1): one block handles 64 columns of one b
__global__ __launch_bounds__(256) void k_colsoftmax(float* __restrict__ S) {
    int b = blockIdx.y;
    int k = blockIdx.x * 64 + (threadIdx.x & 63);
    int grp = threadIdx.x >> 6;  // 0..3
    float* Sb = S + (size_t)b * N_ * N_;
    __shared__ float red[4][64];
    float mx = -1e30f;
    for (int r = grp; r < N_; r += 4) mx = fmaxf(mx, Sb[(size_t)r * N_ + k]);
    red[grp][threadIdx.x & 63] = mx;
    __syncthreads();
    mx = fmaxf(fmaxf(red[0][threadIdx.x & 63], red[1][threadIdx.x & 63]),
               fmaxf(red[2][threadIdx.x & 63], red[3][threadIdx.x & 63]));
    __syncthreads();
    float s = 0.f;
    for (int r = grp; r < N_; r += 4) s += expf(Sb[(size_t)r * N_ + k] - mx);
    red[grp][threadIdx.x & 63] = s;
    __syncthreads();
    s = red[0][threadIdx.x & 63] + red[1][threadIdx.x & 63] + red[2][threadIdx.x & 63] +
        red[3][threadIdx.x & 63];
    float inv = 1.f / s;
    for (int r = grp; r < N_; r += 4) {
        size_t idx = (size_t)r * N_ + k;
        Sb[idx] = expf(Sb[idx] - mx) * inv;
    }
}

// ---------------- graph: CSR build + normalization ----------------

// per-edge: count CSR entries per row; float degree excluding self-loops
__global__ void k_count(const int* __restrict__ rowI, const int* __restrict__ colI,
                        int* __restrict__ cnt, float* __restrict__ deg) {
    int e = blockIdx.x * 256 + threadIdx.x;
    if (e >= E_) return;
    int r = rowI[e];
    atomicAdd(&cnt[r], 1);
    if (r != colI[e]) atomicAdd(&deg[r], 1.0f);
}

// single block, 1024 threads: prefix-sum cnt -> rowPtr, fillPos; dis = rsqrt(deg)
__global__ __launch_bounds__(1024) void k_scan(const int* __restrict__ cnt,
                                               const float* __restrict__ deg,
                                               int* __restrict__ rowPtr,
                                               int* __restrict__ fillPos,
                                               float* __restrict__ dis) {
    __shared__ int s[N_];
    int tid = threadIdx.x;
    int my = cnt[tid];
    s[tid] = my;
    __syncthreads();
    for (int off = 1; off < N_; off <<= 1) {
        int v = 0;
        if (tid >= off) v = s[tid - off];
        __syncthreads();
        s[tid] += v;
        __syncthreads();
    }
    rowPtr[tid + 1] = s[tid];
    if (tid == 0) rowPtr[0] = 0;
    fillPos[tid] = s[tid] - my;
    float d = deg[tid];
    dis[tid] = d > 0.f ? rsqrtf(d) : 0.f;
}

// scatter edge ids into CSR buckets
__global__ void k_fill(const int* __restrict__ rowI, const int* __restrict__ colI,
                       int* __restrict__ fillPos, int* __restrict__ csrRow,
                       int* __restrict__ csrCol) {
    int e = blockIdx.x * 256 + threadIdx.x;
    if (e >= E_) return;
    int r = rowI[e];
    int pos = atomicAdd(&fillPos[r], 1);
    csrRow[pos] = r;
    csrCol[pos] = colI[e];
}

// per CSR slot: norm coefficient and per-batch attention coefficient
__global__ void k_csrcoef(const int* __restrict__ csrRow, const int* __restrict__ csrCol,
                          const float* __restrict__ dis, const float* __restrict__ S,
                          float* __restrict__ csrNorm, float* __restrict__ csrAttn) {
    int p = blockIdx.x * 256 + threadIdx.x;
    if (p >= E_) return;
    int r = csrRow[p], c = csrCol[p];
    float nm = (r == c) ? 0.f : -dis[r] * dis[c];
    csrNorm[p] = nm;
    size_t off = (size_t)r * N_ + c;
#pragma unroll
    for (int b = 0; b < B_; ++b)
        csrAttn[(size_t)b * E_ + p] = nm * S[(size_t)b * N_ * N_ + off];
}

__global__ void k_diag(const float* __restrict__ S, float* __restrict__ diagS) {
    int idx = blockIdx.x * 256 + threadIdx.x;
    if (idx >= B_ * N_) return;
    int n = idx % N_;
    int b = idx / N_;
    diagS[idx] = S[(size_t)b * N_ * N_ + (size_t)n * N_ + n];
}

// Tx0 = diagS * X
__global__ void k_tx0(const float* __restrict__ X, const float* __restrict__ diagS,
                      float* __restrict__ Tx0) {
    int idx = blockIdx.x * 256 + threadIdx.x;
    if (idx >= B_ * N_ * F_ * T_) return;
    int bn = idx / (F_ * T_);
    Tx0[idx] = diagS[bn] * X[idx];
}

// gather propagation: Tout[b,n,:] = scale * sum_{p in csr row n} coef[p] * Tin[b,csrCol[p],:]
//                     (- Tsub[b,n,:] if hasSub)
// block = b + 8*n so that (round-robin dispatch) each XCD sees mostly one batch b
__global__ __launch_bounds__(192) void k_gprop(const float* __restrict__ Tin,
                                               const float* __restrict__ Tsub,
                                               float* __restrict__ Tout,
                                               const float* __restrict__ coef,
                                               const int* __restrict__ csrCol,
                                               const int* __restrict__ rowPtr,
                                               int perB, float scale, int hasSub) {
    int blk = blockIdx.x;
    int b = blk & 7;
    int n = blk >> 3;
    int tid = threadIdx.x;
    int s = rowPtr[n], e = rowPtr[n + 1];
    const float* cbase = coef + (perB ? (size_t)b * E_ : 0);
    float ax = 0.f, ay = 0.f, az = 0.f, aw = 0.f;
    for (int p = s; p < e; ++p) {
        float cf = cbase[p];
        const float4 v =
            *(const float4*)(Tin + ((size_t)(b * N_ + csrCol[p]) * (F_ * T_)) + tid * 4);
        ax += cf * v.x;
        ay += cf * v.y;
        az += cf * v.z;
        aw += cf * v.w;
    }
    size_t obase = (size_t)(b * N_ + n) * (F_ * T_) + tid * 4;
    float4 r;
    r.x = ax * scale;
    r.y = ay * scale;
    r.z = az * scale;
    r.w = aw * scale;
    if (hasSub) {
        const float4 u = *(const float4*)(Tsub + obase);
        r.x -= u.x;
        r.y -= u.y;
        r.z -= u.z;
        r.w -= u.w;
    }
    *(float4*)(Tout + obase) = r;
}

// Xhat[b,n,c,t] = relu( sum_k sum_f Txk[b,n,f,t] * chW[k,f,c] + chb[c] )
__global__ __launch_bounds__(256) void k_cheb(const float* __restrict__ Tx0,
                                              const float* __restrict__ Tx1,
                                              const float* __restrict__ Tx2,
                                              const float* __restrict__ W,
                                              const float* __restrict__ bias,
                                              float* __restrict__ Xhat) {
    __shared__ float s0[F_ * T_], s1[F_ * T_], s2[F_ * T_];
    __shared__ float sw[3 * F_ * CC_];
    int bn = blockIdx.x;
    size_t base = (size_t)bn * F_ * T_;
    int tid = threadIdx.x;
    for (int q = tid; q < F_ * T_; q += 256) {
        s0[q] = Tx0[base + q];
        s1[q] = Tx1[base + q];
        s2[q] = Tx2[base + q];
    }
    for (int q = tid; q < 3 * F_ * CC_; q += 256) sw[q] = W[q];
    __syncthreads();
    for (int q = tid; q < CC_ * T_; q += 256) {
        int c = q / T_, t = q % T_;
        float acc = bias[c];
#pragma unroll
        for (int f = 0; f < F_; ++f) {
            acc += s0[f * T_ + t] * sw[(0 * F_ + f) * CC_ + c];
            acc += s1[f * T_ + t] * sw[(1 * F_ + f) * CC_ + c];
            acc += s2[f * T_ + t] * sw[(2 * F_ + f) * CC_ + c];
        }
        Xhat[(size_t)bn * CC_ * T_ + q] = fmaxf(acc, 0.f);
    }
}

// fused: time conv (1x3) + residual conv (1x1) + relu + layernorm over channels
#define NPER_ 16
__global__ __launch_bounds__(256) void k_final(const float* __restrict__ Xhat,
                                               const float* __restrict__ X,
                                               const float* __restrict__ tw,
                                               const float* __restrict__ tb,
                                               const float* __restrict__ rw,
                                               const float* __restrict__ rb,
                                               const float* __restrict__ g,
                                               const float* __restrict__ bb,
                                               float* __restrict__ out) {
    __shared__ float s_tw[CC_ * 3 * CT_];  // [(ci*3+dt)*64 + co]
    __shared__ float s_rw[F_ * CT_];       // [ci*64 + co]
    __shared__ float s_tb[CT_], s_rb[CT_], s_g[CT_], s_b[CT_];
    __shared__ float s_xh[CC_][T_];
    __shared__ float s_x[F_][T_];
    __shared__ float s_z[CT_ * T_];
    int tid = threadIdx.x;
    for (int q = tid; q < CC_ * 3 * CT_; q += 256) {
        int co = q % CT_;
        int r = q / CT_;
        int dt = r % 3;
        int ci = r / 3;
        s_tw[q] = tw[(co * CC_ + ci) * 3 + dt];
    }
    for (int q = tid; q < F_ * CT_; q += 256) {
        int co = q % CT_;
        int ci = q / CT_;
        s_rw[q] = rw[co * F_ + ci];
    }
    if (tid < CT_) {
        s_tb[tid] = tb[tid];
        s_rb[tid] = rb[tid];
        s_g[tid] = g[tid];
        s_b[tid] = bb[tid];
    }
    int c = tid & 63;
    int tg = tid >> 6;
    for (int ni = 0; ni < NPER_; ++ni) {
        int bn = blockIdx.x * NPER_ + ni;
        size_t xh_base = (size_t)bn * CC_ * T_;
        size_t x_base = (size_t)bn * F_ * T_;
        __syncthreads();
        for (int q = tid; q < CC_ * T_; q += 256) ((float*)s_xh)[q] = Xhat[xh_base + q];
        for (int q = tid; q < F_ * T_; q += 256) ((float*)s_x)[q] = X[x_base + q];
        __syncthreads();
        for (int t = tg; t < T_; t += 4) {
            float acc = s_tb[c] + s_rb[c];
#pragma unroll
            for (int ci = 0; ci < CC_; ++ci) {
                float w0 = s_tw[(ci * 3 + 0) * CT_ + c];
                float w1 = s_tw[(ci * 3 + 1) * CT_ + c];
                float w2 = s_tw[(ci * 3 + 2) * CT_ + c];
                if (t > 0) acc += s_xh[ci][t - 1] * w0;
                acc += s_xh[ci][t] * w1;
                if (t < T_ - 1) acc += s_xh[ci][t + 1] * w2;
            }
#pragma unroll
            for (int ci = 0; ci < F_; ++ci) acc += s_x[ci][t] * s_rw[ci * CT_ + c];
            float z = fmaxf(acc, 0.f);
            float sum1 = z, sum2 = z * z;
            for (int off = 32; off > 0; off >>= 1) {
                sum1 += __shfl_xor(sum1, off);
                sum2 += __shfl_xor(sum2, off);
            }
            float mu = sum1 * (1.f / CT_);
            float var = sum2 * (1.f / CT_) - mu * mu;
            s_z[c * T_ + t] = (z - mu) * rsqrtf(var + LN_EPS_) * s_g[c] + s_b[c];
        }
        __syncthreads();
        for (int q = tid; q < CT_ * T_; q += 256) out[(size_t)bn * CT_ * T_ + q] = s_z[q];
    }
}

extern "C" void kernel_launch(void* const* d_in, const int* in_sizes, int n_in,
                              void* d_out, int out_size, void* d_ws, size_t ws_size,
                              hipStream_t stream) {
    const float* X = (const float*)d_in[0];
    const int* ei = (const int*)d_in[1];
    const float* U1 = (const float*)d_in[2];
    const float* U2 = (const float*)d_in[3];
    const float* U3 = (const float*)d_in[4];
    const float* be = (const float*)d_in[5];
    const float* Ve = (const float*)d_in[6];
    const float* W1 = (const float*)d_in[7];
    const float* W2 = (const float*)d_in[8];
    const float* W3 = (const float*)d_in[9];
    const float* bs = (const float*)d_in[10];
    const float* Vs = (const float*)d_in[11];
    const float* chW = (const float*)d_in[12];
    const float* chb = (const float*)d_in[13];
    const float* tw = (const float*)d_in[14];
    const float* tb = (const float*)d_in[15];
    const float* rw = (const float*)d_in[16];
    const float* rb = (const float*)d_in[17];
    const float* lng = (const float*)d_in[18];
    const float* lnb = (const float*)d_in[19];
    float* out = (float*)d_out;
    float* ws = (float*)d_ws;

    size_t o = 0;
    float* lhs_tf = ws + o; o += B_ * T_ * F_;
    float* lhsN  = ws + o; o += (size_t)B_ * T_ * N_;
    float* rhsT  = ws + o; o += (size_t)B_ * N_ * T_;
    float* Eatt  = ws + o; o += B_ * T_ * T_;
    float* slhsF = ws + o; o += (size_t)B_ * N_ * F_;
    float* slhs  = ws + o; o += (size_t)B_ * N_ * T_;
    float* srhs  = ws + o; o += (size_t)B_ * T_ * N_;
    float* deg   = ws + o; o += N_;
    float* dis   = ws + o; o += N_;
    float* diagS = ws + o; o += B_ * N_;
    float* csrNorm = ws + o; o += E_;
    float* csrAttn = ws + o; o += (size_t)B_ * E_;
    int* cnt     = (int*)(ws + o); o += N_;
    int* rowPtr  = (int*)(ws + o); o += N_ + 1;
    int* fillPos = (int*)(ws + o); o += N_;
    int* csrRow  = (int*)(ws + o); o += E_;
    int* csrCol  = (int*)(ws + o); o += E_;
    float* Xt    = ws + o; o += (size_t)B_ * N_ * F_ * T_;  // later reused as Tx2
    float* Psig  = ws + o; o += (size_t)B_ * N_ * N_;       // later reused as Tx0
    float* S     = ws + o; o += (size_t)B_ * N_ * N_;       // later reused as Tx1
    float* Xhat  = ws + o; o += (size_t)B_ * N_ * CC_ * T_;
    float* Tx0 = Psig;
    float* Tx1 = S;
    float* Tx2 = Xt;
    const int* rowI = ei;
    const int* colI = ei + E_;

    // CSR build (independent of attention pipeline)
    hipMemsetAsync(cnt, 0, N_ * sizeof(int), stream);
    hipMemsetAsync(deg, 0, N_ * sizeof(float), stream);
    k_count<<<(E_ + 255) / 256, 256, 0, stream>>>(rowI, colI, cnt, deg);
    k_scan<<<1, 1024, 0, stream>>>(cnt, deg, rowPtr, fillPos, dis);
    k_fill<<<(E_ + 255) / 256, 256, 0, stream>>>(rowI, colI, fillPos, csrRow, csrCol);

    // temporal attention
    k_lhs_tf<<<(B_ * T_ * F_ + 255) / 256, 256, 0, stream>>>(X, U1, lhs_tf);
    k_lhsN<<<(B_ * T_ * N_ + 255) / 256, 256, 0, stream>>>(lhs_tf, U2, lhsN);
    k_rhsT<<<(B_ * N_ * T_ + 255) / 256, 256, 0, stream>>>(X, U3, rhsT);
    k_eatt<<<B_, 576, 0, stream>>>(lhsN, rhsT, be, Ve, Eatt);
    k_xt<<<B_ * (N_ * F_ * T_ / 256), 256, 0, stream>>>(X, Eatt, Xt);
    // spatial attention
    k_slhsF<<<(B_ * N_ * F_ + 255) / 256, 256, 0, stream>>>(Xt, W1, slhsF);
    k_slhs<<<(B_ * N_ * T_ + 255) / 256, 256, 0, stream>>>(slhsF, W2, slhs);
    k_srhs<<<(B_ * N_ * T_ + 255) / 256, 256, 0, stream>>>(Xt, W3, srhs);
    k_psig<<<(B_ * N_ * N_ + 255) / 256, 256, 0, stream>>>(slhs, srhs, bs, Psig);
    {
        dim3 g(N_ / 64, N_ / 64, B_);
        k_sscore<<<g, 256, 0, stream>>>(Vs, Psig, S);
    }
    {
        dim3 g(N_ / 64, B_);
        k_colsoftmax<<<g, 256, 0, stream>>>(S);
    }
    // coefficients in CSR order (needs S)
    k_csrcoef<<<(E_ + 255) / 256, 256, 0, stream>>>(csrRow, csrCol, dis, S, csrNorm, csrAttn);
    k_diag<<<(B_ * N_ + 255) / 256, 256, 0, stream>>>(S, diagS);
    // chebyshev propagation (gather, no atomics)
    k_tx0<<<(B_ * N_ * F_ * T_ + 255) / 256, 256, 0, stream>>>(X, diagS, Tx0);
    k_gprop<<<B_ * N_, 192, 0, stream>>>(Tx0, nullptr, Tx1, csrAttn, csrCol, rowPtr, 1, 1.0f, 0);
    k_gprop<<<B_ * N_, 192, 0, stream>>>(Tx1, Tx0, Tx2, csrNorm, csrCol, rowPtr, 0, 2.0f, 1);
    k_cheb<<<B_ * N_, 256, 0, stream>>>(Tx0, Tx1, Tx2, chW, chb, Xhat);
    // fused time conv + residual + layernorm
    k_final<<<B_ * N_ / NPER_, 256, 0, stream>>>(Xhat, X, tw, tb, rw, rb, lng, lnb, out);
}

// Round 4
// 1159.553 us; speedup vs baseline: 3.8115x; 1.6142x over previous
//
#include <hip/hip_runtime.h>
#include <math.h>

#define B_ 8
#define N_ 1024
#define F_ 32
#define T_ 24
#define E_ 16384
#define CC_ 64
#define CT_ 64
#define LN_EPS_ 1e-5f

// ---------------- temporal attention ----------------

// lhs_tf[b,t,f] (stored [b][t*32+f]) = sum_n X[b,n,f,t] * U1[n]
// block: (b, 64-n chunk); thread tid<768 reads X[site*768+tid] coalesced.
__global__ __launch_bounds__(768) void k_lhs2(const float* __restrict__ X,
                                              const float* __restrict__ U1,
                                              float* __restrict__ out) {
    __shared__ float su[64];
    int b = blockIdx.x >> 4;
    int n0 = (blockIdx.x & 15) * 64;
    int tid = threadIdx.x;
    if (tid < 64) su[tid] = U1[n0 + tid];
    __syncthreads();
    float acc = 0.f;
    const float* xp = X + ((size_t)b * N_ + n0) * 768 + tid;
#pragma unroll 8
    for (int i = 0; i < 64; ++i) acc += xp[(size_t)i * 768] * su[i];
    int f = tid / 24, t = tid - (tid / 24) * 24;
    atomicAdd(&out[b * 768 + t * 32 + f], acc);
}

// lhsN[b,t,n] = sum_f lhs_tf[b,t,f] * U2[f,n]
__global__ void k_lhsN(const float* __restrict__ lhs_tf, const float* __restrict__ U2,
                       float* __restrict__ out) {
    int idx = blockIdx.x * 256 + threadIdx.x;
    if (idx >= B_ * T_ * N_) return;
    int n = idx % N_;
    int bt = idx / N_;
    float acc = 0.f;
#pragma unroll
    for (int f = 0; f < F_; ++f) acc += lhs_tf[bt * F_ + f] * U2[(size_t)f * N_ + n];
    out[idx] = acc;
}

// rhsT[b,n,t] = sum_f U3[f] * X[b,n,f,t]
__global__ void k_rhsT(const float* __restrict__ X, const float* __restrict__ U3,
                       float* __restrict__ out) {
    int idx = blockIdx.x * 256 + threadIdx.x;
    if (idx >= B_ * N_ * T_) return;
    int t = idx % T_;
    int n = (idx / T_) % N_;
    int b = idx / (N_ * T_);
    const float* xp = X + ((size_t)(b * N_ + n) * F_) * T_ + t;
    float acc = 0.f;
#pragma unroll
    for (int f = 0; f < F_; ++f) acc += U3[f] * xp[f * T_];
    out[idx] = acc;
}

// transpose rhsT [b,n,t] -> rhsTT [b,t,n]
__global__ __launch_bounds__(256) void k_transp(const float* __restrict__ in,
                                                float* __restrict__ outp) {
    __shared__ float s[64 * 25];
    int b = blockIdx.x >> 4;
    int n0 = (blockIdx.x & 15) * 64;
    int tid = threadIdx.x;
    const float* ip = in + ((size_t)b * N_ + n0) * 24;
    for (int q = tid; q < 1536; q += 256) s[(q / 24) * 25 + (q % 24)] = ip[q];
    __syncthreads();
    for (int q = tid; q < 1536; q += 256) {
        int t = q >> 6, n = q & 63;
        outp[((size_t)b * 24 + t) * N_ + n0 + n] = s[n * 25 + t];
    }
}

// sig[b,i,j] = sigmoid( lhsN[b,i,:] . rhsTT[b,j,:] + be[i,j] ); one wave per (b,i,j)
__global__ __launch_bounds__(64) void k_edot(const float* __restrict__ lhsN,
                                             const float* __restrict__ rhsTT,
                                             const float* __restrict__ be,
                                             float* __restrict__ sig) {
    int blk = blockIdx.x;
    int b = blk / 576, ij = blk % 576;
    int i = ij / 24, j = ij % 24;
    int lane = threadIdx.x;
    const float* lp = lhsN + ((size_t)b * 24 + i) * N_;
    const float* rp = rhsTT + ((size_t)b * 24 + j) * N_;
    float acc = 0.f;
#pragma unroll
    for (int n = lane; n < N_; n += 64) acc += lp[n] * rp[n];
    for (int off = 32; off > 0; off >>= 1) acc += __shfl_xor(acc, off);
    if (lane == 0) sig[blk] = 1.f / (1.f + expf(-(acc + be[ij])));
}

// Escore = Ve @ sig, then softmax over rows -> Eatt
__global__ __launch_bounds__(576) void k_eatt2(const float* __restrict__ sig,
                                               const float* __restrict__ Ve,
                                               float* __restrict__ Eatt) {
    __shared__ float ss[T_ * T_];
    __shared__ float esc[T_ * T_];
    int b = blockIdx.x;
    int tid = threadIdx.x;
    ss[tid] = sig[b * 576 + tid];
    __syncthreads();
    int i = tid / T_, j = tid % T_;
    {
        float acc = 0.f;
#pragma unroll
        for (int m = 0; m < T_; ++m) acc += Ve[i * T_ + m] * ss[m * T_ + j];
        esc[tid] = acc;
    }
    __syncthreads();
    if (tid < T_) {
        int jj = tid;
        float mx = -1e30f;
        for (int r = 0; r < T_; ++r) mx = fmaxf(mx, esc[r * T_ + jj]);
        float s = 0.f;
        for (int r = 0; r < T_; ++r) {
            float e = expf(esc[r * T_ + jj] - mx);
            ss[r * T_ + jj] = e;
            s += e;
        }
        float inv = 1.f / s;
        for (int r = 0; r < T_; ++r) Eatt[(size_t)(b * T_ + r) * T_ + jj] = ss[r * T_ + jj] * inv;
    }
}

// Xt[b,nf,t] = sum_k X[b,nf,k] * Eatt[b,k,t]
__global__ void k_xt(const float* __restrict__ X, const float* __restrict__ Eatt,
                     float* __restrict__ Xt) {
    __shared__ float e[T_ * T_];
    const int per_b = N_ * F_ * T_ / 256;  // 3072
    int b = blockIdx.x / per_b;
    int tid = threadIdx.x;
    for (int q = tid; q < T_ * T_; q += 256) e[q] = Eatt[(size_t)b * T_ * T_ + q];
    __syncthreads();
    int off = (blockIdx.x % per_b) * 256 + tid;
    int t = off % T_;
    int nf = off / T_;
    const float* xr = X + ((size_t)b * N_ * F_ + nf) * T_;
    float acc = 0.f;
#pragma unroll
    for (int k = 0; k < T_; ++k) acc += xr[k] * e[k * T_ + t];
    Xt[((size_t)b * N_ * F_ + nf) * T_ + t] = acc;
}

// ---------------- spatial attention ----------------

// slhsF[b,n,f] = sum_t Xt[b,n,f,t] * W1[t]
__global__ void k_slhsF(const float* __restrict__ Xt, const float* __restrict__ W1,
                        float* __restrict__ out) {
    int idx = blockIdx.x * 256 + threadIdx.x;
    if (idx >= B_ * N_ * F_) return;
    const float* xp = Xt + (size_t)idx * T_;
    float acc = 0.f;
#pragma unroll
    for (int t = 0; t < T_; ++t) acc += xp[t] * W1[t];
    out[idx] = acc;
}

// slhs[b,n,t] = sum_f slhsF[b,n,f] * W2[f,t]
__global__ void k_slhs(const float* __restrict__ slhsF, const float* __restrict__ W2,
                       float* __restrict__ out) {
    int idx = blockIdx.x * 256 + threadIdx.x;
    if (idx >= B_ * N_ * T_) return;
    int t = idx % T_;
    int bn = idx / T_;
    float acc = 0.f;
#pragma unroll
    for (int f = 0; f < F_; ++f) acc += slhsF[(size_t)bn * F_ + f] * W2[f * T_ + t];
    out[idx] = acc;
}

// srhs[b,t,n] = sum_f W3[f] * Xt[b,n,f,t]
__global__ void k_srhs(const float* __restrict__ Xt, const float* __restrict__ W3,
                       float* __restrict__ out) {
    int idx = blockIdx.x * 256 + threadIdx.x;
    if (idx >= B_ * N_ * T_) return;
    int t = idx % T_;
    int n = (idx / T_) % N_;
    int b = idx / (N_ * T_);
    const float* xp = Xt + ((size_t)(b * N_ + n) * F_) * T_ + t;
    float acc = 0.f;
#pragma unroll
    for (int f = 0; f < F_; ++f) acc += W3[f] * xp[f * T_];
    out[((size_t)b * T_ + t) * N_ + n] = acc;
}

// Psig[b,i,k] = sigmoid( sum_t slhs[b,i,t]*srhs[b,t,k] + bs[i,k] )
__global__ void k_psig(const float* __restrict__ slhs, const float* __restrict__ srhs,
                       const float* __restrict__ bs, float* __restrict__ Psig) {
    int idx = blockIdx.x * 256 + threadIdx.x;
    if (idx >= B_ * N_ * N_) return;
    int k = idx % N_;
    int i = (idx / N_) % N_;
    int b = idx / (N_ * N_);
    const float* lp = slhs + (size_t)(b * N_ + i) * T_;
    const float* rp = srhs + (size_t)b * T_ * N_ + k;
    float acc = bs[(size_t)i * N_ + k];
#pragma unroll
    for (int t = 0; t < T_; ++t) acc += lp[t] * rp[(size_t)t * N_];
    Psig[idx] = 1.f / (1.f + expf(-acc));
}

// Sc[b] = Vs @ Psig[b]   (64x64 tile, 4x4 per thread)
__global__ __launch_bounds__(256) void k_sscore(const float* __restrict__ Vs,
                                                const float* __restrict__ P,
                                                float* __restrict__ Sc) {
    const int b = blockIdx.z;
    const int bm = blockIdx.y * 64, bn = blockIdx.x * 64;
    __shared__ float As[16][65];  // [k][m], padded
    __shared__ float Bs[16][64];  // [k][n]
    const float* Pb = P + (size_t)b * N_ * N_;
    float acc[4][4] = {};
    const int tid = threadIdx.x;
    const int tm = (tid >> 4) << 2, tn = (tid & 15) << 2;
    for (int k0 = 0; k0 < N_; k0 += 16) {
        for (int q = tid; q < 1024; q += 256) {
            int m = q >> 4, k = q & 15;
            As[k][m] = Vs[(size_t)(bm + m) * N_ + k0 + k];
        }
        for (int q = tid; q < 1024; q += 256) {
            int k = q >> 6, n2 = q & 63;
            Bs[k][n2] = Pb[(size_t)(k0 + k) * N_ + bn + n2];
        }
        __syncthreads();
#pragma unroll
        for (int k = 0; k < 16; ++k) {
            float a0 = As[k][tm + 0], a1 = As[k][tm + 1], a2 = As[k][tm + 2], a3 = As[k][tm + 3];
            float b0 = Bs[k][tn + 0], b1 = Bs[k][tn + 1], b2 = Bs[k][tn + 2], b3 = Bs[k][tn + 3];
            acc[0][0] += a0 * b0; acc[0][1] += a0 * b1; acc[0][2] += a0 * b2; acc[0][3] += a0 * b3;
            acc[1][0] += a1 * b0; acc[1][1] += a1 * b1; acc[1][2] += a1 * b2; acc[1][3] += a1 * b3;
            acc[2][0] += a2 * b0; acc[2][1] += a2 * b1; acc[2][2] += a2 * b2; acc[2][3] += a2 * b3;
            acc[3][0] += a3 * b0; acc[3][1] += a3 * b1; acc[3][2] += a3 * b2; acc[3][3] += a3 * b3;
        }
        __syncthreads();
    }
    float* Scb = Sc + (size_t)b * N_ * N_;
    for (int i = 0; i < 4; ++i)
        for (int j = 0; j < 4; ++j)
            Scb[(size_t)(bm + tm + i) * N_ + bn + tn + j] = acc[i][j];
}

// in-place softmax over rows (axis=1): one block handles 64 columns of one b
__global__ __launch_bounds__(256) void k_colsoftmax(float* __restrict__ S) {
    int b = blockIdx.y;
    int k = blockIdx.x * 64 + (threadIdx.x & 63);
    int grp = threadIdx.x >> 6;  // 0..3
    float* Sb = S + (size_t)b * N_ * N_;
    __shared__ float red[4][64];
    float mx = -1e30f;
    for (int r = grp; r < N_; r += 4) mx = fmaxf(mx, Sb[(size_t)r * N_ + k]);
    red[grp][threadIdx.x & 63] = mx;
    __syncthreads();
    mx = fmaxf(fmaxf(red[0][threadIdx.x & 63], red[1][threadIdx.x & 63]),
               fmaxf(red[2][threadIdx.x & 63], red[3][threadIdx.x & 63]));
    __syncthreads();
    float s = 0.f;
    for (int r = grp; r < N_; r += 4) s += expf(Sb[(size_t)r * N_ + k] - mx);
    red[grp][threadIdx.x & 63] = s;
    __syncthreads();
    s = red[0][threadIdx.x & 63] + red[1][threadIdx.x & 63] + red[2][threadIdx.x & 63] +
        red[3][threadIdx.x & 63];
    float inv = 1.f / s;
    for (int r = grp; r < N_; r += 4) {
        size_t idx = (size_t)r * N_ + k;
        Sb[idx] = expf(Sb[idx] - mx) * inv;
    }
}

// ---------------- graph: CSR build + normalization ----------------

__global__ void k_count(const int* __restrict__ rowI, const int* __restrict__ colI,
                        int* __restrict__ cnt, float* __restrict__ deg) {
    int e = blockIdx.x * 256 + threadIdx.x;
    if (e >= E_) return;
    int r = rowI[e];
    atomicAdd(&cnt[r], 1);
    if (r != colI[e]) atomicAdd(&deg[r], 1.0f);
}

__global__ __launch_bounds__(1024) void k_scan(const int* __restrict__ cnt,
                                               const float* __restrict__ deg,
                                               int* __restrict__ rowPtr,
                                               int* __restrict__ fillPos,
                                               float* __restrict__ dis) {
    __shared__ int s[N_];
    int tid = threadIdx.x;
    int my = cnt[tid];
    s[tid] = my;
    __syncthreads();
    for (int off = 1; off < N_; off <<= 1) {
        int v = 0;
        if (tid >= off) v = s[tid - off];
        __syncthreads();
        s[tid] += v;
        __syncthreads();
    }
    rowPtr[tid + 1] = s[tid];
    if (tid == 0) rowPtr[0] = 0;
    fillPos[tid] = s[tid] - my;
    float d = deg[tid];
    dis[tid] = d > 0.f ? rsqrtf(d) : 0.f;
}

__global__ void k_fill(const int* __restrict__ rowI, const int* __restrict__ colI,
                       int* __restrict__ fillPos, int* __restrict__ csrRow,
                       int* __restrict__ csrCol) {
    int e = blockIdx.x * 256 + threadIdx.x;
    if (e >= E_) return;
    int r = rowI[e];
    int pos = atomicAdd(&fillPos[r], 1);
    csrRow[pos] = r;
    csrCol[pos] = colI[e];
}

__global__ void k_csrcoef(const int* __restrict__ csrRow, const int* __restrict__ csrCol,
                          const float* __restrict__ dis, const float* __restrict__ S,
                          float* __restrict__ csrNorm, float* __restrict__ csrAttn) {
    int p = blockIdx.x * 256 + threadIdx.x;
    if (p >= E_) return;
    int r = csrRow[p], c = csrCol[p];
    float nm = (r == c) ? 0.f : -dis[r] * dis[c];
    csrNorm[p] = nm;
    size_t off = (size_t)r * N_ + c;
#pragma unroll
    for (int b = 0; b < B_; ++b)
        csrAttn[(size_t)b * E_ + p] = nm * S[(size_t)b * N_ * N_ + off];
}

__global__ void k_diag(const float* __restrict__ S, float* __restrict__ diagS) {
    int idx = blockIdx.x * 256 + threadIdx.x;
    if (idx >= B_ * N_) return;
    int n = idx % N_;
    int b = idx / N_;
    diagS[idx] = S[(size_t)b * N_ * N_ + (size_t)n * N_ + n];
}

// Tx0 = diagS * X
__global__ void k_tx0(const float* __restrict__ X, const float* __restrict__ diagS,
                      float* __restrict__ Tx0) {
    int idx = blockIdx.x * 256 + threadIdx.x;
    if (idx >= B_ * N_ * F_ * T_) return;
    int bn = idx / (F_ * T_);
    Tx0[idx] = diagS[bn] * X[idx];
}

// gather propagation: Tout[b,n,:] = scale * sum_{p in csr row n} coef[p] * Tin[b,csrCol[p],:]
__global__ __launch_bounds__(192) void k_gprop(const float* __restrict__ Tin,
                                               const float* __restrict__ Tsub,
                                               float* __restrict__ Tout,
                                               const float* __restrict__ coef,
                                               const int* __restrict__ csrCol,
                                               const int* __restrict__ rowPtr,
                                               int perB, float scale, int hasSub) {
    int blk = blockIdx.x;
    int b = blk & 7;
    int n = blk >> 3;
    int tid = threadIdx.x;
    int s = rowPtr[n], e = rowPtr[n + 1];
    const float* cbase = coef + (perB ? (size_t)b * E_ : 0);
    float ax = 0.f, ay = 0.f, az = 0.f, aw = 0.f;
    for (int p = s; p < e; ++p) {
        float cf = cbase[p];
        const float4 v =
            *(const float4*)(Tin + ((size_t)(b * N_ + csrCol[p]) * (F_ * T_)) + tid * 4);
        ax += cf * v.x;
        ay += cf * v.y;
        az += cf * v.z;
        aw += cf * v.w;
    }
    size_t obase = (size_t)(b * N_ + n) * (F_ * T_) + tid * 4;
    float4 r;
    r.x = ax * scale;
    r.y = ay * scale;
    r.z = az * scale;
    r.w = aw * scale;
    if (hasSub) {
        const float4 u = *(const float4*)(Tsub + obase);
        r.x -= u.x;
        r.y -= u.y;
        r.z -= u.z;
        r.w -= u.w;
    }
    *(float4*)(Tout + obase) = r;
}

// Xhat[b,n,c,t] = relu( sum_k sum_f Txk[b,n,f,t] * chW[k,f,c] + chb[c] )
__global__ __launch_bounds__(256) void k_cheb(const float* __restrict__ Tx0,
                                              const float* __restrict__ Tx1,
                                              const float* __restrict__ Tx2,
                                              const float* __restrict__ W,
                                              const float* __restrict__ bias,
                                              float* __restrict__ Xhat) {
    __shared__ float s0[F_ * T_], s1[F_ * T_], s2[F_ * T_];
    __shared__ float sw[3 * F_ * CC_];
    int bn = blockIdx.x;
    size_t base = (size_t)bn * F_ * T_;
    int tid = threadIdx.x;
    for (int q = tid; q < F_ * T_; q += 256) {
        s0[q] = Tx0[base + q];
        s1[q] = Tx1[base + q];
        s2[q] = Tx2[base + q];
    }
    for (int q = tid; q < 3 * F_ * CC_; q += 256) sw[q] = W[q];
    __syncthreads();
    for (int q = tid; q < CC_ * T_; q += 256) {
        int c = q / T_, t = q % T_;
        float acc = bias[c];
#pragma unroll
        for (int f = 0; f < F_; ++f) {
            acc += s0[f * T_ + t] * sw[(0 * F_ + f) * CC_ + c];
            acc += s1[f * T_ + t] * sw[(1 * F_ + f) * CC_ + c];
            acc += s2[f * T_ + t] * sw[(2 * F_ + f) * CC_ + c];
        }
        Xhat[(size_t)bn * CC_ * T_ + q] = fmaxf(acc, 0.f);
    }
}

// ---------------- fused conv GEMM + layernorm ----------------

// rows g = (b*N+n)*24 + t; cols co; K = 192 (im2col Xhat) + 32 (residual X)
// Z[g,co] = relu( sum_k A[g,k]*B[k,co] + tb[co] + rb[co] )
__global__ __launch_bounds__(256) void k_conv(const float* __restrict__ Xh,
                                              const float* __restrict__ X,
                                              const float* __restrict__ tw,
                                              const float* __restrict__ rw,
                                              const float* __restrict__ tb,
                                              const float* __restrict__ rb,
                                              float* __restrict__ Z) {
    __shared__ float As[16][65];
    __shared__ float Bs[16][64];
    const int row0 = blockIdx.x * 64;
    const int tid = threadIdx.x;
    const int tm = (tid >> 4) << 2, tn = (tid & 15) << 2;
    float acc[4][4] = {};
    for (int k0 = 0; k0 < 224; k0 += 16) {
#pragma unroll
        for (int it = 0; it < 4; ++it) {
            int q = tid + it * 256;
            int m = q & 63, k = q >> 6;
            int kk = k0 + k;
            // A element
            int g = row0 + m;
            int site = g / 24;
            int t = g - site * 24;
            float v, w;
            if (kk < 192) {
                int ci = kk / 3, dt = kk - ci * 3;
                int tt = t + dt - 1;
                v = (tt >= 0 && tt < 24) ? Xh[(size_t)site * 1536 + ci * 24 + tt] : 0.f;
                w = tw[(m * CC_ + ci) * 3 + dt];  // m == co for B tile
            } else {
                int f = kk - 192;
                v = X[(size_t)site * 768 + f * 24 + t];
                w = rw[m * F_ + (kk - 192)];
            }
            As[k][m] = v;
            Bs[k][m] = w;
        }
        __syncthreads();
#pragma unroll
        for (int k = 0; k < 16; ++k) {
            float a0 = As[k][tm + 0], a1 = As[k][tm + 1], a2 = As[k][tm + 2], a3 = As[k][tm + 3];
            float b0 = Bs[k][tn + 0], b1 = Bs[k][tn + 1], b2 = Bs[k][tn + 2], b3 = Bs[k][tn + 3];
            acc[0][0] += a0 * b0; acc[0][1] += a0 * b1; acc[0][2] += a0 * b2; acc[0][3] += a0 * b3;
            acc[1][0] += a1 * b0; acc[1][1] += a1 * b1; acc[1][2] += a1 * b2; acc[1][3] += a1 * b3;
            acc[2][0] += a2 * b0; acc[2][1] += a2 * b1; acc[2][2] += a2 * b2; acc[2][3] += a2 * b3;
            acc[3][0] += a3 * b0; acc[3][1] += a3 * b1; acc[3][2] += a3 * b2; acc[3][3] += a3 * b3;
        }
        __syncthreads();
    }
#pragma unroll
    for (int i = 0; i < 4; ++i)
#pragma unroll
        for (int j = 0; j < 4; ++j) {
            int g = row0 + tm + i;
            int co = tn + j;
            Z[(size_t)g * 64 + co] = fmaxf(acc[i][j] + tb[co] + rb[co], 0.f);
        }
}

// LN over co (64) per (site,t) row of Z[site*1536 + t*64 + co]; write out[site*1536+co*24+t]
__global__ __launch_bounds__(256) void k_ln(const float* __restrict__ Z,
                                            const float* __restrict__ g,
                                            const float* __restrict__ bb,
                                            float* __restrict__ out) {
    __shared__ float s_z[64 * 25];
    int site = blockIdx.x;
    int tid = threadIdx.x;
    int co = tid & 63, w = tid >> 6;
    float gg = g[co], bg = bb[co];
    for (int t = w; t < 24; t += 4) {
        float z = Z[(size_t)site * 1536 + t * 64 + co];
        float s1 = z, s2 = z * z;
        for (int off = 32; off > 0; off >>= 1) {
            s1 += __shfl_xor(s1, off);
            s2 += __shfl_xor(s2, off);
        }
        float mu = s1 * (1.f / 64.f);
        float var = s2 * (1.f / 64.f) - mu * mu;
        s_z[co * 25 + t] = (z - mu) * rsqrtf(var + LN_EPS_) * gg + bg;
    }
    __syncthreads();
    for (int q = tid; q < 1536; q += 256)
        out[(size_t)site * 1536 + q] = s_z[(q / 24) * 25 + (q % 24)];
}

extern "C" void kernel_launch(void* const* d_in, const int* in_sizes, int n_in,
                              void* d_out, int out_size, void* d_ws, size_t ws_size,
                              hipStream_t stream) {
    const float* X = (const float*)d_in[0];
    const int* ei = (const int*)d_in[1];
    const float* U1 = (const float*)d_in[2];
    const float* U2 = (const float*)d_in[3];
    const float* U3 = (const float*)d_in[4];
    const float* be = (const float*)d_in[5];
    const float* Ve = (const float*)d_in[6];
    const float* W1 = (const float*)d_in[7];
    const float* W2 = (const float*)d_in[8];
    const float* W3 = (const float*)d_in[9];
    const float* bs = (const float*)d_in[10];
    const float* Vs = (const float*)d_in[11];
    const float* chW = (const float*)d_in[12];
    const float* chb = (const float*)d_in[13];
    const float* tw = (const float*)d_in[14];
    const float* tb = (const float*)d_in[15];
    const float* rw = (const float*)d_in[16];
    const float* rb = (const float*)d_in[17];
    const float* lng = (const float*)d_in[18];
    const float* lnb = (const float*)d_in[19];
    float* out = (float*)d_out;
    float* ws = (float*)d_ws;

    size_t o = 0;
    float* lhs_tf = ws + o; o += B_ * T_ * F_;
    float* lhsN  = ws + o; o += (size_t)B_ * T_ * N_;
    float* rhsT  = ws + o; o += (size_t)B_ * N_ * T_;
    float* rhsTT = ws + o; o += (size_t)B_ * T_ * N_;
    float* sigE  = ws + o; o += B_ * T_ * T_;
    float* Eatt  = ws + o; o += B_ * T_ * T_;
    float* slhsF = ws + o; o += (size_t)B_ * N_ * F_;
    float* slhs  = ws + o; o += (size_t)B_ * N_ * T_;
    float* srhs  = ws + o; o += (size_t)B_ * T_ * N_;
    float* deg   = ws + o; o += N_;
    float* dis   = ws + o; o += N_;
    float* diagS = ws + o; o += B_ * N_;
    float* csrNorm = ws + o; o += E_;
    float* csrAttn = ws + o; o += (size_t)B_ * E_;
    int* cnt     = (int*)(ws + o); o += N_;
    int* rowPtr  = (int*)(ws + o); o += N_ + 1;
    int* fillPos = (int*)(ws + o); o += N_;
    int* csrRow  = (int*)(ws + o); o += E_;
    int* csrCol  = (int*)(ws + o); o += E_;
    float* Xt    = ws + o; o += (size_t)B_ * N_ * F_ * T_;  // later reused as Tx2
    float* Psig  = ws + o; o += (size_t)B_ * N_ * N_;       // later Tx0, then Zbuf
    float* S     = ws + o; o += (size_t)B_ * N_ * N_;       // later Tx1, then Zbuf tail
    float* Xhat  = ws + o; o += (size_t)B_ * N_ * CC_ * T_;
    float* Tx0 = Psig;
    float* Tx1 = S;
    float* Tx2 = Xt;
    float* Zbuf = Psig;  // 12.58M floats, overlays Psig+S (both dead after k_cheb)
    const int* rowI = ei;
    const int* colI = ei + E_;

    // CSR build (independent of attention pipeline)
    hipMemsetAsync(cnt, 0, N_ * sizeof(int), stream);
    hipMemsetAsync(deg, 0, N_ * sizeof(float), stream);
    k_count<<<(E_ + 255) / 256, 256, 0, stream>>>(rowI, colI, cnt, deg);
    k_scan<<<1, 1024, 0, stream>>>(cnt, deg, rowPtr, fillPos, dis);
    k_fill<<<(E_ + 255) / 256, 256, 0, stream>>>(rowI, colI, fillPos, csrRow, csrCol);

    // temporal attention
    hipMemsetAsync(lhs_tf, 0, B_ * T_ * F_ * sizeof(float), stream);
    k_lhs2<<<B_ * 16, 768, 0, stream>>>(X, U1, lhs_tf);
    k_lhsN<<<(B_ * T_ * N_ + 255) / 256, 256, 0, stream>>>(lhs_tf, U2, lhsN);
    k_rhsT<<<(B_ * N_ * T_ + 255) / 256, 256, 0, stream>>>(X, U3, rhsT);
    k_transp<<<B_ * 16, 256, 0, stream>>>(rhsT, rhsTT);
    k_edot<<<B_ * T_ * T_, 64, 0, stream>>>(lhsN, rhsTT, be, sigE);
    k_eatt2<<<B_, 576, 0, stream>>>(sigE, Ve, Eatt);
    k_xt<<<B_ * (N_ * F_ * T_ / 256), 256, 0, stream>>>(X, Eatt, Xt);
    // spatial attention
    k_slhsF<<<(B_ * N_ * F_ + 255) / 256, 256, 0, stream>>>(Xt, W1, slhsF);
    k_slhs<<<(B_ * N_ * T_ + 255) / 256, 256, 0, stream>>>(slhsF, W2, slhs);
    k_srhs<<<(B_ * N_ * T_ + 255) / 256, 256, 0, stream>>>(Xt, W3, srhs);
    k_psig<<<(B_ * N_ * N_ + 255) / 256, 256, 0, stream>>>(slhs, srhs, bs, Psig);
    {
        dim3 g(N_ / 64, N_ / 64, B_);
        k_sscore<<<g, 256, 0, stream>>>(Vs, Psig, S);
    }
    {
        dim3 g(N_ / 64, B_);
        k_colsoftmax<<<g, 256, 0, stream>>>(S);
    }
    // coefficients in CSR order (needs S)
    k_csrcoef<<<(E_ + 255) / 256, 256, 0, stream>>>(csrRow, csrCol, dis, S, csrNorm, csrAttn);
    k_diag<<<(B_ * N_ + 255) / 256, 256, 0, stream>>>(S, diagS);
    // chebyshev propagation (gather, no atomics)
    k_tx0<<<(B_ * N_ * F_ * T_ + 255) / 256, 256, 0, stream>>>(X, diagS, Tx0);
    k_gprop<<<B_ * N_, 192, 0, stream>>>(Tx0, nullptr, Tx1, csrAttn, csrCol, rowPtr, 1, 1.0f, 0);
    k_gprop<<<B_ * N_, 192, 0, stream>>>(Tx1, Tx0, Tx2, csrNorm, csrCol, rowPtr, 0, 2.0f, 1);
    k_cheb<<<B_ * N_, 256, 0, stream>>>(Tx0, Tx1, Tx2, chW, chb, Xhat);
    // fused time conv + residual as GEMM, then layernorm
    k_conv<<<(B_ * N_ * T_) / 64, 256, 0, stream>>>(Xhat, X, tw, rw, tb, rb, Zbuf);
    k_ln<<<B_ * N_, 256, 0, stream>>>(Zbuf, lng, lnb, out);
}

// Round 5
// 827.319 us; speedup vs baseline: 5.3421x; 1.4016x over previous
//
#include <hip/hip_runtime.h>
#include <hip/hip_bf16.h>
#include <math.h>

#define B_ 8
#define N_ 1024
#define F_ 32
#define T_ 24
#define E_ 16384
#define CC_ 64
#define CT_ 64
#define LN_EPS_ 1e-5f

typedef __attribute__((ext_vector_type(8))) short bf16x8;
typedef __attribute__((ext_vector_type(4))) float f32x4;

__device__ __forceinline__ short f2bf(float f) {
    union { float f; unsigned u; } v; v.f = f;
    unsigned r = v.u + 0x7fffu + ((v.u >> 16) & 1u);  // RNE
    return (short)(r >> 16);
}

// ---------------- temporal attention ----------------

// lhs_tf[b,t,f] (stored [b][t*32+f]) = sum_n X[b,n,f,t] * U1[n]
__global__ __launch_bounds__(768) void k_lhs2(const float* __restrict__ X,
                                              const float* __restrict__ U1,
                                              float* __restrict__ out) {
    __shared__ float su[64];
    int b = blockIdx.x >> 4;
    int n0 = (blockIdx.x & 15) * 64;
    int tid = threadIdx.x;
    if (tid < 64) su[tid] = U1[n0 + tid];
    __syncthreads();
    float acc = 0.f;
    const float* xp = X + ((size_t)b * N_ + n0) * 768 + tid;
#pragma unroll 8
    for (int i = 0; i < 64; ++i) acc += xp[(size_t)i * 768] * su[i];
    int f = tid / 24, t = tid - (tid / 24) * 24;
    atomicAdd(&out[b * 768 + t * 32 + f], acc);
}

// lhsN[b,t,n] = sum_f lhs_tf[b,t,f] * U2[f,n]
__global__ void k_lhsN(const float* __restrict__ lhs_tf, const float* __restrict__ U2,
                       float* __restrict__ out) {
    int idx = blockIdx.x * 256 + threadIdx.x;
    if (idx >= B_ * T_ * N_) return;
    int n = idx % N_;
    int bt = idx / N_;
    float acc = 0.f;
#pragma unroll
    for (int f = 0; f < F_; ++f) acc += lhs_tf[bt * F_ + f] * U2[(size_t)f * N_ + n];
    out[idx] = acc;
}

// rhsT[b,n,t] = sum_f U3[f] * X[b,n,f,t]
__global__ void k_rhsT(const float* __restrict__ X, const float* __restrict__ U3,
                       float* __restrict__ out) {
    int idx = blockIdx.x * 256 + threadIdx.x;
    if (idx >= B_ * N_ * T_) return;
    int t = idx % T_;
    int n = (idx / T_) % N_;
    int b = idx / (N_ * T_);
    const float* xp = X + ((size_t)(b * N_ + n) * F_) * T_ + t;
    float acc = 0.f;
#pragma unroll
    for (int f = 0; f < F_; ++f) acc += U3[f] * xp[f * T_];
    out[idx] = acc;
}

// transpose rhsT [b,n,t] -> rhsTT [b,t,n]
__global__ __launch_bounds__(256) void k_transp(const float* __restrict__ in,
                                                float* __restrict__ outp) {
    __shared__ float s[64 * 25];
    int b = blockIdx.x >> 4;
    int n0 = (blockIdx.x & 15) * 64;
    int tid = threadIdx.x;
    const float* ip = in + ((size_t)b * N_ + n0) * 24;
    for (int q = tid; q < 1536; q += 256) s[(q / 24) * 25 + (q % 24)] = ip[q];
    __syncthreads();
    for (int q = tid; q < 1536; q += 256) {
        int t = q >> 6, n = q & 63;
        outp[((size_t)b * 24 + t) * N_ + n0 + n] = s[n * 25 + t];
    }
}

// sig[b,i,j] = sigmoid( lhsN[b,i,:] . rhsTT[b,j,:] + be[i,j] ); one wave per (b,i,j)
__global__ __launch_bounds__(64) void k_edot(const float* __restrict__ lhsN,
                                             const float* __restrict__ rhsTT,
                                             const float* __restrict__ be,
                                             float* __restrict__ sig) {
    int blk = blockIdx.x;
    int b = blk / 576, ij = blk % 576;
    int i = ij / 24, j = ij % 24;
    int lane = threadIdx.x;
    const float* lp = lhsN + ((size_t)b * 24 + i) * N_;
    const float* rp = rhsTT + ((size_t)b * 24 + j) * N_;
    float acc = 0.f;
#pragma unroll
    for (int n = lane; n < N_; n += 64) acc += lp[n] * rp[n];
    for (int off = 32; off > 0; off >>= 1) acc += __shfl_xor(acc, off);
    if (lane == 0) sig[blk] = 1.f / (1.f + expf(-(acc + be[ij])));
}

// Escore = Ve @ sig, then softmax over rows -> Eatt
__global__ __launch_bounds__(576) void k_eatt2(const float* __restrict__ sig,
                                               const float* __restrict__ Ve,
                                               float* __restrict__ Eatt) {
    __shared__ float ss[T_ * T_];
    __shared__ float esc[T_ * T_];
    int b = blockIdx.x;
    int tid = threadIdx.x;
    ss[tid] = sig[b * 576 + tid];
    __syncthreads();
    int i = tid / T_, j = tid % T_;
    {
        float acc = 0.f;
#pragma unroll
        for (int m = 0; m < T_; ++m) acc += Ve[i * T_ + m] * ss[m * T_ + j];
        esc[tid] = acc;
    }
    __syncthreads();
    if (tid < T_) {
        int jj = tid;
        float mx = -1e30f;
        for (int r = 0; r < T_; ++r) mx = fmaxf(mx, esc[r * T_ + jj]);
        float s = 0.f;
        for (int r = 0; r < T_; ++r) {
            float e = expf(esc[r * T_ + jj] - mx);
            ss[r * T_ + jj] = e;
            s += e;
        }
        float inv = 1.f / s;
        for (int r = 0; r < T_; ++r) Eatt[(size_t)(b * T_ + r) * T_ + jj] = ss[r * T_ + jj] * inv;
    }
}

// Xt[b,nf,t] = sum_k X[b,nf,k] * Eatt[b,k,t]
__global__ void k_xt(const float* __restrict__ X, const float* __restrict__ Eatt,
                     float* __restrict__ Xt) {
    __shared__ float e[T_ * T_];
    const int per_b = N_ * F_ * T_ / 256;  // 3072
    int b = blockIdx.x / per_b;
    int tid = threadIdx.x;
    for (int q = tid; q < T_ * T_; q += 256) e[q] = Eatt[(size_t)b * T_ * T_ + q];
    __syncthreads();
    int off = (blockIdx.x % per_b) * 256 + tid;
    int t = off % T_;
    int nf = off / T_;
    const float* xr = X + ((size_t)b * N_ * F_ + nf) * T_;
    float acc = 0.f;
#pragma unroll
    for (int k = 0; k < T_; ++k) acc += xr[k] * e[k * T_ + t];
    Xt[((size_t)b * N_ * F_ + nf) * T_ + t] = acc;
}

// ---------------- spatial attention ----------------

// slhsF[b,n,f] = sum_t Xt[b,n,f,t] * W1[t]
__global__ void k_slhsF(const float* __restrict__ Xt, const float* __restrict__ W1,
                        float* __restrict__ out) {
    int idx = blockIdx.x * 256 + threadIdx.x;
    if (idx >= B_ * N_ * F_) return;
    const float* xp = Xt + (size_t)idx * T_;
    float acc = 0.f;
#pragma unroll
    for (int t = 0; t < T_; ++t) acc += xp[t] * W1[t];
    out[idx] = acc;
}

// slhs[b,n,t] = sum_f slhsF[b,n,f] * W2[f,t]
__global__ void k_slhs(const float* __restrict__ slhsF, const float* __restrict__ W2,
                       float* __restrict__ out) {
    int idx = blockIdx.x * 256 + threadIdx.x;
    if (idx >= B_ * N_ * T_) return;
    int t = idx % T_;
    int bn = idx / T_;
    float acc = 0.f;
#pragma unroll
    for (int f = 0; f < F_; ++f) acc += slhsF[(size_t)bn * F_ + f] * W2[f * T_ + t];
    out[idx] = acc;
}

// srhs[b,t,n] = sum_f W3[f] * Xt[b,n,f,t]
__global__ void k_srhs(const float* __restrict__ Xt, const float* __restrict__ W3,
                       float* __restrict__ out) {
    int idx = blockIdx.x * 256 + threadIdx.x;
    if (idx >= B_ * N_ * T_) return;
    int t = idx % T_;
    int n = (idx / T_) % N_;
    int b = idx / (N_ * T_);
    const float* xp = Xt + ((size_t)(b * N_ + n) * F_) * T_ + t;
    float acc = 0.f;
#pragma unroll
    for (int f = 0; f < F_; ++f) acc += W3[f] * xp[f * T_];
    out[((size_t)b * T_ + t) * N_ + n] = acc;
}

// Psig tile kernel: Psig[b,i,k] = sigmoid(slhs[b,i,:].srhs[b,:,k] + bs[i,k])  (f32)
// also writes PsigT[b,k,i] in bf16 for the MFMA B-operand.
__global__ __launch_bounds__(256) void k_psig2(const float* __restrict__ slhs,
                                               const float* __restrict__ srhs,
                                               const float* __restrict__ bs,
                                               float* __restrict__ Psig,
                                               __hip_bfloat16* __restrict__ PsigT) {
    __shared__ float sl[64][24];
    __shared__ float sr[24][64];
    __shared__ short st[64][72];
    int b = blockIdx.z;
    int i0 = blockIdx.y * 64, k0 = blockIdx.x * 64;
    int tid = threadIdx.x;
    // load slhs tile (contiguous 1536 floats) and srhs tile (24 rows of 64)
    {
        const float* sp = slhs + ((size_t)b * N_ + i0) * 24;
#pragma unroll
        for (int it = 0; it < 6; ++it) {
            int q = tid + it * 256;
            sl[q / 24][q % 24] = sp[q];
        }
        const float* rp = srhs + (size_t)b * 24 * N_ + k0;
#pragma unroll
        for (int it = 0; it < 6; ++it) {
            int q = tid + it * 256;
            sr[q >> 6][q & 63] = rp[(size_t)(q >> 6) * N_ + (q & 63)];
        }
    }
    __syncthreads();
    int ib = (tid >> 4) * 4;   // 0..60
    int kb = (tid & 15) * 4;   // 0..60
    float acc[4][4];
#pragma unroll
    for (int a = 0; a < 4; ++a) {
        const float4 bv = *(const float4*)(bs + (size_t)(i0 + ib + a) * N_ + k0 + kb);
        acc[a][0] = bv.x; acc[a][1] = bv.y; acc[a][2] = bv.z; acc[a][3] = bv.w;
    }
#pragma unroll
    for (int t = 0; t < 24; ++t) {
        float r0 = sr[t][kb], r1 = sr[t][kb + 1], r2 = sr[t][kb + 2], r3 = sr[t][kb + 3];
#pragma unroll
        for (int a = 0; a < 4; ++a) {
            float lv = sl[ib + a][t];
            acc[a][0] += lv * r0; acc[a][1] += lv * r1; acc[a][2] += lv * r2; acc[a][3] += lv * r3;
        }
    }
#pragma unroll
    for (int a = 0; a < 4; ++a) {
        float4 o;
        o.x = 1.f / (1.f + expf(-acc[a][0]));
        o.y = 1.f / (1.f + expf(-acc[a][1]));
        o.z = 1.f / (1.f + expf(-acc[a][2]));
        o.w = 1.f / (1.f + expf(-acc[a][3]));
        *(float4*)(Psig + (size_t)((size_t)b * N_ + i0 + ib + a) * N_ + k0 + kb) = o;
        // transpose into LDS as bf16: st[k][i]
        st[kb + 0][ib + a] = f2bf(o.x);
        st[kb + 1][ib + a] = f2bf(o.y);
        st[kb + 2][ib + a] = f2bf(o.z);
        st[kb + 3][ib + a] = f2bf(o.w);
    }
    __syncthreads();
    // write PsigT rows: 64 rows x 64 shorts = 512 16B chunks
    short* op = (short*)PsigT + ((size_t)b * N_ + k0) * N_ + i0;
#pragma unroll
    for (int it = 0; it < 2; ++it) {
        int ch = tid + it * 256;
        int kk = ch >> 3, off = (ch & 7) * 8;
        uint4 u = *(uint4*)&st[kk][off];
        *(uint4*)(op + (size_t)kk * N_ + off) = u;
    }
}

// S[b] = Vs @ Psig[b] via bf16 MFMA. 128x128 tile, 4 waves, BK=32.
// A-frag: lane holds A[i=lane&15][k=(lane>>4)*8 + j]; B-frag: B[k][j=lane&15] same k-run.
__global__ __launch_bounds__(256) void k_smfma(const float* __restrict__ Vs,
                                               const __hip_bfloat16* __restrict__ PsigT,
                                               float* __restrict__ S) {
    __shared__ short Asd[128][40];
    __shared__ short Bsd[128][40];
    const int b = blockIdx.z;
    const int bm = blockIdx.y * 128, bn = blockIdx.x * 128;
    const int tid = threadIdx.x;
    const int lane = tid & 63, wave = tid >> 6;
    const int wr = wave >> 1, wc = wave & 1;
    const int fr = lane & 15, ks = lane >> 4;
    f32x4 acc[4][4] = {};
    const short* PT = (const short*)PsigT + (size_t)b * N_ * N_;
    for (int k0 = 0; k0 < N_; k0 += 32) {
        // stage A: Vs[bm..bm+127][k0..k0+31] f32 -> bf16
#pragma unroll
        for (int it = 0; it < 4; ++it) {
            int q = tid + it * 256;           // 0..1023
            int row = q >> 3, kk = (q & 7) * 4;
            float4 v = *(const float4*)(Vs + (size_t)(bm + row) * N_ + k0 + kk);
            short4 s4;
            s4.x = f2bf(v.x); s4.y = f2bf(v.y); s4.z = f2bf(v.z); s4.w = f2bf(v.w);
            *(short4*)&Asd[row][kk] = s4;
        }
        // stage B: PsigT[bn..bn+127][k0..k0+31] bf16 (16B chunks)
#pragma unroll
        for (int it = 0; it < 2; ++it) {
            int q = tid + it * 256;           // 0..511
            int row = q >> 2, kk = (q & 3) * 8;
            uint4 u = *(const uint4*)(PT + (size_t)(bn + row) * N_ + k0 + kk);
            *(uint4*)&Bsd[row][kk] = u;
        }
        __syncthreads();
        bf16x8 a[4], bf[4];
#pragma unroll
        for (int m = 0; m < 4; ++m) a[m] = *(const bf16x8*)&Asd[wr * 64 + m * 16 + fr][ks * 8];
#pragma unroll
        for (int n = 0; n < 4; ++n) bf[n] = *(const bf16x8*)&Bsd[wc * 64 + n * 16 + fr][ks * 8];
#pragma unroll
        for (int m = 0; m < 4; ++m)
#pragma unroll
            for (int n = 0; n < 4; ++n)
                acc[m][n] = __builtin_amdgcn_mfma_f32_16x16x32_bf16(a[m], bf[n], acc[m][n], 0, 0, 0);
        __syncthreads();
    }
    float* Sb = S + (size_t)b * N_ * N_;
#pragma unroll
    for (int m = 0; m < 4; ++m)
#pragma unroll
        for (int n = 0; n < 4; ++n) {
#pragma unroll
            for (int j = 0; j < 4; ++j) {
                int row = bm + wr * 64 + m * 16 + (lane >> 4) * 4 + j;
                int col = bn + wc * 64 + n * 16 + (lane & 15);
                Sb[(size_t)row * N_ + col] = acc[m][n][j];
            }
        }
}

// in-place softmax over rows (axis=1): one block handles 64 columns of one b
__global__ __launch_bounds__(256) void k_colsoftmax(float* __restrict__ S) {
    int b = blockIdx.y;
    int k = blockIdx.x * 64 + (threadIdx.x & 63);
    int grp = threadIdx.x >> 6;  // 0..3
    float* Sb = S + (size_t)b * N_ * N_;
    __shared__ float red[4][64];
    float mx = -1e30f;
    for (int r = grp; r < N_; r += 4) mx = fmaxf(mx, Sb[(size_t)r * N_ + k]);
    red[grp][threadIdx.x & 63] = mx;
    __syncthreads();
    mx = fmaxf(fmaxf(red[0][threadIdx.x & 63], red[1][threadIdx.x & 63]),
               fmaxf(red[2][threadIdx.x & 63], red[3][threadIdx.x & 63]));
    __syncthreads();
    float s = 0.f;
    for (int r = grp; r < N_; r += 4) s += expf(Sb[(size_t)r * N_ + k] - mx);
    red[grp][threadIdx.x & 63] = s;
    __syncthreads();
    s = red[0][threadIdx.x & 63] + red[1][threadIdx.x & 63] + red[2][threadIdx.x & 63] +
        red[3][threadIdx.x & 63];
    float inv = 1.f / s;
    for (int r = grp; r < N_; r += 4) {
        size_t idx = (size_t)r * N_ + k;
        Sb[idx] = expf(Sb[idx] - mx) * inv;
    }
}

// ---------------- graph: CSR build + normalization ----------------

__global__ void k_count(const int* __restrict__ rowI, const int* __restrict__ colI,
                        int* __restrict__ cnt, float* __restrict__ deg) {
    int e = blockIdx.x * 256 + threadIdx.x;
    if (e >= E_) return;
    int r = rowI[e];
    atomicAdd(&cnt[r], 1);
    if (r != colI[e]) atomicAdd(&deg[r], 1.0f);
}

__global__ __launch_bounds__(1024) void k_scan(const int* __restrict__ cnt,
                                               const float* __restrict__ deg,
                                               int* __restrict__ rowPtr,
                                               int* __restrict__ fillPos,
                                               float* __restrict__ dis) {
    __shared__ int s[N_];
    int tid = threadIdx.x;
    int my = cnt[tid];
    s[tid] = my;
    __syncthreads();
    for (int off = 1; off < N_; off <<= 1) {
        int v = 0;
        if (tid >= off) v = s[tid - off];
        __syncthreads();
        s[tid] += v;
        __syncthreads();
    }
    rowPtr[tid + 1] = s[tid];
    if (tid == 0) rowPtr[0] = 0;
    fillPos[tid] = s[tid] - my;
    float d = deg[tid];
    dis[tid] = d > 0.f ? rsqrtf(d) : 0.f;
}

__global__ void k_fill(const int* __restrict__ rowI, const int* __restrict__ colI,
                       int* __restrict__ fillPos, int* __restrict__ csrRow,
                       int* __restrict__ csrCol) {
    int e = blockIdx.x * 256 + threadIdx.x;
    if (e >= E_) return;
    int r = rowI[e];
    int pos = atomicAdd(&fillPos[r], 1);
    csrRow[pos] = r;
    csrCol[pos] = colI[e];
}

__global__ void k_csrcoef(const int* __restrict__ csrRow, const int* __restrict__ csrCol,
                          const float* __restrict__ dis, const float* __restrict__ S,
                          float* __restrict__ csrNorm, float* __restrict__ csrAttn) {
    int p = blockIdx.x * 256 + threadIdx.x;
    if (p >= E_) return;
    int r = csrRow[p], c = csrCol[p];
    float nm = (r == c) ? 0.f : -dis[r] * dis[c];
    csrNorm[p] = nm;
    size_t off = (size_t)r * N_ + c;
#pragma unroll
    for (int b = 0; b < B_; ++b)
        csrAttn[(size_t)b * E_ + p] = nm * S[(size_t)b * N_ * N_ + off];
}

__global__ void k_diag(const float* __restrict__ S, float* __restrict__ diagS) {
    int idx = blockIdx.x * 256 + threadIdx.x;
    if (idx >= B_ * N_) return;
    int n = idx % N_;
    int b = idx / N_;
    diagS[idx] = S[(size_t)b * N_ * N_ + (size_t)n * N_ + n];
}

// Tx0 = diagS * X
__global__ void k_tx0(const float* __restrict__ X, const float* __restrict__ diagS,
                      float* __restrict__ Tx0) {
    int idx = blockIdx.x * 256 + threadIdx.x;
    if (idx >= B_ * N_ * F_ * T_) return;
    int bn = idx / (F_ * T_);
    Tx0[idx] = diagS[bn] * X[idx];
}

// gather propagation: Tout[b,n,:] = scale * sum_{p in csr row n} coef[p] * Tin[b,csrCol[p],:]
__global__ __launch_bounds__(192) void k_gprop(const float* __restrict__ Tin,
                                               const float* __restrict__ Tsub,
                                               float* __restrict__ Tout,
                                               const float* __restrict__ coef,
                                               const int* __restrict__ csrCol,
                                               const int* __restrict__ rowPtr,
                                               int perB, float scale, int hasSub) {
    int blk = blockIdx.x;
    int b = blk & 7;
    int n = blk >> 3;
    int tid = threadIdx.x;
    int s = rowPtr[n], e = rowPtr[n + 1];
    const float* cbase = coef + (perB ? (size_t)b * E_ : 0);
    float ax = 0.f, ay = 0.f, az = 0.f, aw = 0.f;
    for (int p = s; p < e; ++p) {
        float cf = cbase[p];
        const float4 v =
            *(const float4*)(Tin + ((size_t)(b * N_ + csrCol[p]) * (F_ * T_)) + tid * 4);
        ax += cf * v.x;
        ay += cf * v.y;
        az += cf * v.z;
        aw += cf * v.w;
    }
    size_t obase = (size_t)(b * N_ + n) * (F_ * T_) + tid * 4;
    float4 r;
    r.x = ax * scale;
    r.y = ay * scale;
    r.z = az * scale;
    r.w = aw * scale;
    if (hasSub) {
        const float4 u = *(const float4*)(Tsub + obase);
        r.x -= u.x;
        r.y -= u.y;
        r.z -= u.z;
        r.w -= u.w;
    }
    *(float4*)(Tout + obase) = r;
}

// Xhat[b,n,c,t] = relu( sum_k sum_f Txk[b,n,f,t] * chW[k,f,c] + chb[c] )
__global__ __launch_bounds__(256) void k_cheb(const float* __restrict__ Tx0,
                                              const float* __restrict__ Tx1,
                                              const float* __restrict__ Tx2,
                                              const float* __restrict__ W,
                                              const float* __restrict__ bias,
                                              float* __restrict__ Xhat) {
    __shared__ float s0[F_ * T_], s1[F_ * T_], s2[F_ * T_];
    __shared__ float sw[3 * F_ * CC_];
    int bn = blockIdx.x;
    size_t base = (size_t)bn * F_ * T_;
    int tid = threadIdx.x;
    for (int q = tid; q < F_ * T_; q += 256) {
        s0[q] = Tx0[base + q];
        s1[q] = Tx1[base + q];
        s2[q] = Tx2[base + q];
    }
    for (int q = tid; q < 3 * F_ * CC_; q += 256) sw[q] = W[q];
    __syncthreads();
    for (int q = tid; q < CC_ * T_; q += 256) {
        int c = q / T_, t = q % T_;
        float acc = bias[c];
#pragma unroll
        for (int f = 0; f < F_; ++f) {
            acc += s0[f * T_ + t] * sw[(0 * F_ + f) * CC_ + c];
            acc += s1[f * T_ + t] * sw[(1 * F_ + f) * CC_ + c];
            acc += s2[f * T_ + t] * sw[(2 * F_ + f) * CC_ + c];
        }
        Xhat[(size_t)bn * CC_ * T_ + q] = fmaxf(acc, 0.f);
    }
}

// ---------------- fused conv GEMM + layernorm ----------------

__global__ __launch_bounds__(256) void k_conv(const float* __restrict__ Xh,
                                              const float* __restrict__ X,
                                              const float* __restrict__ tw,
                                              const float* __restrict__ rw,
                                              const float* __restrict__ tb,
                                              const float* __restrict__ rb,
                                              float* __restrict__ Z) {
    __shared__ float As[16][65];
    __shared__ float Bs[16][64];
    const int row0 = blockIdx.x * 64;
    const int tid = threadIdx.x;
    const int tm = (tid >> 4) << 2, tn = (tid & 15) << 2;
    float acc[4][4] = {};
    for (int k0 = 0; k0 < 224; k0 += 16) {
#pragma unroll
        for (int it = 0; it < 4; ++it) {
            int q = tid + it * 256;
            int m = q & 63, k = q >> 6;
            int kk = k0 + k;
            int g = row0 + m;
            int site = g / 24;
            int t = g - site * 24;
            float v, w;
            if (kk < 192) {
                int ci = kk / 3, dt = kk - ci * 3;
                int tt = t + dt - 1;
                v = (tt >= 0 && tt < 24) ? Xh[(size_t)site * 1536 + ci * 24 + tt] : 0.f;
                w = tw[(m * CC_ + ci) * 3 + dt];
            } else {
                int f = kk - 192;
                v = X[(size_t)site * 768 + f * 24 + t];
                w = rw[m * F_ + (kk - 192)];
            }
            As[k][m] = v;
            Bs[k][m] = w;
        }
        __syncthreads();
#pragma unroll
        for (int k = 0; k < 16; ++k) {
            float a0 = As[k][tm + 0], a1 = As[k][tm + 1], a2 = As[k][tm + 2], a3 = As[k][tm + 3];
            float b0 = Bs[k][tn + 0], b1 = Bs[k][tn + 1], b2 = Bs[k][tn + 2], b3 = Bs[k][tn + 3];
            acc[0][0] += a0 * b0; acc[0][1] += a0 * b1; acc[0][2] += a0 * b2; acc[0][3] += a0 * b3;
            acc[1][0] += a1 * b0; acc[1][1] += a1 * b1; acc[1][2] += a1 * b2; acc[1][3] += a1 * b3;
            acc[2][0] += a2 * b0; acc[2][1] += a2 * b1; acc[2][2] += a2 * b2; acc[2][3] += a2 * b3;
            acc[3][0] += a3 * b0; acc[3][1] += a3 * b1; acc[3][2] += a3 * b2; acc[3][3] += a3 * b3;
        }
        __syncthreads();
    }
#pragma unroll
    for (int i = 0; i < 4; ++i)
#pragma unroll
        for (int j = 0; j < 4; ++j) {
            int g = row0 + tm + i;
            int co = tn + j;
            Z[(size_t)g * 64 + co] = fmaxf(acc[i][j] + tb[co] + rb[co], 0.f);
        }
}

// LN over co (64) per (site,t) row; write out[site*1536+co*24+t]
__global__ __launch_bounds__(256) void k_ln(const float* __restrict__ Z,
                                            const float* __restrict__ g,
                                            const float* __restrict__ bb,
                                            float* __restrict__ out) {
    __shared__ float s_z[64 * 25];
    int site = blockIdx.x;
    int tid = threadIdx.x;
    int co = tid & 63, w = tid >> 6;
    float gg = g[co], bg = bb[co];
    for (int t = w; t < 24; t += 4) {
        float z = Z[(size_t)site * 1536 + t * 64 + co];
        float s1 = z, s2 = z * z;
        for (int off = 32; off > 0; off >>= 1) {
            s1 += __shfl_xor(s1, off);
            s2 += __shfl_xor(s2, off);
        }
        float mu = s1 * (1.f / 64.f);
        float var = s2 * (1.f / 64.f) - mu * mu;
        s_z[co * 25 + t] = (z - mu) * rsqrtf(var + LN_EPS_) * gg + bg;
    }
    __syncthreads();
    for (int q = tid; q < 1536; q += 256)
        out[(size_t)site * 1536 + q] = s_z[(q / 24) * 25 + (q % 24)];
}

extern "C" void kernel_launch(void* const* d_in, const int* in_sizes, int n_in,
                              void* d_out, int out_size, void* d_ws, size_t ws_size,
                              hipStream_t stream) {
    const float* X = (const float*)d_in[0];
    const int* ei = (const int*)d_in[1];
    const float* U1 = (const float*)d_in[2];
    const float* U2 = (const float*)d_in[3];
    const float* U3 = (const float*)d_in[4];
    const float* be = (const float*)d_in[5];
    const float* Ve = (const float*)d_in[6];
    const float* W1 = (const float*)d_in[7];
    const float* W2 = (const float*)d_in[8];
    const float* W3 = (const float*)d_in[9];
    const float* bs = (const float*)d_in[10];
    const float* Vs = (const float*)d_in[11];
    const float* chW = (const float*)d_in[12];
    const float* chb = (const float*)d_in[13];
    const float* tw = (const float*)d_in[14];
    const float* tb = (const float*)d_in[15];
    const float* rw = (const float*)d_in[16];
    const float* rb = (const float*)d_in[17];
    const float* lng = (const float*)d_in[18];
    const float* lnb = (const float*)d_in[19];
    float* out = (float*)d_out;
    float* ws = (float*)d_ws;

    size_t o = 0;
    float* lhs_tf = ws + o; o += B_ * T_ * F_;
    float* lhsN  = ws + o; o += (size_t)B_ * T_ * N_;
    float* rhsT  = ws + o; o += (size_t)B_ * N_ * T_;
    float* rhsTT = ws + o; o += (size_t)B_ * T_ * N_;
    float* sigE  = ws + o; o += B_ * T_ * T_;
    float* Eatt  = ws + o; o += B_ * T_ * T_;
    float* slhsF = ws + o; o += (size_t)B_ * N_ * F_;
    float* slhs  = ws + o; o += (size_t)B_ * N_ * T_;
    float* srhs  = ws + o; o += (size_t)B_ * T_ * N_;
    float* deg   = ws + o; o += N_;
    float* dis   = ws + o; o += N_;
    float* diagS = ws + o; o += B_ * N_;
    float* csrNorm = ws + o; o += E_;
    float* csrAttn = ws + o; o += (size_t)B_ * E_;
    int* cnt     = (int*)(ws + o); o += N_;
    int* rowPtr  = (int*)(ws + o); o += N_ + 1;
    int* fillPos = (int*)(ws + o); o += N_;
    int* csrRow  = (int*)(ws + o); o += E_;
    int* csrCol  = (int*)(ws + o); o += E_ + 3;  // +3: keep later buffers 16B-aligned
    float* Xt    = ws + o; o += (size_t)B_ * N_ * F_ * T_;  // later reused as Tx2
    float* Psig  = ws + o; o += (size_t)B_ * N_ * N_;       // later Tx0, then Zbuf
    float* S     = ws + o; o += (size_t)B_ * N_ * N_;       // later Tx1
    float* Xhat  = ws + o; o += (size_t)B_ * N_ * CC_ * T_;
    float* Tx0 = Psig;
    float* Tx1 = S;
    float* Tx2 = Xt;
    float* Zbuf = Psig;
    // PsigT (bf16, B*N*N = 16.8MB) overlays Xhat: dead before k_cheb writes Xhat
    __hip_bfloat16* PsigT = (__hip_bfloat16*)Xhat;
    const int* rowI = ei;
    const int* colI = ei + E_;

    // CSR build (independent of attention pipeline)
    hipMemsetAsync(cnt, 0, N_ * sizeof(int), stream);
    hipMemsetAsync(deg, 0, N_ * sizeof(float), stream);
    k_count<<<(E_ + 255) / 256, 256, 0, stream>>>(rowI, colI, cnt, deg);
    k_scan<<<1, 1024, 0, stream>>>(cnt, deg, rowPtr, fillPos, dis);
    k_fill<<<(E_ + 255) / 256, 256, 0, stream>>>(rowI, colI, fillPos, csrRow, csrCol);

    // temporal attention
    hipMemsetAsync(lhs_tf, 0, B_ * T_ * F_ * sizeof(float), stream);
    k_lhs2<<<B_ * 16, 768, 0, stream>>>(X, U1, lhs_tf);
    k_lhsN<<<(B_ * T_ * N_ + 255) / 256, 256, 0, stream>>>(lhs_tf, U2, lhsN);
    k_rhsT<<<(B_ * N_ * T_ + 255) / 256, 256, 0, stream>>>(X, U3, rhsT);
    k_transp<<<B_ * 16, 256, 0, stream>>>(rhsT, rhsTT);
    k_edot<<<B_ * T_ * T_, 64, 0, stream>>>(lhsN, rhsTT, be, sigE);
    k_eatt2<<<B_, 576, 0, stream>>>(sigE, Ve, Eatt);
    k_xt<<<B_ * (N_ * F_ * T_ / 256), 256, 0, stream>>>(X, Eatt, Xt);
    // spatial attention
    k_slhsF<<<(B_ * N_ * F_ + 255) / 256, 256, 0, stream>>>(Xt, W1, slhsF);
    k_slhs<<<(B_ * N_ * T_ + 255) / 256, 256, 0, stream>>>(slhsF, W2, slhs);
    k_srhs<<<(B_ * N_ * T_ + 255) / 256, 256, 0, stream>>>(Xt, W3, srhs);
    {
        dim3 g(16, 16, B_);
        k_psig2<<<g, 256, 0, stream>>>(slhs, srhs, bs, Psig, PsigT);
    }
    {
        dim3 g(8, 8, B_);
        k_smfma<<<g, 256, 0, stream>>>(Vs, PsigT, S);
    }
    {
        dim3 g(N_ / 64, B_);
        k_colsoftmax<<<g, 256, 0, stream>>>(S);
    }
    // coefficients in CSR order (needs S)
    k_csrcoef<<<(E_ + 255) / 256, 256, 0, stream>>>(csrRow, csrCol, dis, S, csrNorm, csrAttn);
    k_diag<<<(B_ * N_ + 255) / 256, 256, 0, stream>>>(S, diagS);
    // chebyshev propagation (gather, no atomics)
    k_tx0<<<(B_ * N_ * F_ * T_ + 255) / 256, 256, 0, stream>>>(X, diagS, Tx0);
    k_gprop<<<B_ * N_, 192, 0, stream>>>(Tx0, nullptr, Tx1, csrAttn, csrCol, rowPtr, 1, 1.0f, 0);
    k_gprop<<<B_ * N_, 192, 0, stream>>>(Tx1, Tx0, Tx2, csrNorm, csrCol, rowPtr, 0, 2.0f, 1);
    k_cheb<<<B_ * N_, 256, 0, stream>>>(Tx0, Tx1, Tx2, chW, chb, Xhat);
    // fused time conv + residual as GEMM, then layernorm
    k_conv<<<(B_ * N_ * T_) / 64, 256, 0, stream>>>(Xhat, X, tw, rw, tb, rb, Zbuf);
    k_ln<<<B_ * N_, 256, 0, stream>>>(Zbuf, lng, lnb, out);
}

// Round 6
// 652.650 us; speedup vs baseline: 6.7719x; 1.2676x over previous
//
#include <hip/hip_runtime.h>
#include <hip/hip_bf16.h>
#include <math.h>

#define B_ 8
#define N_ 1024
#define F_ 32
#define T_ 24
#define E_ 16384
#define CC_ 64
#define CT_ 64
#define LN_EPS_ 1e-5f

typedef __attribute__((ext_vector_type(8))) short bf16x8;
typedef __attribute__((ext_vector_type(4))) float f32x4;

__device__ __forceinline__ short f2bf(float f) {
    union { float f; unsigned u; } v; v.f = f;
    unsigned r = v.u + 0x7fffu + ((v.u >> 16) & 1u);  // RNE
    return (short)(r >> 16);
}

// ---------------- temporal attention ----------------

// lhs_tf[b,t,f] (stored [b][t*32+f]) = sum_n X[b,n,f,t] * U1[n]
__global__ __launch_bounds__(768) void k_lhs2(const float* __restrict__ X,
                                              const float* __restrict__ U1,
                                              float* __restrict__ out) {
    __shared__ float su[64];
    int b = blockIdx.x >> 4;
    int n0 = (blockIdx.x & 15) * 64;
    int tid = threadIdx.x;
    if (tid < 64) su[tid] = U1[n0 + tid];
    __syncthreads();
    float acc = 0.f;
    const float* xp = X + ((size_t)b * N_ + n0) * 768 + tid;
#pragma unroll 8
    for (int i = 0; i < 64; ++i) acc += xp[(size_t)i * 768] * su[i];
    int f = tid / 24, t = tid - (tid / 24) * 24;
    atomicAdd(&out[b * 768 + t * 32 + f], acc);
}

// lhsN[b,t,n] = sum_f lhs_tf[b,t,f] * U2[f,n]
__global__ void k_lhsN(const float* __restrict__ lhs_tf, const float* __restrict__ U2,
                       float* __restrict__ out) {
    int idx = blockIdx.x * 256 + threadIdx.x;
    if (idx >= B_ * T_ * N_) return;
    int n = idx % N_;
    int bt = idx / N_;
    float acc = 0.f;
#pragma unroll
    for (int f = 0; f < F_; ++f) acc += lhs_tf[bt * F_ + f] * U2[(size_t)f * N_ + n];
    out[idx] = acc;
}

// rhsT[b,n,t] = sum_f U3[f] * X[b,n,f,t]
__global__ void k_rhsT(const float* __restrict__ X, const float* __restrict__ U3,
                       float* __restrict__ out) {
    int idx = blockIdx.x * 256 + threadIdx.x;
    if (idx >= B_ * N_ * T_) return;
    int t = idx % T_;
    int n = (idx / T_) % N_;
    int b = idx / (N_ * T_);
    const float* xp = X + ((size_t)(b * N_ + n) * F_) * T_ + t;
    float acc = 0.f;
#pragma unroll
    for (int f = 0; f < F_; ++f) acc += U3[f] * xp[f * T_];
    out[idx] = acc;
}

// transpose rhsT [b,n,t] -> rhsTT [b,t,n]
__global__ __launch_bounds__(256) void k_transp(const float* __restrict__ in,
                                                float* __restrict__ outp) {
    __shared__ float s[64 * 25];
    int b = blockIdx.x >> 4;
    int n0 = (blockIdx.x & 15) * 64;
    int tid = threadIdx.x;
    const float* ip = in + ((size_t)b * N_ + n0) * 24;
    for (int q = tid; q < 1536; q += 256) s[(q / 24) * 25 + (q % 24)] = ip[q];
    __syncthreads();
    for (int q = tid; q < 1536; q += 256) {
        int t = q >> 6, n = q & 63;
        outp[((size_t)b * 24 + t) * N_ + n0 + n] = s[n * 25 + t];
    }
}

// sig[b,i,j] = sigmoid( lhsN[b,i,:] . rhsTT[b,j,:] + be[i,j] ); one wave per (b,i,j)
__global__ __launch_bounds__(64) void k_edot(const float* __restrict__ lhsN,
                                             const float* __restrict__ rhsTT,
                                             const float* __restrict__ be,
                                             float* __restrict__ sig) {
    int blk = blockIdx.x;
    int b = blk / 576, ij = blk % 576;
    int i = ij / 24, j = ij % 24;
    int lane = threadIdx.x;
    const float* lp = lhsN + ((size_t)b * 24 + i) * N_;
    const float* rp = rhsTT + ((size_t)b * 24 + j) * N_;
    float acc = 0.f;
#pragma unroll
    for (int n = lane; n < N_; n += 64) acc += lp[n] * rp[n];
    for (int off = 32; off > 0; off >>= 1) acc += __shfl_xor(acc, off);
    if (lane == 0) sig[blk] = 1.f / (1.f + expf(-(acc + be[ij])));
}

// Escore = Ve @ sig, then softmax over rows -> Eatt
__global__ __launch_bounds__(576) void k_eatt2(const float* __restrict__ sig,
                                               const float* __restrict__ Ve,
                                               float* __restrict__ Eatt) {
    __shared__ float ss[T_ * T_];
    __shared__ float esc[T_ * T_];
    int b = blockIdx.x;
    int tid = threadIdx.x;
    ss[tid] = sig[b * 576 + tid];
    __syncthreads();
    int i = tid / T_, j = tid % T_;
    {
        float acc = 0.f;
#pragma unroll
        for (int m = 0; m < T_; ++m) acc += Ve[i * T_ + m] * ss[m * T_ + j];
        esc[tid] = acc;
    }
    __syncthreads();
    if (tid < T_) {
        int jj = tid;
        float mx = -1e30f;
        for (int r = 0; r < T_; ++r) mx = fmaxf(mx, esc[r * T_ + jj]);
        float s = 0.f;
        for (int r = 0; r < T_; ++r) {
            float e = expf(esc[r * T_ + jj] - mx);
            ss[r * T_ + jj] = e;
            s += e;
        }
        float inv = 1.f / s;
        for (int r = 0; r < T_; ++r) Eatt[(size_t)(b * T_ + r) * T_ + jj] = ss[r * T_ + jj] * inv;
    }
}

// Xt[b,nf,t] = sum_k X[b,nf,k] * Eatt[b,k,t]
__global__ void k_xt(const float* __restrict__ X, const float* __restrict__ Eatt,
                     float* __restrict__ Xt) {
    __shared__ float e[T_ * T_];
    const int per_b = N_ * F_ * T_ / 256;  // 3072
    int b = blockIdx.x / per_b;
    int tid = threadIdx.x;
    for (int q = tid; q < T_ * T_; q += 256) e[q] = Eatt[(size_t)b * T_ * T_ + q];
    __syncthreads();
    int off = (blockIdx.x % per_b) * 256 + tid;
    int t = off % T_;
    int nf = off / T_;
    const float* xr = X + ((size_t)b * N_ * F_ + nf) * T_;
    float acc = 0.f;
#pragma unroll
    for (int k = 0; k < T_; ++k) acc += xr[k] * e[k * T_ + t];
    Xt[((size_t)b * N_ * F_ + nf) * T_ + t] = acc;
}

// ---------------- spatial attention ----------------

// slhsF[b,n,f] = sum_t Xt[b,n,f,t] * W1[t]
__global__ void k_slhsF(const float* __restrict__ Xt, const float* __restrict__ W1,
                        float* __restrict__ out) {
    int idx = blockIdx.x * 256 + threadIdx.x;
    if (idx >= B_ * N_ * F_) return;
    const float* xp = Xt + (size_t)idx * T_;
    float acc = 0.f;
#pragma unroll
    for (int t = 0; t < T_; ++t) acc += xp[t] * W1[t];
    out[idx] = acc;
}

// slhs[b,n,t] = sum_f slhsF[b,n,f] * W2[f,t]
__global__ void k_slhs(const float* __restrict__ slhsF, const float* __restrict__ W2,
                       float* __restrict__ out) {
    int idx = blockIdx.x * 256 + threadIdx.x;
    if (idx >= B_ * N_ * T_) return;
    int t = idx % T_;
    int bn = idx / T_;
    float acc = 0.f;
#pragma unroll
    for (int f = 0; f < F_; ++f) acc += slhsF[(size_t)bn * F_ + f] * W2[f * T_ + t];
    out[idx] = acc;
}

// srhs[b,t,n] = sum_f W3[f] * Xt[b,n,f,t]
__global__ void k_srhs(const float* __restrict__ Xt, const float* __restrict__ W3,
                       float* __restrict__ out) {
    int idx = blockIdx.x * 256 + threadIdx.x;
    if (idx >= B_ * N_ * T_) return;
    int t = idx % T_;
    int n = (idx / T_) % N_;
    int b = idx / (N_ * T_);
    const float* xp = Xt + ((size_t)(b * N_ + n) * F_) * T_ + t;
    float acc = 0.f;
#pragma unroll
    for (int f = 0; f < F_; ++f) acc += W3[f] * xp[f * T_];
    out[((size_t)b * T_ + t) * N_ + n] = acc;
}

// Psig tile kernel: Psig[b,i,k] = sigmoid(slhs[b,i,:].srhs[b,:,k] + bs[i,k])  (f32)
// also writes PsigT[b,k,i] in bf16 for the MFMA B-operand.
__global__ __launch_bounds__(256) void k_psig2(const float* __restrict__ slhs,
                                               const float* __restrict__ srhs,
                                               const float* __restrict__ bs,
                                               float* __restrict__ Psig,
                                               __hip_bfloat16* __restrict__ PsigT) {
    __shared__ float sl[64][24];
    __shared__ float sr[24][64];
    __shared__ short st[64][72];
    int b = blockIdx.z;
    int i0 = blockIdx.y * 64, k0 = blockIdx.x * 64;
    int tid = threadIdx.x;
    {
        const float* sp = slhs + ((size_t)b * N_ + i0) * 24;
#pragma unroll
        for (int it = 0; it < 6; ++it) {
            int q = tid + it * 256;
            sl[q / 24][q % 24] = sp[q];
        }
        const float* rp = srhs + (size_t)b * 24 * N_ + k0;
#pragma unroll
        for (int it = 0; it < 6; ++it) {
            int q = tid + it * 256;
            sr[q >> 6][q & 63] = rp[(size_t)(q >> 6) * N_ + (q & 63)];
        }
    }
    __syncthreads();
    int ib = (tid >> 4) * 4;   // 0..60
    int kb = (tid & 15) * 4;   // 0..60
    float acc[4][4];
#pragma unroll
    for (int a = 0; a < 4; ++a) {
        const float4 bv = *(const float4*)(bs + (size_t)(i0 + ib + a) * N_ + k0 + kb);
        acc[a][0] = bv.x; acc[a][1] = bv.y; acc[a][2] = bv.z; acc[a][3] = bv.w;
    }
#pragma unroll
    for (int t = 0; t < 24; ++t) {
        float r0 = sr[t][kb], r1 = sr[t][kb + 1], r2 = sr[t][kb + 2], r3 = sr[t][kb + 3];
#pragma unroll
        for (int a = 0; a < 4; ++a) {
            float lv = sl[ib + a][t];
            acc[a][0] += lv * r0; acc[a][1] += lv * r1; acc[a][2] += lv * r2; acc[a][3] += lv * r3;
        }
    }
#pragma unroll
    for (int a = 0; a < 4; ++a) {
        float4 o;
        o.x = 1.f / (1.f + expf(-acc[a][0]));
        o.y = 1.f / (1.f + expf(-acc[a][1]));
        o.z = 1.f / (1.f + expf(-acc[a][2]));
        o.w = 1.f / (1.f + expf(-acc[a][3]));
        *(float4*)(Psig + (size_t)((size_t)b * N_ + i0 + ib + a) * N_ + k0 + kb) = o;
        st[kb + 0][ib + a] = f2bf(o.x);
        st[kb + 1][ib + a] = f2bf(o.y);
        st[kb + 2][ib + a] = f2bf(o.z);
        st[kb + 3][ib + a] = f2bf(o.w);
    }
    __syncthreads();
    short* op = (short*)PsigT + ((size_t)b * N_ + k0) * N_ + i0;
#pragma unroll
    for (int it = 0; it < 2; ++it) {
        int ch = tid + it * 256;
        int kk = ch >> 3, off = (ch & 7) * 8;
        uint4 u = *(uint4*)&st[kk][off];
        *(uint4*)(op + (size_t)kk * N_ + off) = u;
    }
}

// S[b] = Vs @ Psig[b] via bf16 MFMA. 128x128 tile, 4 waves, BK=32.
__global__ __launch_bounds__(256) void k_smfma(const float* __restrict__ Vs,
                                               const __hip_bfloat16* __restrict__ PsigT,
                                               float* __restrict__ S) {
    __shared__ short Asd[128][40];
    __shared__ short Bsd[128][40];
    const int b = blockIdx.z;
    const int bm = blockIdx.y * 128, bn = blockIdx.x * 128;
    const int tid = threadIdx.x;
    const int lane = tid & 63, wave = tid >> 6;
    const int wr = wave >> 1, wc = wave & 1;
    const int fr = lane & 15, ks = lane >> 4;
    f32x4 acc[4][4] = {};
    const short* PT = (const short*)PsigT + (size_t)b * N_ * N_;
    for (int k0 = 0; k0 < N_; k0 += 32) {
#pragma unroll
        for (int it = 0; it < 4; ++it) {
            int q = tid + it * 256;           // 0..1023
            int row = q >> 3, kk = (q & 7) * 4;
            float4 v = *(const float4*)(Vs + (size_t)(bm + row) * N_ + k0 + kk);
            short4 s4;
            s4.x = f2bf(v.x); s4.y = f2bf(v.y); s4.z = f2bf(v.z); s4.w = f2bf(v.w);
            *(short4*)&Asd[row][kk] = s4;
        }
#pragma unroll
        for (int it = 0; it < 2; ++it) {
            int q = tid + it * 256;           // 0..511
            int row = q >> 2, kk = (q & 3) * 8;
            uint4 u = *(const uint4*)(PT + (size_t)(bn + row) * N_ + k0 + kk);
            *(uint4*)&Bsd[row][kk] = u;
        }
        __syncthreads();
        bf16x8 a[4], bf[4];
#pragma unroll
        for (int m = 0; m < 4; ++m) a[m] = *(const bf16x8*)&Asd[wr * 64 + m * 16 + fr][ks * 8];
#pragma unroll
        for (int n = 0; n < 4; ++n) bf[n] = *(const bf16x8*)&Bsd[wc * 64 + n * 16 + fr][ks * 8];
#pragma unroll
        for (int m = 0; m < 4; ++m)
#pragma unroll
            for (int n = 0; n < 4; ++n)
                acc[m][n] = __builtin_amdgcn_mfma_f32_16x16x32_bf16(a[m], bf[n], acc[m][n], 0, 0, 0);
        __syncthreads();
    }
    float* Sb = S + (size_t)b * N_ * N_;
#pragma unroll
    for (int m = 0; m < 4; ++m)
#pragma unroll
        for (int n = 0; n < 4; ++n) {
#pragma unroll
            for (int j = 0; j < 4; ++j) {
                int row = bm + wr * 64 + m * 16 + (lane >> 4) * 4 + j;
                int col = bn + wc * 64 + n * 16 + (lane & 15);
                Sb[(size_t)row * N_ + col] = acc[m][n][j];
            }
        }
}

// ---------------- softmax stats (no full normalize pass) ----------------
// softmax over rows (axis=1) per column. Pass 1: per-(128-row chunk) partial max/sumexp.
__global__ __launch_bounds__(256) void k_smpart(const float* __restrict__ S,
                                                float* __restrict__ pmax,
                                                float* __restrict__ psum) {
    __shared__ float tile[128][64];
    __shared__ float redm[4][64];
    __shared__ float reds[4][64];
    int b = blockIdx.z;
    int chunk = blockIdx.y;   // 0..7
    int cg = blockIdx.x;      // 0..15
    int tid = threadIdx.x;
    const float* Sb = S + (size_t)b * N_ * N_ + (size_t)(chunk * 128) * N_ + cg * 64;
    for (int q = tid; q < 8192; q += 256) {
        int r = q >> 6, c = q & 63;
        tile[r][c] = Sb[(size_t)r * N_ + c];
    }
    __syncthreads();
    int c = tid & 63, grp = tid >> 6;
    float m = -1e30f;
    for (int r = grp; r < 128; r += 4) m = fmaxf(m, tile[r][c]);
    redm[grp][c] = m;
    __syncthreads();
    m = fmaxf(fmaxf(redm[0][c], redm[1][c]), fmaxf(redm[2][c], redm[3][c]));
    float s = 0.f;
    for (int r = grp; r < 128; r += 4) s += __expf(tile[r][c] - m);
    reds[grp][c] = s;
    __syncthreads();
    if (grp == 0) {
        s = reds[0][c] + reds[1][c] + reds[2][c] + reds[3][c];
        size_t o = ((size_t)b * 8 + chunk) * N_ + cg * 64 + c;
        pmax[o] = m;
        psum[o] = s;
    }
}

// Pass 2: combine 8 chunk partials per column -> colMax, colInv
__global__ __launch_bounds__(1024) void k_smcomb(const float* __restrict__ pmax,
                                                 const float* __restrict__ psum,
                                                 float* __restrict__ colMax,
                                                 float* __restrict__ colInv) {
    int b = blockIdx.x;
    int col = threadIdx.x;
    float M = -1e30f;
#pragma unroll
    for (int ch = 0; ch < 8; ++ch) M = fmaxf(M, pmax[((size_t)b * 8 + ch) * N_ + col]);
    float s = 0.f;
#pragma unroll
    for (int ch = 0; ch < 8; ++ch)
        s += psum[((size_t)b * 8 + ch) * N_ + col] *
             __expf(pmax[((size_t)b * 8 + ch) * N_ + col] - M);
    colMax[(size_t)b * N_ + col] = M;
    colInv[(size_t)b * N_ + col] = 1.f / s;
}

// ---------------- graph: CSR build + normalization ----------------

__global__ void k_count(const int* __restrict__ rowI, const int* __restrict__ colI,
                        int* __restrict__ cnt, float* __restrict__ deg) {
    int e = blockIdx.x * 256 + threadIdx.x;
    if (e >= E_) return;
    int r = rowI[e];
    atomicAdd(&cnt[r], 1);
    if (r != colI[e]) atomicAdd(&deg[r], 1.0f);
}

__global__ __launch_bounds__(1024) void k_scan(const int* __restrict__ cnt,
                                               const float* __restrict__ deg,
                                               int* __restrict__ rowPtr,
                                               int* __restrict__ fillPos,
                                               float* __restrict__ dis) {
    __shared__ int s[N_];
    int tid = threadIdx.x;
    int my = cnt[tid];
    s[tid] = my;
    __syncthreads();
    for (int off = 1; off < N_; off <<= 1) {
        int v = 0;
        if (tid >= off) v = s[tid - off];
        __syncthreads();
        s[tid] += v;
        __syncthreads();
    }
    rowPtr[tid + 1] = s[tid];
    if (tid == 0) rowPtr[0] = 0;
    fillPos[tid] = s[tid] - my;
    float d = deg[tid];
    dis[tid] = d > 0.f ? rsqrtf(d) : 0.f;
}

__global__ void k_fill(const int* __restrict__ rowI, const int* __restrict__ colI,
                       int* __restrict__ fillPos, int* __restrict__ csrRow,
                       int* __restrict__ csrCol) {
    int e = blockIdx.x * 256 + threadIdx.x;
    if (e >= E_) return;
    int r = rowI[e];
    int pos = atomicAdd(&fillPos[r], 1);
    csrRow[pos] = r;
    csrCol[pos] = colI[e];
}

// softmax applied on the fly at the consumed entries
__global__ void k_csrcoef(const int* __restrict__ csrRow, const int* __restrict__ csrCol,
                          const float* __restrict__ dis, const float* __restrict__ S,
                          const float* __restrict__ colMax, const float* __restrict__ colInv,
                          float* __restrict__ csrNorm, float* __restrict__ csrAttn) {
    int p = blockIdx.x * 256 + threadIdx.x;
    if (p >= E_) return;
    int r = csrRow[p], c = csrCol[p];
    float nm = (r == c) ? 0.f : -dis[r] * dis[c];
    csrNorm[p] = nm;
    size_t off = (size_t)r * N_ + c;
#pragma unroll
    for (int b = 0; b < B_; ++b) {
        float sv = __expf(S[(size_t)b * N_ * N_ + off] - colMax[(size_t)b * N_ + c]) *
                   colInv[(size_t)b * N_ + c];
        csrAttn[(size_t)b * E_ + p] = nm * sv;
    }
}

__global__ void k_diag(const float* __restrict__ S, const float* __restrict__ colMax,
                       const float* __restrict__ colInv, float* __restrict__ diagS) {
    int idx = blockIdx.x * 256 + threadIdx.x;
    if (idx >= B_ * N_) return;
    int n = idx % N_;
    int b = idx / N_;
    float sv = __expf(S[(size_t)b * N_ * N_ + (size_t)n * N_ + n] - colMax[(size_t)b * N_ + n]) *
               colInv[(size_t)b * N_ + n];
    diagS[idx] = sv;
}

// Tx0 = diagS * X
__global__ void k_tx0(const float* __restrict__ X, const float* __restrict__ diagS,
                      float* __restrict__ Tx0) {
    int idx = blockIdx.x * 256 + threadIdx.x;
    if (idx >= B_ * N_ * F_ * T_) return;
    int bn = idx / (F_ * T_);
    Tx0[idx] = diagS[bn] * X[idx];
}

// gather propagation: Tout[b,n,:] = scale * sum_{p in csr row n} coef[p] * Tin[b,csrCol[p],:]
__global__ __launch_bounds__(192) void k_gprop(const float* __restrict__ Tin,
                                               const float* __restrict__ Tsub,
                                               float* __restrict__ Tout,
                                               const float* __restrict__ coef,
                                               const int* __restrict__ csrCol,
                                               const int* __restrict__ rowPtr,
                                               int perB, float scale, int hasSub) {
    int blk = blockIdx.x;
    int b = blk & 7;
    int n = blk >> 3;
    int tid = threadIdx.x;
    int s = rowPtr[n], e = rowPtr[n + 1];
    const float* cbase = coef + (perB ? (size_t)b * E_ : 0);
    float ax = 0.f, ay = 0.f, az = 0.f, aw = 0.f;
    for (int p = s; p < e; ++p) {
        float cf = cbase[p];
        const float4 v =
            *(const float4*)(Tin + ((size_t)(b * N_ + csrCol[p]) * (F_ * T_)) + tid * 4);
        ax += cf * v.x;
        ay += cf * v.y;
        az += cf * v.z;
        aw += cf * v.w;
    }
    size_t obase = (size_t)(b * N_ + n) * (F_ * T_) + tid * 4;
    float4 r;
    r.x = ax * scale;
    r.y = ay * scale;
    r.z = az * scale;
    r.w = aw * scale;
    if (hasSub) {
        const float4 u = *(const float4*)(Tsub + obase);
        r.x -= u.x;
        r.y -= u.y;
        r.z -= u.z;
        r.w -= u.w;
    }
    *(float4*)(Tout + obase) = r;
}

// Xhat[b,n,c,t] = relu( sum_k sum_f Txk[b,n,f,t] * chW[k,f,c] + chb[c] )
__global__ __launch_bounds__(256) void k_cheb(const float* __restrict__ Tx0,
                                              const float* __restrict__ Tx1,
                                              const float* __restrict__ Tx2,
                                              const float* __restrict__ W,
                                              const float* __restrict__ bias,
                                              float* __restrict__ Xhat) {
    __shared__ float s0[F_ * T_], s1[F_ * T_], s2[F_ * T_];
    __shared__ float sw[3 * F_ * CC_];
    int bn = blockIdx.x;
    size_t base = (size_t)bn * F_ * T_;
    int tid = threadIdx.x;
    for (int q = tid; q < F_ * T_; q += 256) {
        s0[q] = Tx0[base + q];
        s1[q] = Tx1[base + q];
        s2[q] = Tx2[base + q];
    }
    for (int q = tid; q < 3 * F_ * CC_; q += 256) sw[q] = W[q];
    __syncthreads();
    for (int q = tid; q < CC_ * T_; q += 256) {
        int c = q / T_, t = q % T_;
        float acc = bias[c];
#pragma unroll
        for (int f = 0; f < F_; ++f) {
            acc += s0[f * T_ + t] * sw[(0 * F_ + f) * CC_ + c];
            acc += s1[f * T_ + t] * sw[(1 * F_ + f) * CC_ + c];
            acc += s2[f * T_ + t] * sw[(2 * F_ + f) * CC_ + c];
        }
        Xhat[(size_t)bn * CC_ * T_ + q] = fmaxf(acc, 0.f);
    }
}

// ---------------- fused conv GEMM + layernorm ----------------

__global__ __launch_bounds__(256) void k_conv(const float* __restrict__ Xh,
                                              const float* __restrict__ X,
                                              const float* __restrict__ tw,
                                              const float* __restrict__ rw,
                                              const float* __restrict__ tb,
                                              const float* __restrict__ rb,
                                              float* __restrict__ Z) {
    __shared__ float As[16][65];
    __shared__ float Bs[16][64];
    const int row0 = blockIdx.x * 64;
    const int tid = threadIdx.x;
    const int tm = (tid >> 4) << 2, tn = (tid & 15) << 2;
    float acc[4][4] = {};
    for (int k0 = 0; k0 < 224; k0 += 16) {
#pragma unroll
        for (int it = 0; it < 4; ++it) {
            int q = tid + it * 256;
            int m = q & 63, k = q >> 6;
            int kk = k0 + k;
            int g = row0 + m;
            int site = g / 24;
            int t = g - site * 24;
            float v, w;
            if (kk < 192) {
                int ci = kk / 3, dt = kk - ci * 3;
                int tt = t + dt - 1;
                v = (tt >= 0 && tt < 24) ? Xh[(size_t)site * 1536 + ci * 24 + tt] : 0.f;
                w = tw[(m * CC_ + ci) * 3 + dt];
            } else {
                int f = kk - 192;
                v = X[(size_t)site * 768 + f * 24 + t];
                w = rw[m * F_ + (kk - 192)];
            }
            As[k][m] = v;
            Bs[k][m] = w;
        }
        __syncthreads();
#pragma unroll
        for (int k = 0; k < 16; ++k) {
            float a0 = As[k][tm + 0], a1 = As[k][tm + 1], a2 = As[k][tm + 2], a3 = As[k][tm + 3];
            float b0 = Bs[k][tn + 0], b1 = Bs[k][tn + 1], b2 = Bs[k][tn + 2], b3 = Bs[k][tn + 3];
            acc[0][0] += a0 * b0; acc[0][1] += a0 * b1; acc[0][2] += a0 * b2; acc[0][3] += a0 * b3;
            acc[1][0] += a1 * b0; acc[1][1] += a1 * b1; acc[1][2] += a1 * b2; acc[1][3] += a1 * b3;
            acc[2][0] += a2 * b0; acc[2][1] += a2 * b1; acc[2][2] += a2 * b2; acc[2][3] += a2 * b3;
            acc[3][0] += a3 * b0; acc[3][1] += a3 * b1; acc[3][2] += a3 * b2; acc[3][3] += a3 * b3;
        }
        __syncthreads();
    }
#pragma unroll
    for (int i = 0; i < 4; ++i)
#pragma unroll
        for (int j = 0; j < 4; ++j) {
            int g = row0 + tm + i;
            int co = tn + j;
            Z[(size_t)g * 64 + co] = fmaxf(acc[i][j] + tb[co] + rb[co], 0.f);
        }
}

// LN over co (64) per (site,t) row; write out[site*1536+co*24+t]
__global__ __launch_bounds__(256) void k_ln(const float* __restrict__ Z,
                                            const float* __restrict__ g,
                                            const float* __restrict__ bb,
                                            float* __restrict__ out) {
    __shared__ float s_z[64 * 25];
    int site = blockIdx.x;
    int tid = threadIdx.x;
    int co = tid & 63, w = tid >> 6;
    float gg = g[co], bg = bb[co];
    for (int t = w; t < 24; t += 4) {
        float z = Z[(size_t)site * 1536 + t * 64 + co];
        float s1 = z, s2 = z * z;
        for (int off = 32; off > 0; off >>= 1) {
            s1 += __shfl_xor(s1, off);
            s2 += __shfl_xor(s2, off);
        }
        float mu = s1 * (1.f / 64.f);
        float var = s2 * (1.f / 64.f) - mu * mu;
        s_z[co * 25 + t] = (z - mu) * rsqrtf(var + LN_EPS_) * gg + bg;
    }
    __syncthreads();
    for (int q = tid; q < 1536; q += 256)
        out[(size_t)site * 1536 + q] = s_z[(q / 24) * 25 + (q % 24)];
}

extern "C" void kernel_launch(void* const* d_in, const int* in_sizes, int n_in,
                              void* d_out, int out_size, void* d_ws, size_t ws_size,
                              hipStream_t stream) {
    const float* X = (const float*)d_in[0];
    const int* ei = (const int*)d_in[1];
    const float* U1 = (const float*)d_in[2];
    const float* U2 = (const float*)d_in[3];
    const float* U3 = (const float*)d_in[4];
    const float* be = (const float*)d_in[5];
    const float* Ve = (const float*)d_in[6];
    const float* W1 = (const float*)d_in[7];
    const float* W2 = (const float*)d_in[8];
    const float* W3 = (const float*)d_in[9];
    const float* bs = (const float*)d_in[10];
    const float* Vs = (const float*)d_in[11];
    const float* chW = (const float*)d_in[12];
    const float* chb = (const float*)d_in[13];
    const float* tw = (const float*)d_in[14];
    const float* tb = (const float*)d_in[15];
    const float* rw = (const float*)d_in[16];
    const float* rb = (const float*)d_in[17];
    const float* lng = (const float*)d_in[18];
    const float* lnb = (const float*)d_in[19];
    float* out = (float*)d_out;
    float* ws = (float*)d_ws;

    size_t o = 0;
    float* lhs_tf = ws + o; o += B_ * T_ * F_;
    float* lhsN  = ws + o; o += (size_t)B_ * T_ * N_;
    float* rhsT  = ws + o; o += (size_t)B_ * N_ * T_;
    float* rhsTT = ws + o; o += (size_t)B_ * T_ * N_;
    float* sigE  = ws + o; o += B_ * T_ * T_;
    float* Eatt  = ws + o; o += B_ * T_ * T_;
    float* slhsF = ws + o; o += (size_t)B_ * N_ * F_;
    float* slhs  = ws + o; o += (size_t)B_ * N_ * T_;
    float* srhs  = ws + o; o += (size_t)B_ * T_ * N_;
    float* deg   = ws + o; o += N_;
    float* dis   = ws + o; o += N_;
    float* diagS = ws + o; o += B_ * N_;
    float* csrNorm = ws + o; o += E_;
    float* csrAttn = ws + o; o += (size_t)B_ * E_;
    float* pmax  = ws + o; o += (size_t)B_ * 8 * N_;
    float* psum  = ws + o; o += (size_t)B_ * 8 * N_;
    float* colMax = ws + o; o += (size_t)B_ * N_;
    float* colInv = ws + o; o += (size_t)B_ * N_;
    int* cnt     = (int*)(ws + o); o += N_;
    int* rowPtr  = (int*)(ws + o); o += N_ + 1;
    int* fillPos = (int*)(ws + o); o += N_;
    int* csrRow  = (int*)(ws + o); o += E_;
    int* csrCol  = (int*)(ws + o); o += E_ + 3;  // +3: keep later buffers 16B-aligned
    float* Xt    = ws + o; o += (size_t)B_ * N_ * F_ * T_;  // later reused as Tx2
    float* Psig  = ws + o; o += (size_t)B_ * N_ * N_;       // later Tx0, then Zbuf
    float* S     = ws + o; o += (size_t)B_ * N_ * N_;       // later Tx1
    float* Xhat  = ws + o; o += (size_t)B_ * N_ * CC_ * T_;
    float* Tx0 = Psig;
    float* Tx1 = S;
    float* Tx2 = Xt;
    float* Zbuf = Psig;
    __hip_bfloat16* PsigT = (__hip_bfloat16*)Xhat;  // overlays Xhat (dead until k_cheb)
    const int* rowI = ei;
    const int* colI = ei + E_;

    // CSR build (independent of attention pipeline)
    hipMemsetAsync(cnt, 0, N_ * sizeof(int), stream);
    hipMemsetAsync(deg, 0, N_ * sizeof(float), stream);
    k_count<<<(E_ + 255) / 256, 256, 0, stream>>>(rowI, colI, cnt, deg);
    k_scan<<<1, 1024, 0, stream>>>(cnt, deg, rowPtr, fillPos, dis);
    k_fill<<<(E_ + 255) / 256, 256, 0, stream>>>(rowI, colI, fillPos, csrRow, csrCol);

    // temporal attention
    hipMemsetAsync(lhs_tf, 0, B_ * T_ * F_ * sizeof(float), stream);
    k_lhs2<<<B_ * 16, 768, 0, stream>>>(X, U1, lhs_tf);
    k_lhsN<<<(B_ * T_ * N_ + 255) / 256, 256, 0, stream>>>(lhs_tf, U2, lhsN);
    k_rhsT<<<(B_ * N_ * T_ + 255) / 256, 256, 0, stream>>>(X, U3, rhsT);
    k_transp<<<B_ * 16, 256, 0, stream>>>(rhsT, rhsTT);
    k_edot<<<B_ * T_ * T_, 64, 0, stream>>>(lhsN, rhsTT, be, sigE);
    k_eatt2<<<B_, 576, 0, stream>>>(sigE, Ve, Eatt);
    k_xt<<<B_ * (N_ * F_ * T_ / 256), 256, 0, stream>>>(X, Eatt, Xt);
    // spatial attention
    k_slhsF<<<(B_ * N_ * F_ + 255) / 256, 256, 0, stream>>>(Xt, W1, slhsF);
    k_slhs<<<(B_ * N_ * T_ + 255) / 256, 256, 0, stream>>>(slhsF, W2, slhs);
    k_srhs<<<(B_ * N_ * T_ + 255) / 256, 256, 0, stream>>>(Xt, W3, srhs);
    {
        dim3 g(16, 16, B_);
        k_psig2<<<g, 256, 0, stream>>>(slhs, srhs, bs, Psig, PsigT);
    }
    {
        dim3 g(8, 8, B_);
        k_smfma<<<g, 256, 0, stream>>>(Vs, PsigT, S);
    }
    // softmax stats only (full normalize pass eliminated)
    {
        dim3 g(16, 8, B_);
        k_smpart<<<g, 256, 0, stream>>>(S, pmax, psum);
    }
    k_smcomb<<<B_, 1024, 0, stream>>>(pmax, psum, colMax, colInv);
    // coefficients in CSR order (softmax applied on the fly)
    k_csrcoef<<<(E_ + 255) / 256, 256, 0, stream>>>(csrRow, csrCol, dis, S, colMax, colInv,
                                                    csrNorm, csrAttn);
    k_diag<<<(B_ * N_ + 255) / 256, 256, 0, stream>>>(S, colMax, colInv, diagS);
    // chebyshev propagation (gather, no atomics)
    k_tx0<<<(B_ * N_ * F_ * T_ + 255) / 256, 256, 0, stream>>>(X, diagS, Tx0);
    k_gprop<<<B_ * N_, 192, 0, stream>>>(Tx0, nullptr, Tx1, csrAttn, csrCol, rowPtr, 1, 1.0f, 0);
    k_gprop<<<B_ * N_, 192, 0, stream>>>(Tx1, Tx0, Tx2, csrNorm, csrCol, rowPtr, 0, 2.0f, 1);
    k_cheb<<<B_ * N_, 256, 0, stream>>>(Tx0, Tx1, Tx2, chW, chb, Xhat);
    // fused time conv + residual as GEMM, then layernorm
    k_conv<<<(B_ * N_ * T_) / 64, 256, 0, stream>>>(Xhat, X, tw, rw, tb, rb, Zbuf);
    k_ln<<<B_ * N_, 256, 0, stream>>>(Zbuf, lng, lnb, out);
}

// Round 8
// 550.592 us; speedup vs baseline: 8.0271x; 1.1854x over previous
//
#include <hip/hip_runtime.h>
#include <hip/hip_bf16.h>
#include <math.h>

#define B_ 8
#define N_ 1024
#define F_ 32
#define T_ 24
#define E_ 16384
#define CC_ 64
#define CT_ 64
#define LN_EPS_ 1e-5f

typedef __attribute__((ext_vector_type(8))) short bf16x8;
typedef __attribute__((ext_vector_type(4))) float f32x4;

__device__ __forceinline__ short f2bf(float f) {
    union { float f; unsigned u; } v; v.f = f;
    unsigned r = v.u + 0x7fffu + ((v.u >> 16) & 1u);  // RNE
    return (short)(r >> 16);
}

// ---------------- temporal attention ----------------

// lhs_tf[b,t,f] (stored [b][t*32+f]) = sum_n X[b,n,f,t] * U1[n]
__global__ __launch_bounds__(768) void k_lhs2(const float* __restrict__ X,
                                              const float* __restrict__ U1,
                                              float* __restrict__ out) {
    __shared__ float su[64];
    int b = blockIdx.x >> 4;
    int n0 = (blockIdx.x & 15) * 64;
    int tid = threadIdx.x;
    if (tid < 64) su[tid] = U1[n0 + tid];
    __syncthreads();
    float acc = 0.f;
    const float* xp = X + ((size_t)b * N_ + n0) * 768 + tid;
#pragma unroll 8
    for (int i = 0; i < 64; ++i) acc += xp[(size_t)i * 768] * su[i];
    int f = tid / 24, t = tid - (tid / 24) * 24;
    atomicAdd(&out[b * 768 + t * 32 + f], acc);
}

// lhsN[b,t,n] = sum_f lhs_tf[b,t,f] * U2[f,n]
__global__ void k_lhsN(const float* __restrict__ lhs_tf, const float* __restrict__ U2,
                       float* __restrict__ out) {
    int idx = blockIdx.x * 256 + threadIdx.x;
    if (idx >= B_ * T_ * N_) return;
    int n = idx % N_;
    int bt = idx / N_;
    float acc = 0.f;
#pragma unroll
    for (int f = 0; f < F_; ++f) acc += lhs_tf[bt * F_ + f] * U2[(size_t)f * N_ + n];
    out[idx] = acc;
}

// rhsT[b,n,t] = sum_f U3[f] * X[b,n,f,t]
__global__ void k_rhsT(const float* __restrict__ X, const float* __restrict__ U3,
                       float* __restrict__ out) {
    int idx = blockIdx.x * 256 + threadIdx.x;
    if (idx >= B_ * N_ * T_) return;
    int t = idx % T_;
    int n = (idx / T_) % N_;
    int b = idx / (N_ * T_);
    const float* xp = X + ((size_t)(b * N_ + n) * F_) * T_ + t;
    float acc = 0.f;
#pragma unroll
    for (int f = 0; f < F_; ++f) acc += U3[f] * xp[f * T_];
    out[idx] = acc;
}

// transpose rhsT [b,n,t] -> rhsTT [b,t,n]
__global__ __launch_bounds__(256) void k_transp(const float* __restrict__ in,
                                                float* __restrict__ outp) {
    __shared__ float s[64 * 25];
    int b = blockIdx.x >> 4;
    int n0 = (blockIdx.x & 15) * 64;
    int tid = threadIdx.x;
    const float* ip = in + ((size_t)b * N_ + n0) * 24;
    for (int q = tid; q < 1536; q += 256) s[(q / 24) * 25 + (q % 24)] = ip[q];
    __syncthreads();
    for (int q = tid; q < 1536; q += 256) {
        int t = q >> 6, n = q & 63;
        outp[((size_t)b * 24 + t) * N_ + n0 + n] = s[n * 25 + t];
    }
}

// sig[b,i,j] = sigmoid( lhsN[b,i,:] . rhsTT[b,j,:] + be[i,j] ); one wave per (b,i,j)
__global__ __launch_bounds__(64) void k_edot(const float* __restrict__ lhsN,
                                             const float* __restrict__ rhsTT,
                                             const float* __restrict__ be,
                                             float* __restrict__ sig) {
    int blk = blockIdx.x;
    int b = blk / 576, ij = blk % 576;
    int i = ij / 24, j = ij % 24;
    int lane = threadIdx.x;
    const float* lp = lhsN + ((size_t)b * 24 + i) * N_;
    const float* rp = rhsTT + ((size_t)b * 24 + j) * N_;
    float acc = 0.f;
#pragma unroll
    for (int n = lane; n < N_; n += 64) acc += lp[n] * rp[n];
    for (int off = 32; off > 0; off >>= 1) acc += __shfl_xor(acc, off);
    if (lane == 0) sig[blk] = 1.f / (1.f + expf(-(acc + be[ij])));
}

// Escore = Ve @ sig, then softmax over rows -> Eatt
__global__ __launch_bounds__(576) void k_eatt2(const float* __restrict__ sig,
                                               const float* __restrict__ Ve,
                                               float* __restrict__ Eatt) {
    __shared__ float ss[T_ * T_];
    __shared__ float esc[T_ * T_];
    int b = blockIdx.x;
    int tid = threadIdx.x;
    ss[tid] = sig[b * 576 + tid];
    __syncthreads();
    int i = tid / T_, j = tid % T_;
    {
        float acc = 0.f;
#pragma unroll
        for (int m = 0; m < T_; ++m) acc += Ve[i * T_ + m] * ss[m * T_ + j];
        esc[tid] = acc;
    }
    __syncthreads();
    if (tid < T_) {
        int jj = tid;
        float mx = -1e30f;
        for (int r = 0; r < T_; ++r) mx = fmaxf(mx, esc[r * T_ + jj]);
        float s = 0.f;
        for (int r = 0; r < T_; ++r) {
            float e = expf(esc[r * T_ + jj] - mx);
            ss[r * T_ + jj] = e;
            s += e;
        }
        float inv = 1.f / s;
        for (int r = 0; r < T_; ++r) Eatt[(size_t)(b * T_ + r) * T_ + jj] = ss[r * T_ + jj] * inv;
    }
}

// Xt[b,nf,t] = sum_k X[b,nf,k] * Eatt[b,k,t]
__global__ void k_xt(const float* __restrict__ X, const float* __restrict__ Eatt,
                     float* __restrict__ Xt) {
    __shared__ float e[T_ * T_];
    const int per_b = N_ * F_ * T_ / 256;  // 3072
    int b = blockIdx.x / per_b;
    int tid = threadIdx.x;
    for (int q = tid; q < T_ * T_; q += 256) e[q] = Eatt[(size_t)b * T_ * T_ + q];
    __syncthreads();
    int off = (blockIdx.x % per_b) * 256 + tid;
    int t = off % T_;
    int nf = off / T_;
    const float* xr = X + ((size_t)b * N_ * F_ + nf) * T_;
    float acc = 0.f;
#pragma unroll
    for (int k = 0; k < T_; ++k) acc += xr[k] * e[k * T_ + t];
    Xt[((size_t)b * N_ * F_ + nf) * T_ + t] = acc;
}

// ---------------- spatial attention ----------------

// slhsF[b,n,f] = sum_t Xt[b,n,f,t] * W1[t]
__global__ void k_slhsF(const float* __restrict__ Xt, const float* __restrict__ W1,
                        float* __restrict__ out) {
    int idx = blockIdx.x * 256 + threadIdx.x;
    if (idx >= B_ * N_ * F_) return;
    const float* xp = Xt + (size_t)idx * T_;
    float acc = 0.f;
#pragma unroll
    for (int t = 0; t < T_; ++t) acc += xp[t] * W1[t];
    out[idx] = acc;
}

// slhs[b,n,t] = sum_f slhsF[b,n,f] * W2[f,t]
__global__ void k_slhs(const float* __restrict__ slhsF, const float* __restrict__ W2,
                       float* __restrict__ out) {
    int idx = blockIdx.x * 256 + threadIdx.x;
    if (idx >= B_ * N_ * T_) return;
    int t = idx % T_;
    int bn = idx / T_;
    float acc = 0.f;
#pragma unroll
    for (int f = 0; f < F_; ++f) acc += slhsF[(size_t)bn * F_ + f] * W2[f * T_ + t];
    out[idx] = acc;
}

// srhs[b,t,n] = sum_f W3[f] * Xt[b,n,f,t]
__global__ void k_srhs(const float* __restrict__ Xt, const float* __restrict__ W3,
                       float* __restrict__ out) {
    int idx = blockIdx.x * 256 + threadIdx.x;
    if (idx >= B_ * N_ * T_) return;
    int t = idx % T_;
    int n = (idx / T_) % N_;
    int b = idx / (N_ * T_);
    const float* xp = Xt + ((size_t)(b * N_ + n) * F_) * T_ + t;
    float acc = 0.f;
#pragma unroll
    for (int f = 0; f < F_; ++f) acc += W3[f] * xp[f * T_];
    out[((size_t)b * T_ + t) * N_ + n] = acc;
}

// Psig tile kernel: Psig[b,i,k] = sigmoid(slhs[b,i,:].srhs[b,:,k] + bs[i,k])  (f32)
// also writes PsigT[b,k,i] in bf16 for the MFMA B-operand.
__global__ __launch_bounds__(256) void k_psig2(const float* __restrict__ slhs,
                                               const float* __restrict__ srhs,
                                               const float* __restrict__ bs,
                                               float* __restrict__ Psig,
                                               __hip_bfloat16* __restrict__ PsigT) {
    __shared__ float sl[64][24];
    __shared__ float sr[24][64];
    __shared__ short st[64][72];
    int b = blockIdx.z;
    int i0 = blockIdx.y * 64, k0 = blockIdx.x * 64;
    int tid = threadIdx.x;
    {
        const float* sp = slhs + ((size_t)b * N_ + i0) * 24;
#pragma unroll
        for (int it = 0; it < 6; ++it) {
            int q = tid + it * 256;
            sl[q / 24][q % 24] = sp[q];
        }
        const float* rp = srhs + (size_t)b * 24 * N_ + k0;
#pragma unroll
        for (int it = 0; it < 6; ++it) {
            int q = tid + it * 256;
            sr[q >> 6][q & 63] = rp[(size_t)(q >> 6) * N_ + (q & 63)];
        }
    }
    __syncthreads();
    int ib = (tid >> 4) * 4;   // 0..60
    int kb = (tid & 15) * 4;   // 0..60
    float acc[4][4];
#pragma unroll
    for (int a = 0; a < 4; ++a) {
        const float4 bv = *(const float4*)(bs + (size_t)(i0 + ib + a) * N_ + k0 + kb);
        acc[a][0] = bv.x; acc[a][1] = bv.y; acc[a][2] = bv.z; acc[a][3] = bv.w;
    }
#pragma unroll
    for (int t = 0; t < 24; ++t) {
        float r0 = sr[t][kb], r1 = sr[t][kb + 1], r2 = sr[t][kb + 2], r3 = sr[t][kb + 3];
#pragma unroll
        for (int a = 0; a < 4; ++a) {
            float lv = sl[ib + a][t];
            acc[a][0] += lv * r0; acc[a][1] += lv * r1; acc[a][2] += lv * r2; acc[a][3] += lv * r3;
        }
    }
#pragma unroll
    for (int a = 0; a < 4; ++a) {
        float4 o;
        o.x = 1.f / (1.f + expf(-acc[a][0]));
        o.y = 1.f / (1.f + expf(-acc[a][1]));
        o.z = 1.f / (1.f + expf(-acc[a][2]));
        o.w = 1.f / (1.f + expf(-acc[a][3]));
        *(float4*)(Psig + (size_t)((size_t)b * N_ + i0 + ib + a) * N_ + k0 + kb) = o;
        st[kb + 0][ib + a] = f2bf(o.x);
        st[kb + 1][ib + a] = f2bf(o.y);
        st[kb + 2][ib + a] = f2bf(o.z);
        st[kb + 3][ib + a] = f2bf(o.w);
    }
    __syncthreads();
    short* op = (short*)PsigT + ((size_t)b * N_ + k0) * N_ + i0;
#pragma unroll
    for (int it = 0; it < 2; ++it) {
        int ch = tid + it * 256;
        int kk = ch >> 3, off = (ch & 7) * 8;
        uint4 u = *(uint4*)&st[kk][off];
        *(uint4*)(op + (size_t)kk * N_ + off) = u;
    }
}

// S[b] = Vs @ Psig[b] via bf16 MFMA. 128x128 tile, 4 waves, BK=32.
__global__ __launch_bounds__(256) void k_smfma(const float* __restrict__ Vs,
                                               const __hip_bfloat16* __restrict__ PsigT,
                                               float* __restrict__ S) {
    __shared__ short Asd[128][40];
    __shared__ short Bsd[128][40];
    const int b = blockIdx.z;
    const int bm = blockIdx.y * 128, bn = blockIdx.x * 128;
    const int tid = threadIdx.x;
    const int lane = tid & 63, wave = tid >> 6;
    const int wr = wave >> 1, wc = wave & 1;
    const int fr = lane & 15, ks = lane >> 4;
    f32x4 acc[4][4] = {};
    const short* PT = (const short*)PsigT + (size_t)b * N_ * N_;
    for (int k0 = 0; k0 < N_; k0 += 32) {
#pragma unroll
        for (int it = 0; it < 4; ++it) {
            int q = tid + it * 256;           // 0..1023
            int row = q >> 3, kk = (q & 7) * 4;
            float4 v = *(const float4*)(Vs + (size_t)(bm + row) * N_ + k0 + kk);
            short4 s4;
            s4.x = f2bf(v.x); s4.y = f2bf(v.y); s4.z = f2bf(v.z); s4.w = f2bf(v.w);
            *(short4*)&Asd[row][kk] = s4;
        }
#pragma unroll
        for (int it = 0; it < 2; ++it) {
            int q = tid + it * 256;           // 0..511
            int row = q >> 2, kk = (q & 3) * 8;
            uint4 u = *(const uint4*)(PT + (size_t)(bn + row) * N_ + k0 + kk);
            *(uint4*)&Bsd[row][kk] = u;
        }
        __syncthreads();
        bf16x8 a[4], bf[4];
#pragma unroll
        for (int m = 0; m < 4; ++m) a[m] = *(const bf16x8*)&Asd[wr * 64 + m * 16 + fr][ks * 8];
#pragma unroll
        for (int n = 0; n < 4; ++n) bf[n] = *(const bf16x8*)&Bsd[wc * 64 + n * 16 + fr][ks * 8];
#pragma unroll
        for (int m = 0; m < 4; ++m)
#pragma unroll
            for (int n = 0; n < 4; ++n)
                acc[m][n] = __builtin_amdgcn_mfma_f32_16x16x32_bf16(a[m], bf[n], acc[m][n], 0, 0, 0);
        __syncthreads();
    }
    float* Sb = S + (size_t)b * N_ * N_;
#pragma unroll
    for (int m = 0; m < 4; ++m)
#pragma unroll
        for (int n = 0; n < 4; ++n) {
#pragma unroll
            for (int j = 0; j < 4; ++j) {
                int row = bm + wr * 64 + m * 16 + (lane >> 4) * 4 + j;
                int col = bn + wc * 64 + n * 16 + (lane & 15);
                Sb[(size_t)row * N_ + col] = acc[m][n][j];
            }
        }
}

// ---------------- softmax stats (no full normalize pass) ----------------
__global__ __launch_bounds__(256) void k_smpart(const float* __restrict__ S,
                                                float* __restrict__ pmax,
                                                float* __restrict__ psum) {
    __shared__ float tile[128][64];
    __shared__ float redm[4][64];
    __shared__ float reds[4][64];
    int b = blockIdx.z;
    int chunk = blockIdx.y;   // 0..7
    int cg = blockIdx.x;      // 0..15
    int tid = threadIdx.x;
    const float* Sb = S + (size_t)b * N_ * N_ + (size_t)(chunk * 128) * N_ + cg * 64;
    for (int q = tid; q < 8192; q += 256) {
        int r = q >> 6, c = q & 63;
        tile[r][c] = Sb[(size_t)r * N_ + c];
    }
    __syncthreads();
    int c = tid & 63, grp = tid >> 6;
    float m = -1e30f;
    for (int r = grp; r < 128; r += 4) m = fmaxf(m, tile[r][c]);
    redm[grp][c] = m;
    __syncthreads();
    m = fmaxf(fmaxf(redm[0][c], redm[1][c]), fmaxf(redm[2][c], redm[3][c]));
    float s = 0.f;
    for (int r = grp; r < 128; r += 4) s += __expf(tile[r][c] - m);
    reds[grp][c] = s;
    __syncthreads();
    if (grp == 0) {
        s = reds[0][c] + reds[1][c] + reds[2][c] + reds[3][c];
        size_t o = ((size_t)b * 8 + chunk) * N_ + cg * 64 + c;
        pmax[o] = m;
        psum[o] = s;
    }
}

__global__ __launch_bounds__(1024) void k_smcomb(const float* __restrict__ pmax,
                                                 const float* __restrict__ psum,
                                                 float* __restrict__ colMax,
                                                 float* __restrict__ colInv) {
    int b = blockIdx.x;
    int col = threadIdx.x;
    float M = -1e30f;
#pragma unroll
    for (int ch = 0; ch < 8; ++ch) M = fmaxf(M, pmax[((size_t)b * 8 + ch) * N_ + col]);
    float s = 0.f;
#pragma unroll
    for (int ch = 0; ch < 8; ++ch)
        s += psum[((size_t)b * 8 + ch) * N_ + col] *
             __expf(pmax[((size_t)b * 8 + ch) * N_ + col] - M);
    colMax[(size_t)b * N_ + col] = M;
    colInv[(size_t)b * N_ + col] = 1.f / s;
}

// ---------------- graph: CSR build + normalization ----------------

__global__ void k_count(const int* __restrict__ rowI, const int* __restrict__ colI,
                        int* __restrict__ cnt, float* __restrict__ deg) {
    int e = blockIdx.x * 256 + threadIdx.x;
    if (e >= E_) return;
    int r = rowI[e];
    atomicAdd(&cnt[r], 1);
    if (r != colI[e]) atomicAdd(&deg[r], 1.0f);
}

__global__ __launch_bounds__(1024) void k_scan(const int* __restrict__ cnt,
                                               const float* __restrict__ deg,
                                               int* __restrict__ rowPtr,
                                               int* __restrict__ fillPos,
                                               float* __restrict__ dis) {
    __shared__ int s[N_];
    int tid = threadIdx.x;
    int my = cnt[tid];
    s[tid] = my;
    __syncthreads();
    for (int off = 1; off < N_; off <<= 1) {
        int v = 0;
        if (tid >= off) v = s[tid - off];
        __syncthreads();
        s[tid] += v;
        __syncthreads();
    }
    rowPtr[tid + 1] = s[tid];
    if (tid == 0) rowPtr[0] = 0;
    fillPos[tid] = s[tid] - my;
    float d = deg[tid];
    dis[tid] = d > 0.f ? rsqrtf(d) : 0.f;
}

__global__ void k_fill(const int* __restrict__ rowI, const int* __restrict__ colI,
                       int* __restrict__ fillPos, int* __restrict__ csrRow,
                       int* __restrict__ csrCol) {
    int e = blockIdx.x * 256 + threadIdx.x;
    if (e >= E_) return;
    int r = rowI[e];
    int pos = atomicAdd(&fillPos[r], 1);
    csrRow[pos] = r;
    csrCol[pos] = colI[e];
}

// softmax applied on the fly at the consumed entries
__global__ void k_csrcoef(const int* __restrict__ csrRow, const int* __restrict__ csrCol,
                          const float* __restrict__ dis, const float* __restrict__ S,
                          const float* __restrict__ colMax, const float* __restrict__ colInv,
                          float* __restrict__ csrNorm, float* __restrict__ csrAttn) {
    int p = blockIdx.x * 256 + threadIdx.x;
    if (p >= E_) return;
    int r = csrRow[p], c = csrCol[p];
    float nm = (r == c) ? 0.f : -dis[r] * dis[c];
    csrNorm[p] = nm;
    size_t off = (size_t)r * N_ + c;
#pragma unroll
    for (int b = 0; b < B_; ++b) {
        float sv = __expf(S[(size_t)b * N_ * N_ + off] - colMax[(size_t)b * N_ + c]) *
                   colInv[(size_t)b * N_ + c];
        csrAttn[(size_t)b * E_ + p] = nm * sv;
    }
}

__global__ void k_diag(const float* __restrict__ S, const float* __restrict__ colMax,
                       const float* __restrict__ colInv, float* __restrict__ diagS) {
    int idx = blockIdx.x * 256 + threadIdx.x;
    if (idx >= B_ * N_) return;
    int n = idx % N_;
    int b = idx / N_;
    float sv = __expf(S[(size_t)b * N_ * N_ + (size_t)n * N_ + n] - colMax[(size_t)b * N_ + n]) *
               colInv[(size_t)b * N_ + n];
    diagS[idx] = sv;
}

// Tx0 = diagS * X
__global__ void k_tx0(const float* __restrict__ X, const float* __restrict__ diagS,
                      float* __restrict__ Tx0) {
    int idx = blockIdx.x * 256 + threadIdx.x;
    if (idx >= B_ * N_ * F_ * T_) return;
    int bn = idx / (F_ * T_);
    Tx0[idx] = diagS[bn] * X[idx];
}

// gather propagation: Tout[b,n,:] = scale * sum_{p in csr row n} coef[p] * Tin[b,csrCol[p],:]
__global__ __launch_bounds__(192) void k_gprop(const float* __restrict__ Tin,
                                               const float* __restrict__ Tsub,
                                               float* __restrict__ Tout,
                                               const float* __restrict__ coef,
                                               const int* __restrict__ csrCol,
                                               const int* __restrict__ rowPtr,
                                               int perB, float scale, int hasSub) {
    int blk = blockIdx.x;
    int b = blk & 7;
    int n = blk >> 3;
    int tid = threadIdx.x;
    int s = rowPtr[n], e = rowPtr[n + 1];
    const float* cbase = coef + (perB ? (size_t)b * E_ : 0);
    float ax = 0.f, ay = 0.f, az = 0.f, aw = 0.f;
    for (int p = s; p < e; ++p) {
        float cf = cbase[p];
        const float4 v =
            *(const float4*)(Tin + ((size_t)(b * N_ + csrCol[p]) * (F_ * T_)) + tid * 4);
        ax += cf * v.x;
        ay += cf * v.y;
        az += cf * v.z;
        aw += cf * v.w;
    }
    size_t obase = (size_t)(b * N_ + n) * (F_ * T_) + tid * 4;
    float4 r;
    r.x = ax * scale;
    r.y = ay * scale;
    r.z = az * scale;
    r.w = aw * scale;
    if (hasSub) {
        const float4 u = *(const float4*)(Tsub + obase);
        r.x -= u.x;
        r.y -= u.y;
        r.z -= u.z;
        r.w -= u.w;
    }
    *(float4*)(Tout + obase) = r;
}

// ---------------- fused tail: cheb GEMM -> relu -> conv GEMM -> relu -> LN ----------------
// block = 4 sites (96 rows x 64 cols). rows g = site*24 + t.
__global__ __launch_bounds__(256) void k_tail(const float* __restrict__ Tx0,
                                              const float* __restrict__ Tx1,
                                              const float* __restrict__ Tx2,
                                              const float* __restrict__ X,
                                              const float* __restrict__ chW,
                                              const float* __restrict__ chb,
                                              const float* __restrict__ tw,
                                              const float* __restrict__ rw,
                                              const float* __restrict__ tb,
                                              const float* __restrict__ rb,
                                              const float* __restrict__ lng,
                                              const float* __restrict__ lnb,
                                              float* __restrict__ out) {
    __shared__ float As[16][96];
    __shared__ float Bs[16][64];
    __shared__ float pool[6656];  // Xhat [4][64][26] (t padded), later z [96][67]
    const int tid = threadIdx.x;
    const int site0 = blockIdx.x * 4;
    const int tm = (tid >> 4) * 6;  // 6 rows/thread
    const int tn = (tid & 15) * 4;  // 4 cols/thread

    // zero pool (provides conv t-halo zeros)
    for (int q = tid; q < 6656; q += 256) pool[q] = 0.f;

    float chb_r[4], tbrb[4], gam[4], bet[4];
#pragma unroll
    for (int j = 0; j < 4; ++j) {
        chb_r[j] = chb[tn + j];
        tbrb[j] = tb[tn + j] + rb[tn + j];
        gam[j] = lng[tn + j];
        bet[j] = lnb[tn + j];
    }

    float acc[6][4];
#pragma unroll
    for (int i = 0; i < 6; ++i)
#pragma unroll
        for (int j = 0; j < 4; ++j) acc[i][j] = 0.f;

    // ---- cheb GEMM: K=96, chunks of 16; chunk kc uses one Tx tensor ----
    for (int kc = 0; kc < 6; ++kc) {
        const float* Tsel = (kc < 2) ? Tx0 : (kc < 4) ? Tx1 : Tx2;
        const int fbase = (kc & 1) * 16;
        __syncthreads();
#pragma unroll
        for (int it = 0; it < 6; ++it) {
            int q = tid + it * 256;
            int k = q / 96, m = q - k * 96;
            int ls = m / 24, t = m - ls * 24;
            As[k][m] = Tsel[(size_t)(site0 + ls) * 768 + (fbase + k) * 24 + t];
        }
#pragma unroll
        for (int it = 0; it < 4; ++it) {
            int q = tid + it * 256;
            ((float*)Bs)[q] = chW[kc * 1024 + q];
        }
        __syncthreads();
#pragma unroll
        for (int k = 0; k < 16; ++k) {
            float b0 = Bs[k][tn], b1 = Bs[k][tn + 1], b2 = Bs[k][tn + 2], b3 = Bs[k][tn + 3];
#pragma unroll
            for (int i = 0; i < 6; ++i) {
                float a = As[k][tm + i];
                acc[i][0] += a * b0; acc[i][1] += a * b1; acc[i][2] += a * b2; acc[i][3] += a * b3;
            }
        }
    }
    // Xhat -> pool with bias+relu; reset acc for conv
    __syncthreads();
#pragma unroll
    for (int i = 0; i < 6; ++i) {
        int r = tm + i;
        int ls = r / 24, t = r - ls * 24;
#pragma unroll
        for (int j = 0; j < 4; ++j) {
            pool[ls * 1664 + (tn + j) * 26 + 1 + t] = fmaxf(acc[i][j] + chb_r[j], 0.f);
            acc[i][j] = tbrb[j];
        }
    }
    __syncthreads();

    // ---- conv GEMM: K=224 (192 im2col Xhat from LDS + 32 residual X) ----
    for (int kc = 0; kc < 14; ++kc) {
        const int k0 = kc * 16;
#pragma unroll
        for (int it = 0; it < 6; ++it) {
            int q = tid + it * 256;
            int k = q / 96, m = q - k * 96;
            int ls = m / 24, t = m - ls * 24;
            int kk = k0 + k;
            float v;
            if (kk < 192) {
                int ci = kk / 3, dt = kk - ci * 3;
                v = pool[ls * 1664 + ci * 26 + t + dt];  // (1 + t + dt - 1)
            } else {
                v = X[(size_t)(site0 + ls) * 768 + (kk - 192) * 24 + t];
            }
            As[k][m] = v;
        }
#pragma unroll
        for (int it = 0; it < 4; ++it) {
            int q = tid + it * 256;
            int co = q & 63, k = q >> 6;
            int kk = k0 + k;
            float w;
            if (kk < 192) {
                int ci = kk / 3, dt = kk - ci * 3;
                w = tw[(co * CC_ + ci) * 3 + dt];
            } else {
                w = rw[co * F_ + kk - 192];
            }
            Bs[k][co] = w;
        }
        __syncthreads();
#pragma unroll
        for (int k = 0; k < 16; ++k) {
            float b0 = Bs[k][tn], b1 = Bs[k][tn + 1], b2 = Bs[k][tn + 2], b3 = Bs[k][tn + 3];
#pragma unroll
            for (int i = 0; i < 6; ++i) {
                float a = As[k][tm + i];
                acc[i][0] += a * b0; acc[i][1] += a * b1; acc[i][2] += a * b2; acc[i][3] += a * b3;
            }
        }
        __syncthreads();
    }

    // ---- relu + LN over 64 channels per row (16-lane shfl groups) ----
#pragma unroll
    for (int i = 0; i < 6; ++i) {
        float z0 = fmaxf(acc[i][0], 0.f), z1 = fmaxf(acc[i][1], 0.f);
        float z2 = fmaxf(acc[i][2], 0.f), z3 = fmaxf(acc[i][3], 0.f);
        float s1 = z0 + z1 + z2 + z3;
        float s2 = z0 * z0 + z1 * z1 + z2 * z2 + z3 * z3;
#pragma unroll
        for (int off = 1; off < 16; off <<= 1) {
            s1 += __shfl_xor(s1, off);
            s2 += __shfl_xor(s2, off);
        }
        float mu = s1 * (1.f / 64.f);
        float var = s2 * (1.f / 64.f) - mu * mu;
        float rs = rsqrtf(var + LN_EPS_);
        acc[i][0] = (z0 - mu) * rs * gam[0] + bet[0];
        acc[i][1] = (z1 - mu) * rs * gam[1] + bet[1];
        acc[i][2] = (z2 - mu) * rs * gam[2] + bet[2];
        acc[i][3] = (z3 - mu) * rs * gam[3] + bet[3];
    }
    // stage z (pool is dead: last staging read completed before prior sync)
#pragma unroll
    for (int i = 0; i < 6; ++i)
#pragma unroll
        for (int j = 0; j < 4; ++j) pool[(tm + i) * 67 + tn + j] = acc[i][j];
    __syncthreads();
    // coalesced write: out[site][co][t]
    float* ob = out + (size_t)site0 * 1536;
    for (int q = tid; q < 6144; q += 256) {
        int ls = q / 1536, rem = q - ls * 1536;
        int co = rem / 24, t = rem - co * 24;
        ob[q] = pool[(ls * 24 + t) * 67 + co];
    }
}

extern "C" void kernel_launch(void* const* d_in, const int* in_sizes, int n_in,
                              void* d_out, int out_size, void* d_ws, size_t ws_size,
                              hipStream_t stream) {
    const float* X = (const float*)d_in[0];
    const int* ei = (const int*)d_in[1];
    const float* U1 = (const float*)d_in[2];
    const float* U2 = (const float*)d_in[3];
    const float* U3 = (const float*)d_in[4];
    const float* be = (const float*)d_in[5];
    const float* Ve = (const float*)d_in[6];
    const float* W1 = (const float*)d_in[7];
    const float* W2 = (const float*)d_in[8];
    const float* W3 = (const float*)d_in[9];
    const float* bs = (const float*)d_in[10];
    const float* Vs = (const float*)d_in[11];
    const float* chW = (const float*)d_in[12];
    const float* chb = (const float*)d_in[13];
    const float* tw = (const float*)d_in[14];
    const float* tb = (const float*)d_in[15];
    const float* rw = (const float*)d_in[16];
    const float* rb = (const float*)d_in[17];
    const float* lng = (const float*)d_in[18];
    const float* lnb = (const float*)d_in[19];
    float* out = (float*)d_out;
    float* ws = (float*)d_ws;

    size_t o = 0;
    float* lhs_tf = ws + o; o += B_ * T_ * F_;
    float* lhsN  = ws + o; o += (size_t)B_ * T_ * N_;
    float* rhsT  = ws + o; o += (size_t)B_ * N_ * T_;
    float* rhsTT = ws + o; o += (size_t)B_ * T_ * N_;
    float* sigE  = ws + o; o += B_ * T_ * T_;
    float* Eatt  = ws + o; o += B_ * T_ * T_;
    float* slhsF = ws + o; o += (size_t)B_ * N_ * F_;
    float* slhs  = ws + o; o += (size_t)B_ * N_ * T_;
    float* srhs  = ws + o; o += (size_t)B_ * T_ * N_;
    float* deg   = ws + o; o += N_;
    float* dis   = ws + o; o += N_;
    float* diagS = ws + o; o += B_ * N_;
    float* csrNorm = ws + o; o += E_;
    float* csrAttn = ws + o; o += (size_t)B_ * E_;
    float* pmax  = ws + o; o += (size_t)B_ * 8 * N_;
    float* psum  = ws + o; o += (size_t)B_ * 8 * N_;
    float* colMax = ws + o; o += (size_t)B_ * N_;
    float* colInv = ws + o; o += (size_t)B_ * N_;
    int* cnt     = (int*)(ws + o); o += N_;
    int* rowPtr  = (int*)(ws + o); o += N_ + 1;
    int* fillPos = (int*)(ws + o); o += N_;
    int* csrRow  = (int*)(ws + o); o += E_;
    int* csrCol  = (int*)(ws + o); o += E_ + 3;  // +3: keep later buffers 16B-aligned
    float* Xt    = ws + o; o += (size_t)B_ * N_ * F_ * T_;  // later reused as Tx2
    float* Psig  = ws + o; o += (size_t)B_ * N_ * N_;       // later Tx0
    float* S     = ws + o; o += (size_t)B_ * N_ * N_;       // later Tx1
    float* Xhat  = ws + o; o += (size_t)B_ * N_ * CC_ * T_; // only used as PsigT overlay now
    float* Tx0 = Psig;
    float* Tx1 = S;
    float* Tx2 = Xt;
    __hip_bfloat16* PsigT = (__hip_bfloat16*)Xhat;
    const int* rowI = ei;
    const int* colI = ei + E_;

    // CSR build (independent of attention pipeline)
    hipMemsetAsync(cnt, 0, N_ * sizeof(int), stream);
    hipMemsetAsync(deg, 0, N_ * sizeof(float), stream);
    k_count<<<(E_ + 255) / 256, 256, 0, stream>>>(rowI, colI, cnt, deg);
    k_scan<<<1, 1024, 0, stream>>>(cnt, deg, rowPtr, fillPos, dis);
    k_fill<<<(E_ + 255) / 256, 256, 0, stream>>>(rowI, colI, fillPos, csrRow, csrCol);

    // temporal attention
    hipMemsetAsync(lhs_tf, 0, B_ * T_ * F_ * sizeof(float), stream);
    k_lhs2<<<B_ * 16, 768, 0, stream>>>(X, U1, lhs_tf);
    k_lhsN<<<(B_ * T_ * N_ + 255) / 256, 256, 0, stream>>>(lhs_tf, U2, lhsN);
    k_rhsT<<<(B_ * N_ * T_ + 255) / 256, 256, 0, stream>>>(X, U3, rhsT);
    k_transp<<<B_ * 16, 256, 0, stream>>>(rhsT, rhsTT);
    k_edot<<<B_ * T_ * T_, 64, 0, stream>>>(lhsN, rhsTT, be, sigE);
    k_eatt2<<<B_, 576, 0, stream>>>(sigE, Ve, Eatt);
    k_xt<<<B_ * (N_ * F_ * T_ / 256), 256, 0, stream>>>(X, Eatt, Xt);
    // spatial attention
    k_slhsF<<<(B_ * N_ * F_ + 255) / 256, 256, 0, stream>>>(Xt, W1, slhsF);
    k_slhs<<<(B_ * N_ * T_ + 255) / 256, 256, 0, stream>>>(slhsF, W2, slhs);
    k_srhs<<<(B_ * N_ * T_ + 255) / 256, 256, 0, stream>>>(Xt, W3, srhs);
    {
        dim3 g(16, 16, B_);
        k_psig2<<<g, 256, 0, stream>>>(slhs, srhs, bs, Psig, PsigT);
    }
    {
        dim3 g(8, 8, B_);
        k_smfma<<<g, 256, 0, stream>>>(Vs, PsigT, S);
    }
    // softmax stats only
    {
        dim3 g(16, 8, B_);
        k_smpart<<<g, 256, 0, stream>>>(S, pmax, psum);
    }
    k_smcomb<<<B_, 1024, 0, stream>>>(pmax, psum, colMax, colInv);
    // coefficients in CSR order (softmax applied on the fly)
    k_csrcoef<<<(E_ + 255) / 256, 256, 0, stream>>>(csrRow, csrCol, dis, S, colMax, colInv,
                                                    csrNorm, csrAttn);
    k_diag<<<(B_ * N_ + 255) / 256, 256, 0, stream>>>(S, colMax, colInv, diagS);
    // chebyshev propagation (gather, no atomics)
    k_tx0<<<(B_ * N_ * F_ * T_ + 255) / 256, 256, 0, stream>>>(X, diagS, Tx0);
    k_gprop<<<B_ * N_, 192, 0, stream>>>(Tx0, nullptr, Tx1, csrAttn, csrCol, rowPtr, 1, 1.0f, 0);
    k_gprop<<<B_ * N_, 192, 0, stream>>>(Tx1, Tx0, Tx2, csrNorm, csrCol, rowPtr, 0, 2.0f, 1);
    // fused tail: cheb + time conv + residual + layernorm
    k_tail<<<B_ * N_ / 4, 256, 0, stream>>>(Tx0, Tx1, Tx2, X, chW, chb, tw, rw, tb, rb,
                                            lng, lnb, out);
}

// Round 9
// 507.143 us; speedup vs baseline: 8.7148x; 1.0857x over previous
//
#include <hip/hip_runtime.h>
#include <hip/hip_bf16.h>
#include <math.h>

#define B_ 8
#define N_ 1024
#define F_ 32
#define T_ 24
#define E_ 16384
#define CC_ 64
#define CT_ 64
#define LN_EPS_ 1e-5f

typedef __attribute__((ext_vector_type(8))) short bf16x8;
typedef __attribute__((ext_vector_type(4))) float f32x4;

__device__ __forceinline__ short f2bf(float f) {
    union { float f; unsigned u; } v; v.f = f;
    unsigned r = v.u + 0x7fffu + ((v.u >> 16) & 1u);  // RNE
    return (short)(r >> 16);
}

// ---------------- temporal attention ----------------

// lhs_tf[b,t,f] (stored [b][t*32+f]) = sum_n X[b,n,f,t] * U1[n]
__global__ __launch_bounds__(768) void k_lhs2(const float* __restrict__ X,
                                              const float* __restrict__ U1,
                                              float* __restrict__ out) {
    __shared__ float su[64];
    int b = blockIdx.x >> 4;
    int n0 = (blockIdx.x & 15) * 64;
    int tid = threadIdx.x;
    if (tid < 64) su[tid] = U1[n0 + tid];
    __syncthreads();
    float acc = 0.f;
    const float* xp = X + ((size_t)b * N_ + n0) * 768 + tid;
#pragma unroll 8
    for (int i = 0; i < 64; ++i) acc += xp[(size_t)i * 768] * su[i];
    int f = tid / 24, t = tid - (tid / 24) * 24;
    atomicAdd(&out[b * 768 + t * 32 + f], acc);
}

// lhsN[b,t,n] = sum_f lhs_tf[b,t,f] * U2[f,n]
__global__ void k_lhsN(const float* __restrict__ lhs_tf, const float* __restrict__ U2,
                       float* __restrict__ out) {
    int idx = blockIdx.x * 256 + threadIdx.x;
    if (idx >= B_ * T_ * N_) return;
    int n = idx % N_;
    int bt = idx / N_;
    float acc = 0.f;
#pragma unroll
    for (int f = 0; f < F_; ++f) acc += lhs_tf[bt * F_ + f] * U2[(size_t)f * N_ + n];
    out[idx] = acc;
}

// rhsT[b,n,t] = sum_f U3[f] * X[b,n,f,t]
__global__ void k_rhsT(const float* __restrict__ X, const float* __restrict__ U3,
                       float* __restrict__ out) {
    int idx = blockIdx.x * 256 + threadIdx.x;
    if (idx >= B_ * N_ * T_) return;
    int t = idx % T_;
    int n = (idx / T_) % N_;
    int b = idx / (N_ * T_);
    const float* xp = X + ((size_t)(b * N_ + n) * F_) * T_ + t;
    float acc = 0.f;
#pragma unroll
    for (int f = 0; f < F_; ++f) acc += U3[f] * xp[f * T_];
    out[idx] = acc;
}

// transpose rhsT [b,n,t] -> rhsTT [b,t,n]
__global__ __launch_bounds__(256) void k_transp(const float* __restrict__ in,
                                                float* __restrict__ outp) {
    __shared__ float s[64 * 25];
    int b = blockIdx.x >> 4;
    int n0 = (blockIdx.x & 15) * 64;
    int tid = threadIdx.x;
    const float* ip = in + ((size_t)b * N_ + n0) * 24;
    for (int q = tid; q < 1536; q += 256) s[(q / 24) * 25 + (q % 24)] = ip[q];
    __syncthreads();
    for (int q = tid; q < 1536; q += 256) {
        int t = q >> 6, n = q & 63;
        outp[((size_t)b * 24 + t) * N_ + n0 + n] = s[n * 25 + t];
    }
}

// sig[b,i,j] = sigmoid( lhsN[b,i,:] . rhsTT[b,j,:] + be[i,j] ); one wave per (b,i,j)
__global__ __launch_bounds__(64) void k_edot(const float* __restrict__ lhsN,
                                             const float* __restrict__ rhsTT,
                                             const float* __restrict__ be,
                                             float* __restrict__ sig) {
    int blk = blockIdx.x;
    int b = blk / 576, ij = blk % 576;
    int i = ij / 24, j = ij % 24;
    int lane = threadIdx.x;
    const float* lp = lhsN + ((size_t)b * 24 + i) * N_;
    const float* rp = rhsTT + ((size_t)b * 24 + j) * N_;
    float acc = 0.f;
#pragma unroll
    for (int n = lane; n < N_; n += 64) acc += lp[n] * rp[n];
    for (int off = 32; off > 0; off >>= 1) acc += __shfl_xor(acc, off);
    if (lane == 0) sig[blk] = 1.f / (1.f + expf(-(acc + be[ij])));
}

// Escore = Ve @ sig, then softmax over rows -> Eatt
__global__ __launch_bounds__(576) void k_eatt2(const float* __restrict__ sig,
                                               const float* __restrict__ Ve,
                                               float* __restrict__ Eatt) {
    __shared__ float ss[T_ * T_];
    __shared__ float esc[T_ * T_];
    int b = blockIdx.x;
    int tid = threadIdx.x;
    ss[tid] = sig[b * 576 + tid];
    __syncthreads();
    int i = tid / T_, j = tid % T_;
    {
        float acc = 0.f;
#pragma unroll
        for (int m = 0; m < T_; ++m) acc += Ve[i * T_ + m] * ss[m * T_ + j];
        esc[tid] = acc;
    }
    __syncthreads();
    if (tid < T_) {
        int jj = tid;
        float mx = -1e30f;
        for (int r = 0; r < T_; ++r) mx = fmaxf(mx, esc[r * T_ + jj]);
        float s = 0.f;
        for (int r = 0; r < T_; ++r) {
            float e = expf(esc[r * T_ + jj] - mx);
            ss[r * T_ + jj] = e;
            s += e;
        }
        float inv = 1.f / s;
        for (int r = 0; r < T_; ++r) Eatt[(size_t)(b * T_ + r) * T_ + jj] = ss[r * T_ + jj] * inv;
    }
}

// Xt[b,nf,t] = sum_k X[b,nf,k] * Eatt[b,k,t]
__global__ void k_xt(const float* __restrict__ X, const float* __restrict__ Eatt,
                     float* __restrict__ Xt) {
    __shared__ float e[T_ * T_];
    const int per_b = N_ * F_ * T_ / 256;  // 3072
    int b = blockIdx.x / per_b;
    int tid = threadIdx.x;
    for (int q = tid; q < T_ * T_; q += 256) e[q] = Eatt[(size_t)b * T_ * T_ + q];
    __syncthreads();
    int off = (blockIdx.x % per_b) * 256 + tid;
    int t = off % T_;
    int nf = off / T_;
    const float* xr = X + ((size_t)b * N_ * F_ + nf) * T_;
    float acc = 0.f;
#pragma unroll
    for (int k = 0; k < T_; ++k) acc += xr[k] * e[k * T_ + t];
    Xt[((size_t)b * N_ * F_ + nf) * T_ + t] = acc;
}

// ---------------- spatial attention ----------------

// slhsF[b,n,f] = sum_t Xt[b,n,f,t] * W1[t]
__global__ void k_slhsF(const float* __restrict__ Xt, const float* __restrict__ W1,
                        float* __restrict__ out) {
    int idx = blockIdx.x * 256 + threadIdx.x;
    if (idx >= B_ * N_ * F_) return;
    const float* xp = Xt + (size_t)idx * T_;
    float acc = 0.f;
#pragma unroll
    for (int t = 0; t < T_; ++t) acc += xp[t] * W1[t];
    out[idx] = acc;
}

// slhs[b,n,t] = sum_f slhsF[b,n,f] * W2[f,t]
__global__ void k_slhs(const float* __restrict__ slhsF, const float* __restrict__ W2,
                       float* __restrict__ out) {
    int idx = blockIdx.x * 256 + threadIdx.x;
    if (idx >= B_ * N_ * T_) return;
    int t = idx % T_;
    int bn = idx / T_;
    float acc = 0.f;
#pragma unroll
    for (int f = 0; f < F_; ++f) acc += slhsF[(size_t)bn * F_ + f] * W2[f * T_ + t];
    out[idx] = acc;
}

// srhs[b,t,n] = sum_f W3[f] * Xt[b,n,f,t]
__global__ void k_srhs(const float* __restrict__ Xt, const float* __restrict__ W3,
                       float* __restrict__ out) {
    int idx = blockIdx.x * 256 + threadIdx.x;
    if (idx >= B_ * N_ * T_) return;
    int t = idx % T_;
    int n = (idx / T_) % N_;
    int b = idx / (N_ * T_);
    const float* xp = Xt + ((size_t)(b * N_ + n) * F_) * T_ + t;
    float acc = 0.f;
#pragma unroll
    for (int f = 0; f < F_; ++f) acc += W3[f] * xp[f * T_];
    out[((size_t)b * T_ + t) * N_ + n] = acc;
}

// Psig tile kernel: Psig[b,i,k] = sigmoid(slhs[b,i,:].srhs[b,:,k] + bs[i,k])  (f32)
// also writes PsigT[b,k,i] in bf16 for the MFMA B-operand.
__global__ __launch_bounds__(256) void k_psig2(const float* __restrict__ slhs,
                                               const float* __restrict__ srhs,
                                               const float* __restrict__ bs,
                                               float* __restrict__ Psig,
                                               __hip_bfloat16* __restrict__ PsigT) {
    __shared__ float sl[64][24];
    __shared__ float sr[24][64];
    __shared__ short st[64][72];
    int b = blockIdx.z;
    int i0 = blockIdx.y * 64, k0 = blockIdx.x * 64;
    int tid = threadIdx.x;
    {
        const float* sp = slhs + ((size_t)b * N_ + i0) * 24;
#pragma unroll
        for (int it = 0; it < 6; ++it) {
            int q = tid + it * 256;
            sl[q / 24][q % 24] = sp[q];
        }
        const float* rp = srhs + (size_t)b * 24 * N_ + k0;
#pragma unroll
        for (int it = 0; it < 6; ++it) {
            int q = tid + it * 256;
            sr[q >> 6][q & 63] = rp[(size_t)(q >> 6) * N_ + (q & 63)];
        }
    }
    __syncthreads();
    int ib = (tid >> 4) * 4;   // 0..60
    int kb = (tid & 15) * 4;   // 0..60
    float acc[4][4];
#pragma unroll
    for (int a = 0; a < 4; ++a) {
        const float4 bv = *(const float4*)(bs + (size_t)(i0 + ib + a) * N_ + k0 + kb);
        acc[a][0] = bv.x; acc[a][1] = bv.y; acc[a][2] = bv.z; acc[a][3] = bv.w;
    }
#pragma unroll
    for (int t = 0; t < 24; ++t) {
        float r0 = sr[t][kb], r1 = sr[t][kb + 1], r2 = sr[t][kb + 2], r3 = sr[t][kb + 3];
#pragma unroll
        for (int a = 0; a < 4; ++a) {
            float lv = sl[ib + a][t];
            acc[a][0] += lv * r0; acc[a][1] += lv * r1; acc[a][2] += lv * r2; acc[a][3] += lv * r3;
        }
    }
#pragma unroll
    for (int a = 0; a < 4; ++a) {
        float4 o;
        o.x = 1.f / (1.f + expf(-acc[a][0]));
        o.y = 1.f / (1.f + expf(-acc[a][1]));
        o.z = 1.f / (1.f + expf(-acc[a][2]));
        o.w = 1.f / (1.f + expf(-acc[a][3]));
        *(float4*)(Psig + (size_t)((size_t)b * N_ + i0 + ib + a) * N_ + k0 + kb) = o;
        st[kb + 0][ib + a] = f2bf(o.x);
        st[kb + 1][ib + a] = f2bf(o.y);
        st[kb + 2][ib + a] = f2bf(o.z);
        st[kb + 3][ib + a] = f2bf(o.w);
    }
    __syncthreads();
    short* op = (short*)PsigT + ((size_t)b * N_ + k0) * N_ + i0;
#pragma unroll
    for (int it = 0; it < 2; ++it) {
        int ch = tid + it * 256;
        int kk = ch >> 3, off = (ch & 7) * 8;
        uint4 u = *(uint4*)&st[kk][off];
        *(uint4*)(op + (size_t)kk * N_ + off) = u;
    }
}

// S[b] = Vs @ Psig[b] via bf16 MFMA. 128x128 tile, 4 waves, BK=32.
__global__ __launch_bounds__(256) void k_smfma(const float* __restrict__ Vs,
                                               const __hip_bfloat16* __restrict__ PsigT,
                                               float* __restrict__ S) {
    __shared__ short Asd[128][40];
    __shared__ short Bsd[128][40];
    const int b = blockIdx.z;
    const int bm = blockIdx.y * 128, bn = blockIdx.x * 128;
    const int tid = threadIdx.x;
    const int lane = tid & 63, wave = tid >> 6;
    const int wr = wave >> 1, wc = wave & 1;
    const int fr = lane & 15, ks = lane >> 4;
    f32x4 acc[4][4] = {};
    const short* PT = (const short*)PsigT + (size_t)b * N_ * N_;
    for (int k0 = 0; k0 < N_; k0 += 32) {
#pragma unroll
        for (int it = 0; it < 4; ++it) {
            int q = tid + it * 256;           // 0..1023
            int row = q >> 3, kk = (q & 7) * 4;
            float4 v = *(const float4*)(Vs + (size_t)(bm + row) * N_ + k0 + kk);
            short4 s4;
            s4.x = f2bf(v.x); s4.y = f2bf(v.y); s4.z = f2bf(v.z); s4.w = f2bf(v.w);
            *(short4*)&Asd[row][kk] = s4;
        }
#pragma unroll
        for (int it = 0; it < 2; ++it) {
            int q = tid + it * 256;           // 0..511
            int row = q >> 2, kk = (q & 3) * 8;
            uint4 u = *(const uint4*)(PT + (size_t)(bn + row) * N_ + k0 + kk);
            *(uint4*)&Bsd[row][kk] = u;
        }
        __syncthreads();
        bf16x8 a[4], bf[4];
#pragma unroll
        for (int m = 0; m < 4; ++m) a[m] = *(const bf16x8*)&Asd[wr * 64 + m * 16 + fr][ks * 8];
#pragma unroll
        for (int n = 0; n < 4; ++n) bf[n] = *(const bf16x8*)&Bsd[wc * 64 + n * 16 + fr][ks * 8];
#pragma unroll
        for (int m = 0; m < 4; ++m)
#pragma unroll
            for (int n = 0; n < 4; ++n)
                acc[m][n] = __builtin_amdgcn_mfma_f32_16x16x32_bf16(a[m], bf[n], acc[m][n], 0, 0, 0);
        __syncthreads();
    }
    float* Sb = S + (size_t)b * N_ * N_;
#pragma unroll
    for (int m = 0; m < 4; ++m)
#pragma unroll
        for (int n = 0; n < 4; ++n) {
#pragma unroll
            for (int j = 0; j < 4; ++j) {
                int row = bm + wr * 64 + m * 16 + (lane >> 4) * 4 + j;
                int col = bn + wc * 64 + n * 16 + (lane & 15);
                Sb[(size_t)row * N_ + col] = acc[m][n][j];
            }
        }
}

// ---------------- softmax stats (no full normalize pass) ----------------
__global__ __launch_bounds__(256) void k_smpart(const float* __restrict__ S,
                                                float* __restrict__ pmax,
                                                float* __restrict__ psum) {
    __shared__ float tile[128][64];
    __shared__ float redm[4][64];
    __shared__ float reds[4][64];
    int b = blockIdx.z;
    int chunk = blockIdx.y;   // 0..7
    int cg = blockIdx.x;      // 0..15
    int tid = threadIdx.x;
    const float* Sb = S + (size_t)b * N_ * N_ + (size_t)(chunk * 128) * N_ + cg * 64;
    for (int q = tid; q < 8192; q += 256) {
        int r = q >> 6, c = q & 63;
        tile[r][c] = Sb[(size_t)r * N_ + c];
    }
    __syncthreads();
    int c = tid & 63, grp = tid >> 6;
    float m = -1e30f;
    for (int r = grp; r < 128; r += 4) m = fmaxf(m, tile[r][c]);
    redm[grp][c] = m;
    __syncthreads();
    m = fmaxf(fmaxf(redm[0][c], redm[1][c]), fmaxf(redm[2][c], redm[3][c]));
    float s = 0.f;
    for (int r = grp; r < 128; r += 4) s += __expf(tile[r][c] - m);
    reds[grp][c] = s;
    __syncthreads();
    if (grp == 0) {
        s = reds[0][c] + reds[1][c] + reds[2][c] + reds[3][c];
        size_t o = ((size_t)b * 8 + chunk) * N_ + cg * 64 + c;
        pmax[o] = m;
        psum[o] = s;
    }
}

__global__ __launch_bounds__(1024) void k_smcomb(const float* __restrict__ pmax,
                                                 const float* __restrict__ psum,
                                                 float* __restrict__ colMax,
                                                 float* __restrict__ colInv) {
    int b = blockIdx.x;
    int col = threadIdx.x;
    float M = -1e30f;
#pragma unroll
    for (int ch = 0; ch < 8; ++ch) M = fmaxf(M, pmax[((size_t)b * 8 + ch) * N_ + col]);
    float s = 0.f;
#pragma unroll
    for (int ch = 0; ch < 8; ++ch)
        s += psum[((size_t)b * 8 + ch) * N_ + col] *
             __expf(pmax[((size_t)b * 8 + ch) * N_ + col] - M);
    colMax[(size_t)b * N_ + col] = M;
    colInv[(size_t)b * N_ + col] = 1.f / s;
}

// ---------------- graph: CSR build + normalization ----------------

__global__ void k_count(const int* __restrict__ rowI, const int* __restrict__ colI,
                        int* __restrict__ cnt, float* __restrict__ deg) {
    int e = blockIdx.x * 256 + threadIdx.x;
    if (e >= E_) return;
    int r = rowI[e];
    atomicAdd(&cnt[r], 1);
    if (r != colI[e]) atomicAdd(&deg[r], 1.0f);
}

__global__ __launch_bounds__(1024) void k_scan(const int* __restrict__ cnt,
                                               const float* __restrict__ deg,
                                               int* __restrict__ rowPtr,
                                               int* __restrict__ fillPos,
                                               float* __restrict__ dis) {
    __shared__ int s[N_];
    int tid = threadIdx.x;
    int my = cnt[tid];
    s[tid] = my;
    __syncthreads();
    for (int off = 1; off < N_; off <<= 1) {
        int v = 0;
        if (tid >= off) v = s[tid - off];
        __syncthreads();
        s[tid] += v;
        __syncthreads();
    }
    rowPtr[tid + 1] = s[tid];
    if (tid == 0) rowPtr[0] = 0;
    fillPos[tid] = s[tid] - my;
    float d = deg[tid];
    dis[tid] = d > 0.f ? rsqrtf(d) : 0.f;
}

__global__ void k_fill(const int* __restrict__ rowI, const int* __restrict__ colI,
                       int* __restrict__ fillPos, int* __restrict__ csrRow,
                       int* __restrict__ csrCol) {
    int e = blockIdx.x * 256 + threadIdx.x;
    if (e >= E_) return;
    int r = rowI[e];
    int pos = atomicAdd(&fillPos[r], 1);
    csrRow[pos] = r;
    csrCol[pos] = colI[e];
}

// softmax applied on the fly at the consumed entries
__global__ void k_csrcoef(const int* __restrict__ csrRow, const int* __restrict__ csrCol,
                          const float* __restrict__ dis, const float* __restrict__ S,
                          const float* __restrict__ colMax, const float* __restrict__ colInv,
                          float* __restrict__ csrNorm, float* __restrict__ csrAttn) {
    int p = blockIdx.x * 256 + threadIdx.x;
    if (p >= E_) return;
    int r = csrRow[p], c = csrCol[p];
    float nm = (r == c) ? 0.f : -dis[r] * dis[c];
    csrNorm[p] = nm;
    size_t off = (size_t)r * N_ + c;
#pragma unroll
    for (int b = 0; b < B_; ++b) {
        float sv = __expf(S[(size_t)b * N_ * N_ + off] - colMax[(size_t)b * N_ + c]) *
                   colInv[(size_t)b * N_ + c];
        csrAttn[(size_t)b * E_ + p] = nm * sv;
    }
}

__global__ void k_diag(const float* __restrict__ S, const float* __restrict__ colMax,
                       const float* __restrict__ colInv, float* __restrict__ diagS) {
    int idx = blockIdx.x * 256 + threadIdx.x;
    if (idx >= B_ * N_) return;
    int n = idx % N_;
    int b = idx / N_;
    float sv = __expf(S[(size_t)b * N_ * N_ + (size_t)n * N_ + n] - colMax[(size_t)b * N_ + n]) *
               colInv[(size_t)b * N_ + n];
    diagS[idx] = sv;
}

// Tx0 = diagS * X
__global__ void k_tx0(const float* __restrict__ X, const float* __restrict__ diagS,
                      float* __restrict__ Tx0) {
    int idx = blockIdx.x * 256 + threadIdx.x;
    if (idx >= B_ * N_ * F_ * T_) return;
    int bn = idx / (F_ * T_);
    Tx0[idx] = diagS[bn] * X[idx];
}

// gather propagation: Tout[b,n,:] = scale * sum_{p in csr row n} coef[p] * Tin[b,csrCol[p],:]
__global__ __launch_bounds__(192) void k_gprop(const float* __restrict__ Tin,
                                               const float* __restrict__ Tsub,
                                               float* __restrict__ Tout,
                                               const float* __restrict__ coef,
                                               const int* __restrict__ csrCol,
                                               const int* __restrict__ rowPtr,
                                               int perB, float scale, int hasSub) {
    int blk = blockIdx.x;
    int b = blk & 7;
    int n = blk >> 3;
    int tid = threadIdx.x;
    int s = rowPtr[n], e = rowPtr[n + 1];
    const float* cbase = coef + (perB ? (size_t)b * E_ : 0);
    float ax = 0.f, ay = 0.f, az = 0.f, aw = 0.f;
    for (int p = s; p < e; ++p) {
        float cf = cbase[p];
        const float4 v =
            *(const float4*)(Tin + ((size_t)(b * N_ + csrCol[p]) * (F_ * T_)) + tid * 4);
        ax += cf * v.x;
        ay += cf * v.y;
        az += cf * v.z;
        aw += cf * v.w;
    }
    size_t obase = (size_t)(b * N_ + n) * (F_ * T_) + tid * 4;
    float4 r;
    r.x = ax * scale;
    r.y = ay * scale;
    r.z = az * scale;
    r.w = aw * scale;
    if (hasSub) {
        const float4 u = *(const float4*)(Tsub + obase);
        r.x -= u.x;
        r.y -= u.y;
        r.z -= u.z;
        r.w -= u.w;
    }
    *(float4*)(Tout + obase) = r;
}

// weight prep: twT[kk][co], kk<192 -> tw, kk in [192,224) -> rw
__global__ void k_wprep(const float* __restrict__ tw, const float* __restrict__ rw,
                        float* __restrict__ twT) {
    int idx = blockIdx.x * 256 + threadIdx.x;
    if (idx >= 224 * 64) return;
    int kk = idx >> 6, co = idx & 63;
    twT[idx] = (kk < 192) ? tw[co * 192 + kk] : rw[co * 32 + (kk - 192)];
}

// ---------------- fused tail: cheb GEMM -> relu -> conv GEMM -> relu -> LN ----------------
// block = 4 sites (96 rows x 64 cols). K=32 chunks, fully unrolled.
__global__ __launch_bounds__(256) void k_tail(const float* __restrict__ Tx0,
                                              const float* __restrict__ Tx1,
                                              const float* __restrict__ Tx2,
                                              const float* __restrict__ X,
                                              const float* __restrict__ chW,
                                              const float* __restrict__ chb,
                                              const float* __restrict__ twT,
                                              const float* __restrict__ tb,
                                              const float* __restrict__ rb,
                                              const float* __restrict__ lng,
                                              const float* __restrict__ lnb,
                                              float* __restrict__ out) {
    __shared__ float As[32 * 97];   // 12416 B, padded stride
    __shared__ float Bs[32 * 64];   // 8192 B
    __shared__ float pool[6656];    // Xhat [4][64][26] halo-padded; later z [96][67]
    const int tid = threadIdx.x;
    const int site0 = blockIdx.x * 4;
    const int tm = (tid >> 4) * 6;  // 6 rows/thread
    const int tn = (tid & 15) * 4;  // 4 cols/thread

    for (int q = tid; q < 6656; q += 256) pool[q] = 0.f;

    float chb_r[4], tbrb[4], gam[4], bet[4];
#pragma unroll
    for (int j = 0; j < 4; ++j) {
        chb_r[j] = chb[tn + j];
        tbrb[j] = tb[tn + j] + rb[tn + j];
        gam[j] = lng[tn + j];
        bet[j] = lnb[tn + j];
    }

    float acc[6][4];
#pragma unroll
    for (int i = 0; i < 6; ++i)
#pragma unroll
        for (int j = 0; j < 4; ++j) acc[i][j] = 0.f;

    // ---- cheb GEMM: K=96 = 3 chunks of 32, chunk kc = whole Tx_kc ----
#pragma unroll
    for (int kc = 0; kc < 3; ++kc) {
        const float* Tsel = (kc == 0) ? Tx0 : (kc == 1) ? Tx1 : Tx2;
        const float* gsrc = Tsel + (size_t)site0 * 768;
        __syncthreads();
#pragma unroll
        for (int it = 0; it < 12; ++it) {
            int q = tid + it * 256;          // contiguous (ls,k,t)
            int ls = q / 768, r = q - ls * 768;
            int k = r / 24, t = r - k * 24;
            As[k * 97 + ls * 24 + t] = gsrc[q];
        }
#pragma unroll
        for (int it = 0; it < 8; ++it) {
            int q = tid + it * 256;
            Bs[q] = chW[kc * 2048 + q];      // [k][c] contiguous
        }
        __syncthreads();
#pragma unroll
        for (int k = 0; k < 32; ++k) {
            const float4 bv = *(const float4*)&Bs[k * 64 + tn];
#pragma unroll
            for (int i = 0; i < 6; ++i) {
                float a = As[k * 97 + tm + i];
                acc[i][0] += a * bv.x; acc[i][1] += a * bv.y;
                acc[i][2] += a * bv.z; acc[i][3] += a * bv.w;
            }
        }
    }
    // Xhat -> pool with bias+relu; reset acc for conv
    __syncthreads();
#pragma unroll
    for (int i = 0; i < 6; ++i) {
        int r = tm + i;
        int ls = r / 24, t = r - ls * 24;
#pragma unroll
        for (int j = 0; j < 4; ++j) {
            pool[ls * 1664 + (tn + j) * 26 + 1 + t] = fmaxf(acc[i][j] + chb_r[j], 0.f);
            acc[i][j] = tbrb[j];
        }
    }

    // ---- conv GEMM: K=224 = 6 pool chunks + 1 residual chunk ----
#pragma unroll
    for (int kc = 0; kc < 7; ++kc) {
        const int k0 = kc * 32;
        __syncthreads();
        if (kc < 6) {
#pragma unroll
            for (int it = 0; it < 12; ++it) {
                int q = tid + it * 256;
                int k = q / 96, m = q - k * 96;
                int ls = m / 24, t = m - ls * 24;
                int kk = k0 + k;
                int ci = kk / 3, dt = kk - ci * 3;
                As[k * 97 + m] = pool[ls * 1664 + ci * 26 + t + dt];
            }
        } else {
            const float* gsrc = X + (size_t)site0 * 768;
#pragma unroll
            for (int it = 0; it < 12; ++it) {
                int q = tid + it * 256;      // contiguous (ls,f,t)
                int ls = q / 768, r = q - ls * 768;
                int k = r / 24, t = r - k * 24;
                As[k * 97 + ls * 24 + t] = gsrc[q];
            }
        }
#pragma unroll
        for (int it = 0; it < 8; ++it) {
            int q = tid + it * 256;
            Bs[q] = twT[k0 * 64 + q];        // pre-transposed, contiguous
        }
        __syncthreads();
#pragma unroll
        for (int k = 0; k < 32; ++k) {
            const float4 bv = *(const float4*)&Bs[k * 64 + tn];
#pragma unroll
            for (int i = 0; i < 6; ++i) {
                float a = As[k * 97 + tm + i];
                acc[i][0] += a * bv.x; acc[i][1] += a * bv.y;
                acc[i][2] += a * bv.z; acc[i][3] += a * bv.w;
            }
        }
    }

    // ---- relu + LN over 64 channels per row (16-lane shfl groups) ----
#pragma unroll
    for (int i = 0; i < 6; ++i) {
        float z0 = fmaxf(acc[i][0], 0.f), z1 = fmaxf(acc[i][1], 0.f);
        float z2 = fmaxf(acc[i][2], 0.f), z3 = fmaxf(acc[i][3], 0.f);
        float s1 = z0 + z1 + z2 + z3;
        float s2 = z0 * z0 + z1 * z1 + z2 * z2 + z3 * z3;
#pragma unroll
        for (int off = 1; off < 16; off <<= 1) {
            s1 += __shfl_xor(s1, off);
            s2 += __shfl_xor(s2, off);
        }
        float mu = s1 * (1.f / 64.f);
        float var = s2 * (1.f / 64.f) - mu * mu;
        float rs = rsqrtf(var + LN_EPS_);
        acc[i][0] = (z0 - mu) * rs * gam[0] + bet[0];
        acc[i][1] = (z1 - mu) * rs * gam[1] + bet[1];
        acc[i][2] = (z2 - mu) * rs * gam[2] + bet[2];
        acc[i][3] = (z3 - mu) * rs * gam[3] + bet[3];
    }
    // stage z into pool (all pool reads finished before last chunk's barrier)
#pragma unroll
    for (int i = 0; i < 6; ++i)
#pragma unroll
        for (int j = 0; j < 4; ++j) pool[(tm + i) * 67 + tn + j] = acc[i][j];
    __syncthreads();
    // coalesced write: out[site][co][t]
    float* ob = out + (size_t)site0 * 1536;
    for (int q = tid; q < 6144; q += 256) {
        int ls = q / 1536, rem = q - ls * 1536;
        int co = rem / 24, t = rem - co * 24;
        ob[q] = pool[(ls * 24 + t) * 67 + co];
    }
}

extern "C" void kernel_launch(void* const* d_in, const int* in_sizes, int n_in,
                              void* d_out, int out_size, void* d_ws, size_t ws_size,
                              hipStream_t stream) {
    const float* X = (const float*)d_in[0];
    const int* ei = (const int*)d_in[1];
    const float* U1 = (const float*)d_in[2];
    const float* U2 = (const float*)d_in[3];
    const float* U3 = (const float*)d_in[4];
    const float* be = (const float*)d_in[5];
    const float* Ve = (const float*)d_in[6];
    const float* W1 = (const float*)d_in[7];
    const float* W2 = (const float*)d_in[8];
    const float* W3 = (const float*)d_in[9];
    const float* bs = (const float*)d_in[10];
    const float* Vs = (const float*)d_in[11];
    const float* chW = (const float*)d_in[12];
    const float* chb = (const float*)d_in[13];
    const float* tw = (const float*)d_in[14];
    const float* tb = (const float*)d_in[15];
    const float* rw = (const float*)d_in[16];
    const float* rb = (const float*)d_in[17];
    const float* lng = (const float*)d_in[18];
    const float* lnb = (const float*)d_in[19];
    float* out = (float*)d_out;
    float* ws = (float*)d_ws;

    size_t o = 0;
    float* lhs_tf = ws + o; o += B_ * T_ * F_;
    float* lhsN  = ws + o; o += (size_t)B_ * T_ * N_;
    float* rhsT  = ws + o; o += (size_t)B_ * N_ * T_;
    float* rhsTT = ws + o; o += (size_t)B_ * T_ * N_;
    float* sigE  = ws + o; o += B_ * T_ * T_;
    float* Eatt  = ws + o; o += B_ * T_ * T_;
    float* slhsF = ws + o; o += (size_t)B_ * N_ * F_;
    float* slhs  = ws + o; o += (size_t)B_ * N_ * T_;
    float* srhs  = ws + o; o += (size_t)B_ * T_ * N_;
    float* deg   = ws + o; o += N_;
    float* dis   = ws + o; o += N_;
    float* diagS = ws + o; o += B_ * N_;
    float* csrNorm = ws + o; o += E_;
    float* csrAttn = ws + o; o += (size_t)B_ * E_;
    float* pmax  = ws + o; o += (size_t)B_ * 8 * N_;
    float* psum  = ws + o; o += (size_t)B_ * 8 * N_;
    float* colMax = ws + o; o += (size_t)B_ * N_;
    float* colInv = ws + o; o += (size_t)B_ * N_;
    float* twT   = ws + o; o += 224 * 64;
    int* cnt     = (int*)(ws + o); o += N_;
    int* rowPtr  = (int*)(ws + o); o += N_ + 1;
    int* fillPos = (int*)(ws + o); o += N_;
    int* csrRow  = (int*)(ws + o); o += E_;
    int* csrCol  = (int*)(ws + o); o += E_ + 3;  // +3: keep later buffers 16B-aligned
    float* Xt    = ws + o; o += (size_t)B_ * N_ * F_ * T_;  // later reused as Tx2
    float* Psig  = ws + o; o += (size_t)B_ * N_ * N_;       // later Tx0
    float* S     = ws + o; o += (size_t)B_ * N_ * N_;       // later Tx1
    float* Xhat  = ws + o; o += (size_t)B_ * N_ * CC_ * T_; // only used as PsigT overlay now
    float* Tx0 = Psig;
    float* Tx1 = S;
    float* Tx2 = Xt;
    __hip_bfloat16* PsigT = (__hip_bfloat16*)Xhat;
    const int* rowI = ei;
    const int* colI = ei + E_;

    // CSR build + weight prep (independent of attention pipeline)
    hipMemsetAsync(cnt, 0, N_ * sizeof(int), stream);
    hipMemsetAsync(deg, 0, N_ * sizeof(float), stream);
    k_count<<<(E_ + 255) / 256, 256, 0, stream>>>(rowI, colI, cnt, deg);
    k_scan<<<1, 1024, 0, stream>>>(cnt, deg, rowPtr, fillPos, dis);
    k_fill<<<(E_ + 255) / 256, 256, 0, stream>>>(rowI, colI, fillPos, csrRow, csrCol);
    k_wprep<<<(224 * 64 + 255) / 256, 256, 0, stream>>>(tw, rw, twT);

    // temporal attention
    hipMemsetAsync(lhs_tf, 0, B_ * T_ * F_ * sizeof(float), stream);
    k_lhs2<<<B_ * 16, 768, 0, stream>>>(X, U1, lhs_tf);
    k_lhsN<<<(B_ * T_ * N_ + 255) / 256, 256, 0, stream>>>(lhs_tf, U2, lhsN);
    k_rhsT<<<(B_ * N_ * T_ + 255) / 256, 256, 0, stream>>>(X, U3, rhsT);
    k_transp<<<B_ * 16, 256, 0, stream>>>(rhsT, rhsTT);
    k_edot<<<B_ * T_ * T_, 64, 0, stream>>>(lhsN, rhsTT, be, sigE);
    k_eatt2<<<B_, 576, 0, stream>>>(sigE, Ve, Eatt);
    k_xt<<<B_ * (N_ * F_ * T_ / 256), 256, 0, stream>>>(X, Eatt, Xt);
    // spatial attention
    k_slhsF<<<(B_ * N_ * F_ + 255) / 256, 256, 0, stream>>>(Xt, W1, slhsF);
    k_slhs<<<(B_ * N_ * T_ + 255) / 256, 256, 0, stream>>>(slhsF, W2, slhs);
    k_srhs<<<(B_ * N_ * T_ + 255) / 256, 256, 0, stream>>>(Xt, W3, srhs);
    {
        dim3 g(16, 16, B_);
        k_psig2<<<g, 256, 0, stream>>>(slhs, srhs, bs, Psig, PsigT);
    }
    {
        dim3 g(8, 8, B_);
        k_smfma<<<g, 256, 0, stream>>>(Vs, PsigT, S);
    }
    // softmax stats only
    {
        dim3 g(16, 8, B_);
        k_smpart<<<g, 256, 0, stream>>>(S, pmax, psum);
    }
    k_smcomb<<<B_, 1024, 0, stream>>>(pmax, psum, colMax, colInv);
    // coefficients in CSR order (softmax applied on the fly)
    k_csrcoef<<<(E_ + 255) / 256, 256, 0, stream>>>(csrRow, csrCol, dis, S, colMax, colInv,
                                                    csrNorm, csrAttn);
    k_diag<<<(B_ * N_ + 255) / 256, 256, 0, stream>>>(S, colMax, colInv, diagS);
    // chebyshev propagation (gather, no atomics)
    k_tx0<<<(B_ * N_ * F_ * T_ + 255) / 256, 256, 0, stream>>>(X, diagS, Tx0);
    k_gprop<<<B_ * N_, 192, 0, stream>>>(Tx0, nullptr, Tx1, csrAttn, csrCol, rowPtr, 1, 1.0f, 0);
    k_gprop<<<B_ * N_, 192, 0, stream>>>(Tx1, Tx0, Tx2, csrNorm, csrCol, rowPtr, 0, 2.0f, 1);
    // fused tail: cheb + time conv + residual + layernorm
    k_tail<<<B_ * N_ / 4, 256, 0, stream>>>(Tx0, Tx1, Tx2, X, chW, chb, twT, tb, rb,
                                            lng, lnb, out);
}

// Round 10
// 476.011 us; speedup vs baseline: 9.2848x; 1.0654x over previous
//
#include <hip/hip_runtime.h>
#include <hip/hip_bf16.h>
#include <math.h>

#define B_ 8
#define N_ 1024
#define F_ 32
#define T_ 24
#define E_ 16384
#define CC_ 64
#define CT_ 64
#define LN_EPS_ 1e-5f

typedef __attribute__((ext_vector_type(8))) short bf16x8;
typedef __attribute__((ext_vector_type(4))) float f32x4;

__device__ __forceinline__ short f2bf(float f) {
    union { float f; unsigned u; } v; v.f = f;
    unsigned r = v.u + 0x7fffu + ((v.u >> 16) & 1u);  // RNE
    return (short)(r >> 16);
}

// ---------------- temporal attention ----------------

// lhs_tf[b,t,f] (stored [b][t*32+f]) = sum_n X[b,n,f,t] * U1[n]
__global__ __launch_bounds__(768) void k_lhs2(const float* __restrict__ X,
                                              const float* __restrict__ U1,
                                              float* __restrict__ out) {
    __shared__ float su[64];
    int b = blockIdx.x >> 4;
    int n0 = (blockIdx.x & 15) * 64;
    int tid = threadIdx.x;
    if (tid < 64) su[tid] = U1[n0 + tid];
    __syncthreads();
    float acc = 0.f;
    const float* xp = X + ((size_t)b * N_ + n0) * 768 + tid;
#pragma unroll 8
    for (int i = 0; i < 64; ++i) acc += xp[(size_t)i * 768] * su[i];
    int f = tid / 24, t = tid - (tid / 24) * 24;
    atomicAdd(&out[b * 768 + t * 32 + f], acc);
}

// lhsN[b,t,n] = sum_f lhs_tf[b,t,f] * U2[f,n]
__global__ void k_lhsN(const float* __restrict__ lhs_tf, const float* __restrict__ U2,
                       float* __restrict__ out) {
    int idx = blockIdx.x * 256 + threadIdx.x;
    if (idx >= B_ * T_ * N_) return;
    int n = idx % N_;
    int bt = idx / N_;
    float acc = 0.f;
#pragma unroll
    for (int f = 0; f < F_; ++f) acc += lhs_tf[bt * F_ + f] * U2[(size_t)f * N_ + n];
    out[idx] = acc;
}

// rhsTT[b,t,n] = sum_f U3[f] * X[b,n,f,t]  (transposed store, fused)
__global__ __launch_bounds__(256) void k_rhsTT(const float* __restrict__ X,
                                               const float* __restrict__ U3,
                                               float* __restrict__ outp) {
    __shared__ float s[64 * 25];
    __shared__ float su3[32];
    int b = blockIdx.x >> 4;
    int n0 = (blockIdx.x & 15) * 64;
    int tid = threadIdx.x;
    if (tid < 32) su3[tid] = U3[tid];
    __syncthreads();
    for (int q = tid; q < 1536; q += 256) {
        int n = q / 24, t = q - (q / 24) * 24;
        const float* xp = X + ((size_t)(b * N_ + n0 + n) * 32) * 24 + t;
        float acc = 0.f;
#pragma unroll
        for (int f = 0; f < 32; ++f) acc += su3[f] * xp[f * 24];
        s[n * 25 + t] = acc;
    }
    __syncthreads();
    for (int q = tid; q < 1536; q += 256) {
        int t = q >> 6, n = q & 63;
        outp[((size_t)b * 24 + t) * N_ + n0 + n] = s[n * 25 + t];
    }
}

// sig[b,i,j] = sigmoid( lhsN[b,i,:] . rhsTT[b,j,:] + be[i,j] ); one wave per (b,i,j)
__global__ __launch_bounds__(64) void k_edot(const float* __restrict__ lhsN,
                                             const float* __restrict__ rhsTT,
                                             const float* __restrict__ be,
                                             float* __restrict__ sig) {
    int blk = blockIdx.x;
    int b = blk / 576, ij = blk % 576;
    int i = ij / 24, j = ij % 24;
    int lane = threadIdx.x;
    const float* lp = lhsN + ((size_t)b * 24 + i) * N_;
    const float* rp = rhsTT + ((size_t)b * 24 + j) * N_;
    float acc = 0.f;
#pragma unroll
    for (int n = lane; n < N_; n += 64) acc += lp[n] * rp[n];
    for (int off = 32; off > 0; off >>= 1) acc += __shfl_xor(acc, off);
    if (lane == 0) sig[blk] = 1.f / (1.f + expf(-(acc + be[ij])));
}

// Escore = Ve @ sig, then softmax over rows -> Eatt
__global__ __launch_bounds__(576) void k_eatt2(const float* __restrict__ sig,
                                               const float* __restrict__ Ve,
                                               float* __restrict__ Eatt) {
    __shared__ float ss[T_ * T_];
    __shared__ float esc[T_ * T_];
    int b = blockIdx.x;
    int tid = threadIdx.x;
    ss[tid] = sig[b * 576 + tid];
    __syncthreads();
    int i = tid / T_, j = tid % T_;
    {
        float acc = 0.f;
#pragma unroll
        for (int m = 0; m < T_; ++m) acc += Ve[i * T_ + m] * ss[m * T_ + j];
        esc[tid] = acc;
    }
    __syncthreads();
    if (tid < T_) {
        int jj = tid;
        float mx = -1e30f;
        for (int r = 0; r < T_; ++r) mx = fmaxf(mx, esc[r * T_ + jj]);
        float s = 0.f;
        for (int r = 0; r < T_; ++r) {
            float e = expf(esc[r * T_ + jj] - mx);
            ss[r * T_ + jj] = e;
            s += e;
        }
        float inv = 1.f / s;
        for (int r = 0; r < T_; ++r) Eatt[(size_t)(b * T_ + r) * T_ + jj] = ss[r * T_ + jj] * inv;
    }
}

// ---------------- fused spatial prep: Xt (in-reg) -> slhs, srhs ----------------
// block = (b, 8 nodes); thread = one (n,f) row. Xt never materialized.
__global__ __launch_bounds__(256) void k_spat(const float* __restrict__ X,
                                              const float* __restrict__ Eatt,
                                              const float* __restrict__ W1,
                                              const float* __restrict__ W2,
                                              const float* __restrict__ W3,
                                              float* __restrict__ slhs,
                                              float* __restrict__ srhs) {
    __shared__ float se[576];
    __shared__ float sw2[768];
    __shared__ float sw1[24];
    __shared__ float sw3[32];
    __shared__ float scratch[256 * 25];  // W3[f]*xt rows
    __shared__ float sF[256];            // slhsF per (n_loc,f)
    int b = blockIdx.x >> 7;
    int n0 = (blockIdx.x & 127) * 8;
    int tid = threadIdx.x;
    int n_loc = tid >> 5, f = tid & 31;
    for (int q = tid; q < 576; q += 256) se[q] = Eatt[b * 576 + q];
    for (int q = tid; q < 768; q += 256) sw2[q] = W2[q];
    if (tid < 24) sw1[tid] = W1[tid];
    if (tid < 32) sw3[tid] = W3[tid];
    __syncthreads();
    // read X row (24 floats)
    const float* xp = X + ((size_t)(b * N_ + n0 + n_loc) * 32 + f) * 24;
    float xr[24];
#pragma unroll
    for (int j = 0; j < 6; ++j) {
        float4 v = *(const float4*)(xp + j * 4);
        xr[j * 4 + 0] = v.x; xr[j * 4 + 1] = v.y; xr[j * 4 + 2] = v.z; xr[j * 4 + 3] = v.w;
    }
    // xt[t] = sum_k xr[k] * Eatt[k,t]
    float xt[24];
#pragma unroll
    for (int t = 0; t < 24; ++t) xt[t] = 0.f;
#pragma unroll
    for (int k = 0; k < 24; ++k) {
        float xv = xr[k];
#pragma unroll
        for (int t = 0; t < 24; ++t) xt[t] += xv * se[k * 24 + t];
    }
    // slhsF and W3-scaled rows
    float sf = 0.f;
#pragma unroll
    for (int t = 0; t < 24; ++t) sf += xt[t] * sw1[t];
    sF[tid] = sf;
    float w3v = sw3[f];
#pragma unroll
    for (int t = 0; t < 24; ++t) scratch[tid * 25 + t] = w3v * xt[t];
    __syncthreads();
    if (tid < 192) {
        int nl = tid / 24, t = tid - (tid / 24) * 24;
        float sr_acc = 0.f, sl_acc = 0.f;
#pragma unroll
        for (int ff = 0; ff < 32; ++ff) {
            sr_acc += scratch[(nl * 32 + ff) * 25 + t];
            sl_acc += sF[nl * 32 + ff] * sw2[ff * 24 + t];
        }
        int n = n0 + nl;
        slhs[((size_t)b * N_ + n) * 24 + t] = sl_acc;
        srhs[((size_t)b * 24 + t) * N_ + n] = sr_acc;
    }
}

// Psig tile kernel -> PsigT[b,k,i] bf16 only (f32 Psig write was dead)
__global__ __launch_bounds__(256) void k_psig2(const float* __restrict__ slhs,
                                               const float* __restrict__ srhs,
                                               const float* __restrict__ bs,
                                               __hip_bfloat16* __restrict__ PsigT) {
    __shared__ float sl[64][24];
    __shared__ float sr[24][64];
    __shared__ short st[64][72];
    int b = blockIdx.z;
    int i0 = blockIdx.y * 64, k0 = blockIdx.x * 64;
    int tid = threadIdx.x;
    {
        const float* sp = slhs + ((size_t)b * N_ + i0) * 24;
#pragma unroll
        for (int it = 0; it < 6; ++it) {
            int q = tid + it * 256;
            sl[q / 24][q % 24] = sp[q];
        }
        const float* rp = srhs + (size_t)b * 24 * N_ + k0;
#pragma unroll
        for (int it = 0; it < 6; ++it) {
            int q = tid + it * 256;
            sr[q >> 6][q & 63] = rp[(size_t)(q >> 6) * N_ + (q & 63)];
        }
    }
    __syncthreads();
    int ib = (tid >> 4) * 4;
    int kb = (tid & 15) * 4;
    float acc[4][4];
#pragma unroll
    for (int a = 0; a < 4; ++a) {
        const float4 bv = *(const float4*)(bs + (size_t)(i0 + ib + a) * N_ + k0 + kb);
        acc[a][0] = bv.x; acc[a][1] = bv.y; acc[a][2] = bv.z; acc[a][3] = bv.w;
    }
#pragma unroll
    for (int t = 0; t < 24; ++t) {
        float r0 = sr[t][kb], r1 = sr[t][kb + 1], r2 = sr[t][kb + 2], r3 = sr[t][kb + 3];
#pragma unroll
        for (int a = 0; a < 4; ++a) {
            float lv = sl[ib + a][t];
            acc[a][0] += lv * r0; acc[a][1] += lv * r1; acc[a][2] += lv * r2; acc[a][3] += lv * r3;
        }
    }
#pragma unroll
    for (int a = 0; a < 4; ++a) {
        st[kb + 0][ib + a] = f2bf(1.f / (1.f + expf(-acc[a][0])));
        st[kb + 1][ib + a] = f2bf(1.f / (1.f + expf(-acc[a][1])));
        st[kb + 2][ib + a] = f2bf(1.f / (1.f + expf(-acc[a][2])));
        st[kb + 3][ib + a] = f2bf(1.f / (1.f + expf(-acc[a][3])));
    }
    __syncthreads();
    short* op = (short*)PsigT + ((size_t)b * N_ + k0) * N_ + i0;
#pragma unroll
    for (int it = 0; it < 2; ++it) {
        int ch = tid + it * 256;
        int kk = ch >> 3, off = (ch & 7) * 8;
        uint4 u = *(uint4*)&st[kk][off];
        *(uint4*)(op + (size_t)kk * N_ + off) = u;
    }
}

// S[b] = Vs @ Psig[b] via bf16 MFMA. 128x128 tile, 4 waves, BK=32.
__global__ __launch_bounds__(256) void k_smfma(const float* __restrict__ Vs,
                                               const __hip_bfloat16* __restrict__ PsigT,
                                               float* __restrict__ S) {
    __shared__ short Asd[128][40];
    __shared__ short Bsd[128][40];
    const int b = blockIdx.z;
    const int bm = blockIdx.y * 128, bn = blockIdx.x * 128;
    const int tid = threadIdx.x;
    const int lane = tid & 63, wave = tid >> 6;
    const int wr = wave >> 1, wc = wave & 1;
    const int fr = lane & 15, ks = lane >> 4;
    f32x4 acc[4][4] = {};
    const short* PT = (const short*)PsigT + (size_t)b * N_ * N_;
    for (int k0 = 0; k0 < N_; k0 += 32) {
#pragma unroll
        for (int it = 0; it < 4; ++it) {
            int q = tid + it * 256;
            int row = q >> 3, kk = (q & 7) * 4;
            float4 v = *(const float4*)(Vs + (size_t)(bm + row) * N_ + k0 + kk);
            short4 s4;
            s4.x = f2bf(v.x); s4.y = f2bf(v.y); s4.z = f2bf(v.z); s4.w = f2bf(v.w);
            *(short4*)&Asd[row][kk] = s4;
        }
#pragma unroll
        for (int it = 0; it < 2; ++it) {
            int q = tid + it * 256;
            int row = q >> 2, kk = (q & 3) * 8;
            uint4 u = *(const uint4*)(PT + (size_t)(bn + row) * N_ + k0 + kk);
            *(uint4*)&Bsd[row][kk] = u;
        }
        __syncthreads();
        bf16x8 a[4], bf[4];
#pragma unroll
        for (int m = 0; m < 4; ++m) a[m] = *(const bf16x8*)&Asd[wr * 64 + m * 16 + fr][ks * 8];
#pragma unroll
        for (int n = 0; n < 4; ++n) bf[n] = *(const bf16x8*)&Bsd[wc * 64 + n * 16 + fr][ks * 8];
#pragma unroll
        for (int m = 0; m < 4; ++m)
#pragma unroll
            for (int n = 0; n < 4; ++n)
                acc[m][n] = __builtin_amdgcn_mfma_f32_16x16x32_bf16(a[m], bf[n], acc[m][n], 0, 0, 0);
        __syncthreads();
    }
    float* Sb = S + (size_t)b * N_ * N_;
#pragma unroll
    for (int m = 0; m < 4; ++m)
#pragma unroll
        for (int n = 0; n < 4; ++n) {
#pragma unroll
            for (int j = 0; j < 4; ++j) {
                int row = bm + wr * 64 + m * 16 + (lane >> 4) * 4 + j;
                int col = bn + wc * 64 + n * 16 + (lane & 15);
                Sb[(size_t)row * N_ + col] = acc[m][n][j];
            }
        }
}

// ---------------- softmax stats (no full normalize pass) ----------------
__global__ __launch_bounds__(256) void k_smpart(const float* __restrict__ S,
                                                float* __restrict__ pmax,
                                                float* __restrict__ psum) {
    __shared__ float tile[128][64];
    __shared__ float redm[4][64];
    __shared__ float reds[4][64];
    int b = blockIdx.z;
    int chunk = blockIdx.y;
    int cg = blockIdx.x;
    int tid = threadIdx.x;
    const float* Sb = S + (size_t)b * N_ * N_ + (size_t)(chunk * 128) * N_ + cg * 64;
    for (int q = tid; q < 8192; q += 256) {
        int r = q >> 6, c = q & 63;
        tile[r][c] = Sb[(size_t)r * N_ + c];
    }
    __syncthreads();
    int c = tid & 63, grp = tid >> 6;
    float m = -1e30f;
    for (int r = grp; r < 128; r += 4) m = fmaxf(m, tile[r][c]);
    redm[grp][c] = m;
    __syncthreads();
    m = fmaxf(fmaxf(redm[0][c], redm[1][c]), fmaxf(redm[2][c], redm[3][c]));
    float s = 0.f;
    for (int r = grp; r < 128; r += 4) s += __expf(tile[r][c] - m);
    reds[grp][c] = s;
    __syncthreads();
    if (grp == 0) {
        s = reds[0][c] + reds[1][c] + reds[2][c] + reds[3][c];
        size_t o = ((size_t)b * 8 + chunk) * N_ + cg * 64 + c;
        pmax[o] = m;
        psum[o] = s;
    }
}

__global__ __launch_bounds__(1024) void k_smcomb(const float* __restrict__ pmax,
                                                 const float* __restrict__ psum,
                                                 float* __restrict__ colMax,
                                                 float* __restrict__ colInv) {
    int b = blockIdx.x;
    int col = threadIdx.x;
    float M = -1e30f;
#pragma unroll
    for (int ch = 0; ch < 8; ++ch) M = fmaxf(M, pmax[((size_t)b * 8 + ch) * N_ + col]);
    float s = 0.f;
#pragma unroll
    for (int ch = 0; ch < 8; ++ch)
        s += psum[((size_t)b * 8 + ch) * N_ + col] *
             __expf(pmax[((size_t)b * 8 + ch) * N_ + col] - M);
    colMax[(size_t)b * N_ + col] = M;
    colInv[(size_t)b * N_ + col] = 1.f / s;
}

// ---------------- graph: fused CSR build (count+scan+fill) + weight prep ----------------
__global__ __launch_bounds__(1024) void k_graph(const int* __restrict__ rowI,
                                                const int* __restrict__ colI,
                                                const float* __restrict__ tw,
                                                const float* __restrict__ rw,
                                                int* __restrict__ rowPtr,
                                                int* __restrict__ csrRow,
                                                int* __restrict__ csrCol,
                                                float* __restrict__ dis,
                                                float* __restrict__ twT) {
    __shared__ int s[N_];
    __shared__ int fillPos[N_];
    __shared__ int degc[N_];
    int tid = threadIdx.x;
    s[tid] = 0;
    degc[tid] = 0;
    __syncthreads();
#pragma unroll
    for (int i = 0; i < 16; ++i) {
        int e = tid + i * 1024;
        int r = rowI[e], c = colI[e];
        atomicAdd(&s[r], 1);
        if (r != c) atomicAdd(&degc[r], 1);
    }
    __syncthreads();
    int my = s[tid];
    __syncthreads();
    for (int off = 1; off < N_; off <<= 1) {
        int v = 0;
        if (tid >= off) v = s[tid - off];
        __syncthreads();
        s[tid] += v;
        __syncthreads();
    }
    rowPtr[tid + 1] = s[tid];
    if (tid == 0) rowPtr[0] = 0;
    fillPos[tid] = s[tid] - my;
    float d = (float)degc[tid];
    dis[tid] = d > 0.f ? rsqrtf(d) : 0.f;
    __syncthreads();
#pragma unroll
    for (int i = 0; i < 16; ++i) {
        int e = tid + i * 1024;
        int r = rowI[e];
        int pos = atomicAdd(&fillPos[r], 1);
        csrRow[pos] = r;
        csrCol[pos] = colI[e];
    }
    // weight prep: twT[kk][co]
    for (int q = tid; q < 224 * 64; q += 1024) {
        int kk = q >> 6, co = q & 63;
        twT[q] = (kk < 192) ? tw[co * 192 + kk] : rw[co * 32 + (kk - 192)];
    }
}

// softmax applied on the fly at the consumed entries
__global__ void k_csrcoef(const int* __restrict__ csrRow, const int* __restrict__ csrCol,
                          const float* __restrict__ dis, const float* __restrict__ S,
                          const float* __restrict__ colMax, const float* __restrict__ colInv,
                          float* __restrict__ csrNorm, float* __restrict__ csrAttn) {
    int p = blockIdx.x * 256 + threadIdx.x;
    if (p >= E_) return;
    int r = csrRow[p], c = csrCol[p];
    float nm = (r == c) ? 0.f : -dis[r] * dis[c];
    csrNorm[p] = nm;
    size_t off = (size_t)r * N_ + c;
#pragma unroll
    for (int b = 0; b < B_; ++b) {
        float sv = __expf(S[(size_t)b * N_ * N_ + off] - colMax[(size_t)b * N_ + c]) *
                   colInv[(size_t)b * N_ + c];
        csrAttn[(size_t)b * E_ + p] = nm * sv;
    }
}

__global__ void k_diag(const float* __restrict__ S, const float* __restrict__ colMax,
                       const float* __restrict__ colInv, float* __restrict__ diagS) {
    int idx = blockIdx.x * 256 + threadIdx.x;
    if (idx >= B_ * N_) return;
    int n = idx % N_;
    int b = idx / N_;
    float sv = __expf(S[(size_t)b * N_ * N_ + (size_t)n * N_ + n] - colMax[(size_t)b * N_ + n]) *
               colInv[(size_t)b * N_ + n];
    diagS[idx] = sv;
}

// Tx0 = diagS * X
__global__ void k_tx0(const float* __restrict__ X, const float* __restrict__ diagS,
                      float* __restrict__ Tx0) {
    int idx = blockIdx.x * 256 + threadIdx.x;
    if (idx >= B_ * N_ * F_ * T_) return;
    int bn = idx / (F_ * T_);
    Tx0[idx] = diagS[bn] * X[idx];
}

// gather propagation: Tout[b,n,:] = scale * sum_{p in csr row n} coef[p] * Tin[b,csrCol[p],:]
__global__ __launch_bounds__(192) void k_gprop(const float* __restrict__ Tin,
                                               const float* __restrict__ Tsub,
                                               float* __restrict__ Tout,
                                               const float* __restrict__ coef,
                                               const int* __restrict__ csrCol,
                                               const int* __restrict__ rowPtr,
                                               int perB, float scale, int hasSub) {
    int blk = blockIdx.x;
    int b = blk & 7;
    int n = blk >> 3;
    int tid = threadIdx.x;
    int s = rowPtr[n], e = rowPtr[n + 1];
    const float* cbase = coef + (perB ? (size_t)b * E_ : 0);
    float ax = 0.f, ay = 0.f, az = 0.f, aw = 0.f;
    for (int p = s; p < e; ++p) {
        float cf = cbase[p];
        const float4 v =
            *(const float4*)(Tin + ((size_t)(b * N_ + csrCol[p]) * (F_ * T_)) + tid * 4);
        ax += cf * v.x;
        ay += cf * v.y;
        az += cf * v.z;
        aw += cf * v.w;
    }
    size_t obase = (size_t)(b * N_ + n) * (F_ * T_) + tid * 4;
    float4 r;
    r.x = ax * scale;
    r.y = ay * scale;
    r.z = az * scale;
    r.w = aw * scale;
    if (hasSub) {
        const float4 u = *(const float4*)(Tsub + obase);
        r.x -= u.x;
        r.y -= u.y;
        r.z -= u.z;
        r.w -= u.w;
    }
    *(float4*)(Tout + obase) = r;
}

// ---------------- fused tail: cheb GEMM -> relu -> conv GEMM -> relu -> LN ----------------
__global__ __launch_bounds__(256) void k_tail(const float* __restrict__ Tx0,
                                              const float* __restrict__ Tx1,
                                              const float* __restrict__ Tx2,
                                              const float* __restrict__ X,
                                              const float* __restrict__ chW,
                                              const float* __restrict__ chb,
                                              const float* __restrict__ twT,
                                              const float* __restrict__ tb,
                                              const float* __restrict__ rb,
                                              const float* __restrict__ lng,
                                              const float* __restrict__ lnb,
                                              float* __restrict__ out) {
    __shared__ float As[32 * 97];
    __shared__ float Bs[32 * 64];
    __shared__ float pool[6656];
    const int tid = threadIdx.x;
    const int site0 = blockIdx.x * 4;
    const int tm = (tid >> 4) * 6;
    const int tn = (tid & 15) * 4;

    for (int q = tid; q < 6656; q += 256) pool[q] = 0.f;

    float chb_r[4], tbrb[4], gam[4], bet[4];
#pragma unroll
    for (int j = 0; j < 4; ++j) {
        chb_r[j] = chb[tn + j];
        tbrb[j] = tb[tn + j] + rb[tn + j];
        gam[j] = lng[tn + j];
        bet[j] = lnb[tn + j];
    }

    float acc[6][4];
#pragma unroll
    for (int i = 0; i < 6; ++i)
#pragma unroll
        for (int j = 0; j < 4; ++j) acc[i][j] = 0.f;

#pragma unroll
    for (int kc = 0; kc < 3; ++kc) {
        const float* Tsel = (kc == 0) ? Tx0 : (kc == 1) ? Tx1 : Tx2;
        const float* gsrc = Tsel + (size_t)site0 * 768;
        __syncthreads();
#pragma unroll
        for (int it = 0; it < 12; ++it) {
            int q = tid + it * 256;
            int ls = q / 768, r = q - ls * 768;
            int k = r / 24, t = r - k * 24;
            As[k * 97 + ls * 24 + t] = gsrc[q];
        }
#pragma unroll
        for (int it = 0; it < 8; ++it) {
            int q = tid + it * 256;
            Bs[q] = chW[kc * 2048 + q];
        }
        __syncthreads();
#pragma unroll
        for (int k = 0; k < 32; ++k) {
            const float4 bv = *(const float4*)&Bs[k * 64 + tn];
#pragma unroll
            for (int i = 0; i < 6; ++i) {
                float a = As[k * 97 + tm + i];
                acc[i][0] += a * bv.x; acc[i][1] += a * bv.y;
                acc[i][2] += a * bv.z; acc[i][3] += a * bv.w;
            }
        }
    }
    __syncthreads();
#pragma unroll
    for (int i = 0; i < 6; ++i) {
        int r = tm + i;
        int ls = r / 24, t = r - ls * 24;
#pragma unroll
        for (int j = 0; j < 4; ++j) {
            pool[ls * 1664 + (tn + j) * 26 + 1 + t] = fmaxf(acc[i][j] + chb_r[j], 0.f);
            acc[i][j] = tbrb[j];
        }
    }

#pragma unroll
    for (int kc = 0; kc < 7; ++kc) {
        const int k0 = kc * 32;
        __syncthreads();
        if (kc < 6) {
#pragma unroll
            for (int it = 0; it < 12; ++it) {
                int q = tid + it * 256;
                int k = q / 96, m = q - k * 96;
                int ls = m / 24, t = m - ls * 24;
                int kk = k0 + k;
                int ci = kk / 3, dt = kk - ci * 3;
                As[k * 97 + m] = pool[ls * 1664 + ci * 26 + t + dt];
            }
        } else {
            const float* gsrc = X + (size_t)site0 * 768;
#pragma unroll
            for (int it = 0; it < 12; ++it) {
                int q = tid + it * 256;
                int ls = q / 768, r = q - ls * 768;
                int k = r / 24, t = r - k * 24;
                As[k * 97 + ls * 24 + t] = gsrc[q];
            }
        }
#pragma unroll
        for (int it = 0; it < 8; ++it) {
            int q = tid + it * 256;
            Bs[q] = twT[k0 * 64 + q];
        }
        __syncthreads();
#pragma unroll
        for (int k = 0; k < 32; ++k) {
            const float4 bv = *(const float4*)&Bs[k * 64 + tn];
#pragma unroll
            for (int i = 0; i < 6; ++i) {
                float a = As[k * 97 + tm + i];
                acc[i][0] += a * bv.x; acc[i][1] += a * bv.y;
                acc[i][2] += a * bv.z; acc[i][3] += a * bv.w;
            }
        }
    }

#pragma unroll
    for (int i = 0; i < 6; ++i) {
        float z0 = fmaxf(acc[i][0], 0.f), z1 = fmaxf(acc[i][1], 0.f);
        float z2 = fmaxf(acc[i][2], 0.f), z3 = fmaxf(acc[i][3], 0.f);
        float s1 = z0 + z1 + z2 + z3;
        float s2 = z0 * z0 + z1 * z1 + z2 * z2 + z3 * z3;
#pragma unroll
        for (int off = 1; off < 16; off <<= 1) {
            s1 += __shfl_xor(s1, off);
            s2 += __shfl_xor(s2, off);
        }
        float mu = s1 * (1.f / 64.f);
        float var = s2 * (1.f / 64.f) - mu * mu;
        float rs = rsqrtf(var + LN_EPS_);
        acc[i][0] = (z0 - mu) * rs * gam[0] + bet[0];
        acc[i][1] = (z1 - mu) * rs * gam[1] + bet[1];
        acc[i][2] = (z2 - mu) * rs * gam[2] + bet[2];
        acc[i][3] = (z3 - mu) * rs * gam[3] + bet[3];
    }
#pragma unroll
    for (int i = 0; i < 6; ++i)
#pragma unroll
        for (int j = 0; j < 4; ++j) pool[(tm + i) * 67 + tn + j] = acc[i][j];
    __syncthreads();
    float* ob = out + (size_t)site0 * 1536;
    for (int q = tid; q < 6144; q += 256) {
        int ls = q / 1536, rem = q - ls * 1536;
        int co = rem / 24, t = rem - co * 24;
        ob[q] = pool[(ls * 24 + t) * 67 + co];
    }
}

extern "C" void kernel_launch(void* const* d_in, const int* in_sizes, int n_in,
                              void* d_out, int out_size, void* d_ws, size_t ws_size,
                              hipStream_t stream) {
    const float* X = (const float*)d_in[0];
    const int* ei = (const int*)d_in[1];
    const float* U1 = (const float*)d_in[2];
    const float* U2 = (const float*)d_in[3];
    const float* U3 = (const float*)d_in[4];
    const float* be = (const float*)d_in[5];
    const float* Ve = (const float*)d_in[6];
    const float* W1 = (const float*)d_in[7];
    const float* W2 = (const float*)d_in[8];
    const float* W3 = (const float*)d_in[9];
    const float* bs = (const float*)d_in[10];
    const float* Vs = (const float*)d_in[11];
    const float* chW = (const float*)d_in[12];
    const float* chb = (const float*)d_in[13];
    const float* tw = (const float*)d_in[14];
    const float* tb = (const float*)d_in[15];
    const float* rw = (const float*)d_in[16];
    const float* rb = (const float*)d_in[17];
    const float* lng = (const float*)d_in[18];
    const float* lnb = (const float*)d_in[19];
    float* out = (float*)d_out;
    float* ws = (float*)d_ws;

    size_t o = 0;
    float* lhs_tf = ws + o; o += B_ * T_ * F_;
    float* lhsN  = ws + o; o += (size_t)B_ * T_ * N_;
    float* rhsTT = ws + o; o += (size_t)B_ * T_ * N_;
    float* sigE  = ws + o; o += B_ * T_ * T_;
    float* Eatt  = ws + o; o += B_ * T_ * T_;
    float* slhs  = ws + o; o += (size_t)B_ * N_ * T_;
    float* srhs  = ws + o; o += (size_t)B_ * T_ * N_;
    float* dis   = ws + o; o += N_;
    float* diagS = ws + o; o += B_ * N_;
    float* csrNorm = ws + o; o += E_;
    float* csrAttn = ws + o; o += (size_t)B_ * E_;
    float* pmax  = ws + o; o += (size_t)B_ * 8 * N_;
    float* psum  = ws + o; o += (size_t)B_ * 8 * N_;
    float* colMax = ws + o; o += (size_t)B_ * N_;
    float* colInv = ws + o; o += (size_t)B_ * N_;
    float* twT   = ws + o; o += 224 * 64;
    int* rowPtr  = (int*)(ws + o); o += N_ + 1;
    int* csrRow  = (int*)(ws + o); o += E_;
    int* csrCol  = (int*)(ws + o); o += E_ + 3;  // +3: keep later buffers 16B-aligned
    float* Xt    = ws + o; o += (size_t)B_ * N_ * F_ * T_;  // Tx2 scratch
    float* Psig  = ws + o; o += (size_t)B_ * N_ * N_;       // Tx0 scratch
    float* S     = ws + o; o += (size_t)B_ * N_ * N_;       // Tx1 scratch
    float* Xhat  = ws + o; o += (size_t)B_ * N_ * CC_ * T_; // PsigT overlay
    float* Tx0 = Psig;
    float* Tx1 = S;
    float* Tx2 = Xt;
    __hip_bfloat16* PsigT = (__hip_bfloat16*)Xhat;
    const int* rowI = ei;
    const int* colI = ei + E_;

    // fused CSR build + weight prep (one block)
    k_graph<<<1, 1024, 0, stream>>>(rowI, colI, tw, rw, rowPtr, csrRow, csrCol, dis, twT);

    // temporal attention
    hipMemsetAsync(lhs_tf, 0, B_ * T_ * F_ * sizeof(float), stream);
    k_lhs2<<<B_ * 16, 768, 0, stream>>>(X, U1, lhs_tf);
    k_lhsN<<<(B_ * T_ * N_ + 255) / 256, 256, 0, stream>>>(lhs_tf, U2, lhsN);
    k_rhsTT<<<B_ * 16, 256, 0, stream>>>(X, U3, rhsTT);
    k_edot<<<B_ * T_ * T_, 64, 0, stream>>>(lhsN, rhsTT, be, sigE);
    k_eatt2<<<B_, 576, 0, stream>>>(sigE, Ve, Eatt);
    // fused spatial prep (Xt never materialized)
    k_spat<<<B_ * 128, 256, 0, stream>>>(X, Eatt, W1, W2, W3, slhs, srhs);
    {
        dim3 g(16, 16, B_);
        k_psig2<<<g, 256, 0, stream>>>(slhs, srhs, bs, PsigT);
    }
    {
        dim3 g(8, 8, B_);
        k_smfma<<<g, 256, 0, stream>>>(Vs, PsigT, S);
    }
    // softmax stats only
    {
        dim3 g(16, 8, B_);
        k_smpart<<<g, 256, 0, stream>>>(S, pmax, psum);
    }
    k_smcomb<<<B_, 1024, 0, stream>>>(pmax, psum, colMax, colInv);
    // coefficients in CSR order (softmax applied on the fly)
    k_csrcoef<<<(E_ + 255) / 256, 256, 0, stream>>>(csrRow, csrCol, dis, S, colMax, colInv,
                                                    csrNorm, csrAttn);
    k_diag<<<(B_ * N_ + 255) / 256, 256, 0, stream>>>(S, colMax, colInv, diagS);
    // chebyshev propagation (gather, no atomics)
    k_tx0<<<(B_ * N_ * F_ * T_ + 255) / 256, 256, 0, stream>>>(X, diagS, Tx0);
    k_gprop<<<B_ * N_, 192, 0, stream>>>(Tx0, nullptr, Tx1, csrAttn, csrCol, rowPtr, 1, 1.0f, 0);
    k_gprop<<<B_ * N_, 192, 0, stream>>>(Tx1, Tx0, Tx2, csrNorm, csrCol, rowPtr, 0, 2.0f, 1);
    // fused tail: cheb + time conv + residual + layernorm
    k_tail<<<B_ * N_ / 4, 256, 0, stream>>>(Tx0, Tx1, Tx2, X, chW, chb, twT, tb, rb,
                                            lng, lnb, out);
}